// Round 9
// baseline (215.247 us; speedup 1.0000x reference)
//
#include <hip/hip_runtime.h>
#include <hip/hip_bf16.h>
#include <math.h>

#define Bc 4
#define Lc 1024
#define Dc 768
#define Hc 12
#define Ec 24
#define Mc 4
#define Pc 552
#define EMBc 768
#define NLc 97
#define Rc (Bc*Pc)      // 2208
#define KSPL 48         // bilinear: 12 k-blocks x 4 i-splits of 16
#define HT_ABS (35*32*512)   // htbf flin per-batch stride (shorts)

typedef __attribute__((ext_vector_type(4))) float f32x4;
typedef __attribute__((ext_vector_type(8))) short short8;
typedef __attribute__((ext_vector_type(4))) unsigned short us4;
typedef _Float16 f16x8 __attribute__((ext_vector_type(8)));

static __device__ __forceinline__ unsigned short f2bf(float x){
  unsigned int u = __float_as_uint(x);
  unsigned int r = u + 0x7fffu + ((u >> 16) & 1u);   // RNE
  return (unsigned short)(r >> 16);
}
static __device__ __forceinline__ unsigned short f2h(float x){
  _Float16 h = (_Float16)x;
  return __builtin_bit_cast(unsigned short, h);
}
// flin index: row r, k-index kk, KT = K/32 chunks
static __device__ __forceinline__ size_t flin_off(int r, int kk, int KT){
  return ((size_t)(r>>4)*KT + (kk>>5))*512 + (size_t)((((kk&31)>>3)*16 + (r&15))*8) + (kk&7);
}

// ---------------- K0: weight prep + ent_att + mention gather (one launch) ----------------
__global__ __launch_bounds__(256) void k_prep(const float* __restrict__ bilW, unsigned short* __restrict__ Wbf,
                                              const float* __restrict__ seq, unsigned short* __restrict__ seqf,
                                              const float* __restrict__ W_q, unsigned short* __restrict__ Wq_f,
                                              const float* __restrict__ W_k, unsigned short* __restrict__ Wk_f,
                                              const float* __restrict__ headW, unsigned short* __restrict__ headW_f,
                                              const float* __restrict__ tailW, unsigned short* __restrict__ tailW_f,
                                              const float* __restrict__ att, const int* __restrict__ mpos,
                                              float* __restrict__ ent_att,
                                              float* __restrict__ ment, unsigned short* __restrict__ ment_bf){
  int bx = blockIdx.x;
  int tid = threadIdx.x;
  if (bx < 1536){
    const float* Ws = bilW + (size_t)bx*32*NLc;
    unsigned short* o = Wbf + (size_t)bx*4480;
    for (int idx = tid; idx < 112*32; idx += 256){
      int n = idx % 112, kk = idx / 112;
      float v = (n < NLc) ? Ws[(size_t)kk*NLc + n] : 0.f;
      o[n*40 + kk] = f2h(v);
    }
    return;
  }
  if (bx >= 3168){                  // ent_att + gather
    int blk = bx - 3168;            // (b*E+e)*H + h, 1152 blocks
    int h  = blk % Hc;
    int be = blk / Hc;
    int b  = be / Ec;
    int p0 = mpos[be*Mc+0]+1, p1 = mpos[be*Mc+1]+1;
    int p2 = mpos[be*Mc+2]+1, p3 = mpos[be*Mc+3]+1;
    const float* ab = att + ((size_t)b*Hc + h)*Lc*Lc;
    const float* a0 = ab + (size_t)p0*Lc;
    const float* a1 = ab + (size_t)p1*Lc;
    const float* a2 = ab + (size_t)p2*Lc;
    const float* a3 = ab + (size_t)p3*Lc;
    float* o = ent_att + (size_t)blk*Lc;
    for (int l = tid; l < Lc; l += 256)
      o[l] = 0.25f*(a0[l]+a1[l]+a2[l]+a3[l]);
    int gidx = blk*256 + tid;       // over B*E*M*D
    int d = gidx % Dc;
    int bem = gidx / Dc;
    int bb = bem / (Ec*Mc);
    int pos = mpos[bem] + 1;
    float v = seq[((size_t)bb*Lc + pos)*Dc + d];
    ment[gidx] = v;
    ment_bf[flin_off(bem, d, 24)] = f2bf(v);
    return;
  }
  bx -= 1536;
  const float* src; unsigned short* dst; int tk, tn, KTW;
  if (bx < 768){                     // seq [1024x768] x4 -> flin KTW=32
    int z = bx / 192, rem = bx % 192;
    src = seq + (size_t)z*Lc*Dc; dst = seqf + (size_t)z*(Dc/16)*(Lc/32)*512;
    tk = rem % 16; tn = rem / 16; KTW = 32;
  } else if (bx < 768+144){
    int rem = bx - 768;
    src = W_q; dst = Wq_f; tk = rem % 12; tn = rem / 12; KTW = 24;
  } else if (bx < 768+288){
    int rem = bx - (768+144);
    src = W_k; dst = Wk_f; tk = rem % 12; tn = rem / 12; KTW = 24;
  } else if (bx < 768+288+288){
    int rem = bx - (768+288);
    src = headW; dst = headW_f; tk = rem % 24; tn = rem / 24; KTW = 48;
  } else {
    int rem = bx - (768+288+288);
    src = tailW; dst = tailW_f; tk = rem % 24; tn = rem / 24; KTW = 48;
  }
  int r0 = tk*64, c0 = tn*64;       // r0 along K, c0 along N(=768)
  __shared__ float t[64][65];
  #pragma unroll
  for (int q8 = 0; q8 < 16; q8++){
    int idx = q8*256 + tid;
    int rr = idx >> 6, cc = idx & 63;
    t[rr][cc] = src[(size_t)(r0+rr)*768 + c0+cc];
  }
  __syncthreads();
  #pragma unroll
  for (int q8 = 0; q8 < 16; q8++){
    int idx = q8*256 + tid;
    int li = idx & 511, sub = idx >> 9;
    int nt_l = sub >> 1, kt_l = sub & 1;
    int lane = li >> 3, e = li & 7;
    int kl = kt_l*32 + (lane>>4)*8 + e;
    int nl = nt_l*16 + (lane&15);
    dst[ ((size_t)(c0/16 + nt_l)*KTW + (r0/32 + kt_l))*512 + li ] = f2bf(t[kl][nl]);
  }
}

// ---------------- K2: ht_att -> bf16 flin (zero pad rows 552..559) ----------------
__global__ __launch_bounds__(256) void k_ht_att(const float* __restrict__ ent_att,
                                                const int* __restrict__ hts,
                                                unsigned short* __restrict__ htbf){
  int b = blockIdx.x & 3;
  int p = blockIdx.x >> 2;          // 0..559
  unsigned short* o = htbf + (size_t)b*HT_ABS;
  int l4 = threadIdx.x*4;
  if (p >= Pc){
    us4 z4 = {0,0,0,0};
    *(us4*)(o + flin_off(p, l4, 32)) = z4;
    return;
  }
  int r = b*Pc + p;
  int hi = hts[r*2+0], ti = hts[r*2+1];
  const float* eh = ent_att + (size_t)(b*Ec+hi)*Hc*Lc;
  const float* et = ent_att + (size_t)(b*Ec+ti)*Hc*Lc;
  __shared__ float raw[Lc];
  __shared__ float wsum[4];
  float4 s4 = {0.f,0.f,0.f,0.f};
  #pragma unroll
  for (int h = 0; h < Hc; h++){
    float4 e1 = *(const float4*)&eh[h*Lc + l4];
    float4 e2 = *(const float4*)&et[h*Lc + l4];
    s4.x = fmaf(e1.x,e2.x,s4.x); s4.y = fmaf(e1.y,e2.y,s4.y);
    s4.z = fmaf(e1.z,e2.z,s4.z); s4.w = fmaf(e1.w,e2.w,s4.w);
  }
  s4.x *= (1.0f/Hc); s4.y *= (1.0f/Hc); s4.z *= (1.0f/Hc); s4.w *= (1.0f/Hc);
  *(float4*)&raw[l4] = s4;
  float lsum = s4.x+s4.y+s4.z+s4.w;
  for (int off = 32; off; off >>= 1) lsum += __shfl_down(lsum, off);
  if ((threadIdx.x & 63) == 0) wsum[threadIdx.x>>6] = lsum;
  __syncthreads();
  float inv = 1.0f/(wsum[0]+wsum[1]+wsum[2]+wsum[3] + 1e-5f);
  float4 rv = *(const float4*)&raw[l4];
  us4 v4;
  v4[0] = f2bf(rv.x*inv); v4[1] = f2bf(rv.y*inv);
  v4[2] = f2bf(rv.z*inv); v4[3] = f2bf(rv.w*inv);
  *(us4*)(o + flin_off(p, l4, 32)) = v4;
}

// ---------------- K4: flin MFMA GEMM, 2 m-frags/wave (32 rows) ----------------
struct FJob {
  const unsigned short* A1; const unsigned short* A2;
  const unsigned short* W;  const float* bias; void* C;
  int M; int mtmax; size_t Abs; size_t Wbs; int rowsPerBatch;
};

// CT: 0 = fp32 (+bias), 2 = bf16 flin (KTC=24)
template<int KT1, int CT>
__global__ __launch_bounds__(256) void k_fgemm(FJob j0, FJob j1, int nx0){
  FJob j = (blockIdx.x < nx0) ? j0 : j1;
  int mbx = (blockIdx.x < nx0) ? blockIdx.x : blockIdx.x - nx0;
  int z = blockIdx.z;
  int lane = threadIdx.x & 63, wid = threadIdx.x >> 6;
  int row16 = lane & 15, oct = lane >> 4;
  int rb = mbx*128 + wid*32;
  int mt0 = rb >> 4;       if (mt0 >= j.mtmax) mt0 = j.mtmax - 1;
  int mt1 = (rb >> 4) + 1; if (mt1 >= j.mtmax) mt1 = j.mtmax - 1;
  const unsigned short* ap0 = j.A1 + (size_t)z*j.Abs + (size_t)mt0*KT1*512 + lane*8;
  const unsigned short* ap1 = j.A1 + (size_t)z*j.Abs + (size_t)mt1*KT1*512 + lane*8;
  const unsigned short* wb = j.W  + (size_t)z*j.Wbs + (size_t)(blockIdx.y*4)*KT1*512 + lane*8;
  f32x4 acc[2][4];
  #pragma unroll
  for (int m = 0; m < 2; m++)
    #pragma unroll
    for (int n = 0; n < 4; n++) acc[m][n] = (f32x4){0.f,0.f,0.f,0.f};
  #pragma unroll 4
  for (int kt = 0; kt < KT1; kt++){
    short8 a0 = *(const short8*)(ap0 + (size_t)kt*512);
    short8 a1 = *(const short8*)(ap1 + (size_t)kt*512);
    #pragma unroll
    for (int n = 0; n < 4; n++){
      short8 bv = *(const short8*)(wb + (size_t)(n*KT1 + kt)*512);
      acc[0][n] = __builtin_amdgcn_mfma_f32_16x16x32_bf16(a0, bv, acc[0][n], 0, 0, 0);
      acc[1][n] = __builtin_amdgcn_mfma_f32_16x16x32_bf16(a1, bv, acc[1][n], 0, 0, 0);
    }
  }
  int colb = blockIdx.y*64;
  #pragma unroll
  for (int m = 0; m < 2; m++)
    #pragma unroll
    for (int n = 0; n < 4; n++)
      #pragma unroll
      for (int jj = 0; jj < 4; jj++){
        int r = rb + m*16 + oct*4 + jj;
        if (r < j.M){
          int col = colb + n*16 + row16;
          float v = acc[m][n][jj];
          if (CT == 0 && j.bias) v += j.bias[col];
          int rg = z*j.rowsPerBatch + r;
          if (CT == 2){
            ((unsigned short*)j.C)[flin_off(rg, col, 24)] = f2bf(v);
          } else {
            ((float*)j.C)[(size_t)rg*768 + col] = v;
          }
        }
      }
}

// ---------------- K5: fused head+tail GEMM + tanh -> fp16 row-major ----------------
// 128 threads (2 waves x 32 rows); grid (36,12)
__global__ __launch_bounds__(128) void k_hts(const unsigned short* __restrict__ h_bf,
                                             const unsigned short* __restrict__ t_bf,
                                             const unsigned short* __restrict__ rs_bf,
                                             const unsigned short* __restrict__ headW_f,
                                             const unsigned short* __restrict__ tailW_f,
                                             const float* __restrict__ headb,
                                             const float* __restrict__ tailb,
                                             unsigned short* __restrict__ hs16,
                                             unsigned short* __restrict__ ts16){
  int lane = threadIdx.x & 63, wid = threadIdx.x >> 6;
  int row16 = lane & 15, oct = lane >> 4;
  int rb = blockIdx.x*64 + wid*32;
  int mt0 = rb >> 4;  if (mt0 > 137) mt0 = 137;
  int mt1 = mt0 + 1;  if (mt1 > 137) mt1 = 137;
  const unsigned short* ah0 = h_bf  + (size_t)mt0*24*512 + lane*8;
  const unsigned short* ah1 = h_bf  + (size_t)mt1*24*512 + lane*8;
  const unsigned short* at0 = t_bf  + (size_t)mt0*24*512 + lane*8;
  const unsigned short* at1 = t_bf  + (size_t)mt1*24*512 + lane*8;
  const unsigned short* ar0 = rs_bf + (size_t)mt0*24*512 + lane*8;
  const unsigned short* ar1 = rs_bf + (size_t)mt1*24*512 + lane*8;
  const unsigned short* wh = headW_f + (size_t)(blockIdx.y*4)*48*512 + lane*8;
  const unsigned short* wt = tailW_f + (size_t)(blockIdx.y*4)*48*512 + lane*8;
  f32x4 acch[2][4], acct[2][4];
  #pragma unroll
  for (int m = 0; m < 2; m++)
    #pragma unroll
    for (int n = 0; n < 4; n++){
      acch[m][n] = (f32x4){0.f,0.f,0.f,0.f};
      acct[m][n] = (f32x4){0.f,0.f,0.f,0.f};
    }
  #pragma unroll 2
  for (int kt = 0; kt < 24; kt++){
    short8 a0 = *(const short8*)(ah0 + (size_t)kt*512);
    short8 a1 = *(const short8*)(ah1 + (size_t)kt*512);
    short8 b0 = *(const short8*)(at0 + (size_t)kt*512);
    short8 b1 = *(const short8*)(at1 + (size_t)kt*512);
    #pragma unroll
    for (int n = 0; n < 4; n++){
      short8 bh = *(const short8*)(wh + (size_t)(n*48 + kt)*512);
      short8 bt = *(const short8*)(wt + (size_t)(n*48 + kt)*512);
      acch[0][n] = __builtin_amdgcn_mfma_f32_16x16x32_bf16(a0, bh, acch[0][n], 0, 0, 0);
      acch[1][n] = __builtin_amdgcn_mfma_f32_16x16x32_bf16(a1, bh, acch[1][n], 0, 0, 0);
      acct[0][n] = __builtin_amdgcn_mfma_f32_16x16x32_bf16(b0, bt, acct[0][n], 0, 0, 0);
      acct[1][n] = __builtin_amdgcn_mfma_f32_16x16x32_bf16(b1, bt, acct[1][n], 0, 0, 0);
    }
  }
  #pragma unroll 2
  for (int kt = 0; kt < 24; kt++){
    short8 a0 = *(const short8*)(ar0 + (size_t)kt*512);
    short8 a1 = *(const short8*)(ar1 + (size_t)kt*512);
    #pragma unroll
    for (int n = 0; n < 4; n++){
      short8 bh = *(const short8*)(wh + (size_t)(n*48 + 24 + kt)*512);
      short8 bt = *(const short8*)(wt + (size_t)(n*48 + 24 + kt)*512);
      acch[0][n] = __builtin_amdgcn_mfma_f32_16x16x32_bf16(a0, bh, acch[0][n], 0, 0, 0);
      acch[1][n] = __builtin_amdgcn_mfma_f32_16x16x32_bf16(a1, bh, acch[1][n], 0, 0, 0);
      acct[0][n] = __builtin_amdgcn_mfma_f32_16x16x32_bf16(a0, bt, acct[0][n], 0, 0, 0);
      acct[1][n] = __builtin_amdgcn_mfma_f32_16x16x32_bf16(a1, bt, acct[1][n], 0, 0, 0);
    }
  }
  int colb = blockIdx.y*64;
  #pragma unroll
  for (int m = 0; m < 2; m++)
    #pragma unroll
    for (int n = 0; n < 4; n++)
      #pragma unroll
      for (int jj = 0; jj < 4; jj++){
        int r = rb + m*16 + oct*4 + jj;
        if (r < Rc){
          int col = colb + n*16 + row16;
          hs16[(size_t)r*768 + col] = f2h(tanhf(acch[m][n][jj] + headb[col]));
          ts16[(size_t)r*768 + col] = f2h(tanhf(acct[m][n][jj] + tailb[col]));
        }
      }
}

// ---------------- K6: pool, wave-per-r (no barriers) ----------------
__global__ __launch_bounds__(256) void k_pool(const float* __restrict__ kment,
                                              const float* __restrict__ ment,
                                              const float* __restrict__ q_c,
                                              const int* __restrict__ hts,
                                              unsigned short* __restrict__ h_bf,
                                              unsigned short* __restrict__ t_bf){
  int wid = threadIdx.x >> 6, lane = threadIdx.x & 63;
  int r = blockIdx.x*4 + wid;
  int b = r / Pc;
  float q[12];
  const float* qp = q_c + (size_t)r*Dc + lane;
  #pragma unroll
  for (int u = 0; u < 12; u++) q[u] = qp[u*64];
  const float invs = 0.03608439182435161f;  // 1/sqrt(768)
  #pragma unroll
  for (int side = 0; side < 2; side++){
    int e = hts[r*2+side];
    const float* kb = kment + (size_t)(b*Ec+e)*Mc*Dc + lane;
    const float* mb = ment  + (size_t)(b*Ec+e)*Mc*Dc;   // FIX: no +lane (d below includes lane)
    float part[Mc] = {0.f,0.f,0.f,0.f};
    #pragma unroll
    for (int m = 0; m < Mc; m++)
      #pragma unroll
      for (int u = 0; u < 12; u++)
        part[m] = fmaf(kb[m*Dc + u*64], q[u], part[m]);
    #pragma unroll
    for (int m = 0; m < Mc; m++)
      #pragma unroll
      for (int off = 1; off < 64; off <<= 1)
        part[m] += __shfl_xor(part[m], off);
    float mx = fmaxf(fmaxf(part[0],part[1]), fmaxf(part[2],part[3])) * invs;
    float w0 = expf(part[0]*invs - mx), w1 = expf(part[1]*invs - mx);
    float w2 = expf(part[2]*invs - mx), w3 = expf(part[3]*invs - mx);
    float isum = 1.0f/(w0+w1+w2+w3);
    w0 *= isum; w1 *= isum; w2 *= isum; w3 *= isum;
    unsigned short* o = side ? t_bf : h_bf;
    #pragma unroll
    for (int u = 0; u < 12; u++){
      int d = lane + u*64;
      float v = w0*mb[d] + w1*mb[Dc+d] + w2*mb[2*Dc+d] + w3*mb[3*Dc+d];
      o[flin_off(r, d, 24)] = f2bf(v);
    }
  }
}

// ---------------- K8: MFMA bilinear fp16, 4 m-frags/wave, KSPL=48 ----------------
// grid = mb(9) x kb(48); block 4 waves x 64 rows = 256 rows
__global__ __launch_bounds__(256) void k_bilinear_mfma(
    const unsigned short* __restrict__ hs16, const unsigned short* __restrict__ ts16,
    const unsigned short* __restrict__ Wbf,
    float* __restrict__ partial)
{
  int mb = blockIdx.x / KSPL;
  int kb = blockIdx.x % KSPL;
  int k  = kb >> 2;             // EMB block 0..11
  int i0 = (kb & 3) * 16;       // i sub-range (16 wide)

  int tid  = threadIdx.x;
  int lane = tid & 63;
  int wid  = tid >> 6;
  int row16 = lane & 15;
  int oct   = lane >> 4;

  int rbase = mb*256 + wid*64;

  __shared__ __align__(16) unsigned short Wlds[2][8960];

  f16x8 tsh[4][2];  // [m][jhalf]
  f16x8 hsh[4][2];  // [m][q], i = q*8 + e  (16 i-values)
  #pragma unroll
  for (int m = 0; m < 4; m++){
    int r = rbase + m*16 + row16; if (r > Rc-1) r = Rc-1;
    const unsigned short* tp = ts16 + (size_t)r*EMBc + k*64;
    tsh[m][0] = __builtin_bit_cast(f16x8, *(const short8*)(tp + oct*8));
    tsh[m][1] = __builtin_bit_cast(f16x8, *(const short8*)(tp + 32 + oct*8));
    const unsigned short* hp = hs16 + (size_t)r*EMBc + k*64 + i0;
    hsh[m][0] = __builtin_bit_cast(f16x8, *(const short8*)(hp));
    hsh[m][1] = __builtin_bit_cast(f16x8, *(const short8*)(hp + 8));
  }

  const char* wsrc = (const char*)(Wbf + ((size_t)(k*128 + i0*2))*4480);

  #pragma unroll
  for (int rr = 0; rr < 5; rr++){
    int u = tid + rr*256;
    if (u < 1120)
      __builtin_amdgcn_global_load_lds(
        (const __attribute__((address_space(1))) unsigned int*)(wsrc + (size_t)u*16),
        (__attribute__((address_space(3))) unsigned int*)((char*)&Wlds[0][0] + u*16),
        16, 0, 0);
  }

  f32x4 acc[4][7];
  #pragma unroll
  for (int m = 0; m < 4; m++)
    #pragma unroll
    for (int n = 0; n < 7; n++) acc[m][n] = (f32x4){0.f,0.f,0.f,0.f};

  __syncthreads();   // pair 0 staged

  #pragma unroll
  for (int cp = 0; cp < 16; cp++){    // pair cp = chunks (i=cp, jh=0/1)
    int cur = cp & 1;
    if (cp < 15){
      const char* nsrc = wsrc + (size_t)(cp+1)*17920;
      #pragma unroll
      for (int rr = 0; rr < 5; rr++){
        int u = tid + rr*256;
        if (u < 1120)
          __builtin_amdgcn_global_load_lds(
            (const __attribute__((address_space(1))) unsigned int*)(nsrc + (size_t)u*16),
            (__attribute__((address_space(3))) unsigned int*)((char*)&Wlds[cur^1][0] + u*16),
            16, 0, 0);
      }
    }
    #pragma unroll
    for (int half = 0; half < 2; half++){
      f16x8 af[4];
      #pragma unroll
      for (int m = 0; m < 4; m++){
        _Float16 hv = hsh[m][cp>>3][cp&7];       // static after full unroll
        f16x8 hvb = {hv,hv,hv,hv,hv,hv,hv,hv};
        af[m] = tsh[m][half] * hvb;              // 4x v_pk_mul_f16
      }
      #pragma unroll
      for (int n = 0; n < 7; n++){
        f16x8 bfr = __builtin_bit_cast(f16x8,
            *(const short8*)&Wlds[cur][half*4480 + (n*16 + row16)*40 + oct*8]);
        #pragma unroll
        for (int m = 0; m < 4; m++)
          acc[m][n] = __builtin_amdgcn_mfma_f32_16x16x32_f16(af[m], bfr, acc[m][n], 0, 0, 0);
      }
    }
    __syncthreads();
  }

  float* pk = partial + (size_t)kb*Rc*NLc;
  #pragma unroll
  for (int m = 0; m < 4; m++){
    #pragma unroll
    for (int n = 0; n < 7; n++){
      #pragma unroll
      for (int j = 0; j < 4; j++){
        int r = rbase + m*16 + oct*4 + j;
        int col = n*16 + row16;
        if (r < Rc && col < NLc)
          pk[(size_t)r*NLc + col] = acc[m][n][j];
      }
    }
  }
}

// ---------------- K9: sum partials + bias ----------------
__global__ __launch_bounds__(256) void k_reduce(const float* __restrict__ partial,
                                                const float* __restrict__ bilb,
                                                float* __restrict__ out){
  int idx = blockIdx.x*256 + threadIdx.x;
  if (idx >= Rc*NLc) return;
  int n = idx % NLc;
  float s = bilb[n];
  #pragma unroll
  for (int ks = 0; ks < KSPL; ks++) s += partial[(size_t)ks*Rc*NLc + idx];
  out[idx] = s;
}

extern "C" void kernel_launch(void* const* d_in, const int* in_sizes, int n_in,
                              void* d_out, int out_size, void* d_ws, size_t ws_size,
                              hipStream_t stream){
  const float* seq   = (const float*)d_in[0];
  const float* att   = (const float*)d_in[1];
  const float* W_q   = (const float*)d_in[2];
  const float* W_k   = (const float*)d_in[3];
  const float* headW = (const float*)d_in[4];
  const float* headb = (const float*)d_in[5];
  const float* tailW = (const float*)d_in[6];
  const float* tailb = (const float*)d_in[7];
  const float* bilW  = (const float*)d_in[8];
  const float* bilb  = (const float*)d_in[9];
  const int*   mpos  = (const int*)d_in[10];
  const int*   hts   = (const int*)d_in[11];
  float* out = (float*)d_out;

  float* ws = (float*)d_ws;
  float* ent_att = ws;                                      // 1,179,648 f
  float* q_c     = ws + 1179648;                            // 1,695,744 f
  float* kment   = q_c + 1695744;                           //   294,912 f
  float* ment    = kment + 294912;                          //   294,912 f
  unsigned short* seqf    = (unsigned short*)(ment + 294912);   // 3,145,728 sh
  unsigned short* htbf    = seqf + 3145728;                     // 2,293,760 sh
  unsigned short* rs_bf   = htbf + 4*HT_ABS;                    // 1,695,744 sh
  unsigned short* ment_bf = rs_bf + 1695744;                    //   294,912 sh
  unsigned short* h_bf    = ment_bf + 294912;                   // 1,695,744 sh
  unsigned short* t_bf    = h_bf + 1695744;                     // 1,695,744 sh
  unsigned short* Wq_f    = t_bf + 1695744;                     //   589,824 sh
  unsigned short* Wk_f    = Wq_f + 589824;                      //   589,824 sh
  unsigned short* headW_f = Wk_f + 589824;                      // 1,179,648 sh
  unsigned short* tailW_f = headW_f + 1179648;                  // 1,179,648 sh
  unsigned short* hs16 = tailW_f + 1179648;                 // 1,695,744 sh (fp16 row-major)
  unsigned short* ts16 = hs16 + 1695744;                    // 1,695,744 sh
  unsigned short* Wbf  = ts16 + 1695744;                    // 6,881,280 sh (fp16)
  float* partial = ws;   // 48*2208*97 = 10,280,448 f < 10,645,504 f prefix: safe

  k_prep   <<<4320, 256, 0, stream>>>(bilW, Wbf, seq, seqf, W_q, Wq_f, W_k, Wk_f,
                                      headW, headW_f, tailW, tailW_f,
                                      att, mpos, ent_att, ment, ment_bf);
  k_ht_att <<<4*560, 256, 0, stream>>>(ent_att, hts, htbf);
  {
    FJob jrs = { htbf, nullptr, seqf, nullptr, rs_bf, Pc, 35,
                 (size_t)HT_ABS, (size_t)(48*32*512), Pc };
    k_fgemm<32,2><<<dim3(5,12,4), 256, 0, stream>>>(jrs, jrs, 5);
  }
  {
    FJob jq = { rs_bf,   nullptr, Wq_f, nullptr, q_c,   Rc,       138, 0, 0, 0 };
    FJob jk = { ment_bf, nullptr, Wk_f, nullptr, kment, Bc*Ec*Mc,  24, 0, 0, 0 };
    k_fgemm<24,0><<<dim3(21,12), 256, 0, stream>>>(jq, jk, 18);
  }
  k_pool   <<<Rc/4, 256, 0, stream>>>(kment, ment, q_c, hts, h_bf, t_bf);
  k_hts    <<<dim3(36,12), 128, 0, stream>>>(h_bf, t_bf, rs_bf, headW_f, tailW_f,
                                             headb, tailb, hs16, ts16);
  k_bilinear_mfma<<<9*KSPL, 256, 0, stream>>>(hs16, ts16, Wbf, partial);
  k_reduce <<<(Rc*NLc+255)/256, 256, 0, stream>>>(partial, bilb, out);
}

// Round 10
// 172.218 us; speedup vs baseline: 1.2499x; 1.2499x over previous
//
#include <hip/hip_runtime.h>
#include <hip/hip_bf16.h>
#include <math.h>

#define Bc 4
#define Lc 1024
#define Dc 768
#define Hc 12
#define Ec 24
#define Mc 4
#define Pc 552
#define EMBc 768
#define NLc 97
#define Rc (Bc*Pc)      // 2208
#define KSPL 24         // bilinear: 12 k-blocks x 2 i-splits of 32
#define HT_ABS (35*32*512)   // htbf flin per-batch stride (shorts)

typedef __attribute__((ext_vector_type(4))) float f32x4;
typedef __attribute__((ext_vector_type(8))) short short8;
typedef __attribute__((ext_vector_type(4))) unsigned short us4;
typedef _Float16 f16x8 __attribute__((ext_vector_type(8)));

static __device__ __forceinline__ unsigned short f2bf(float x){
  unsigned int u = __float_as_uint(x);
  unsigned int r = u + 0x7fffu + ((u >> 16) & 1u);   // RNE
  return (unsigned short)(r >> 16);
}
static __device__ __forceinline__ unsigned short f2h(float x){
  _Float16 h = (_Float16)x;
  return __builtin_bit_cast(unsigned short, h);
}
// flin index: row r, k-index kk, KT = K/32 chunks
static __device__ __forceinline__ size_t flin_off(int r, int kk, int KT){
  return ((size_t)(r>>4)*KT + (kk>>5))*512 + (size_t)((((kk&31)>>3)*16 + (r&15))*8) + (kk&7);
}

// ---------------- K0: weight prep + ent_att + mention gather (one launch) ----------------
__global__ __launch_bounds__(256) void k_prep(const float* __restrict__ bilW, unsigned short* __restrict__ Wbf,
                                              const float* __restrict__ seq, unsigned short* __restrict__ seqf,
                                              const float* __restrict__ W_q, unsigned short* __restrict__ Wq_f,
                                              const float* __restrict__ W_k, unsigned short* __restrict__ Wk_f,
                                              const float* __restrict__ headW, unsigned short* __restrict__ headW_f,
                                              const float* __restrict__ tailW, unsigned short* __restrict__ tailW_f,
                                              const float* __restrict__ att, const int* __restrict__ mpos,
                                              float* __restrict__ ent_att,
                                              float* __restrict__ ment, unsigned short* __restrict__ ment_bf){
  int bx = blockIdx.x;
  int tid = threadIdx.x;
  if (bx < 1536){
    const float* Ws = bilW + (size_t)bx*32*NLc;
    unsigned short* o = Wbf + (size_t)bx*4480;
    for (int idx = tid; idx < 112*32; idx += 256){
      int n = idx % 112, kk = idx / 112;
      float v = (n < NLc) ? Ws[(size_t)kk*NLc + n] : 0.f;
      o[n*40 + kk] = f2h(v);
    }
    return;
  }
  if (bx >= 3168){                  // ent_att + gather
    int blk = bx - 3168;            // (b*E+e)*H + h, 1152 blocks
    int h  = blk % Hc;
    int be = blk / Hc;
    int b  = be / Ec;
    int p0 = mpos[be*Mc+0]+1, p1 = mpos[be*Mc+1]+1;
    int p2 = mpos[be*Mc+2]+1, p3 = mpos[be*Mc+3]+1;
    const float* ab = att + ((size_t)b*Hc + h)*Lc*Lc;
    const float* a0 = ab + (size_t)p0*Lc;
    const float* a1 = ab + (size_t)p1*Lc;
    const float* a2 = ab + (size_t)p2*Lc;
    const float* a3 = ab + (size_t)p3*Lc;
    float* o = ent_att + (size_t)blk*Lc;
    for (int l = tid; l < Lc; l += 256)
      o[l] = 0.25f*(a0[l]+a1[l]+a2[l]+a3[l]);
    int gidx = blk*256 + tid;       // over B*E*M*D
    int d = gidx % Dc;
    int bem = gidx / Dc;
    int bb = bem / (Ec*Mc);
    int pos = mpos[bem] + 1;
    float v = seq[((size_t)bb*Lc + pos)*Dc + d];
    ment[gidx] = v;
    ment_bf[flin_off(bem, d, 24)] = f2bf(v);
    return;
  }
  bx -= 1536;
  const float* src; unsigned short* dst; int tk, tn, KTW;
  if (bx < 768){                     // seq [1024x768] x4 -> flin KTW=32
    int z = bx / 192, rem = bx % 192;
    src = seq + (size_t)z*Lc*Dc; dst = seqf + (size_t)z*(Dc/16)*(Lc/32)*512;
    tk = rem % 16; tn = rem / 16; KTW = 32;
  } else if (bx < 768+144){
    int rem = bx - 768;
    src = W_q; dst = Wq_f; tk = rem % 12; tn = rem / 12; KTW = 24;
  } else if (bx < 768+288){
    int rem = bx - (768+144);
    src = W_k; dst = Wk_f; tk = rem % 12; tn = rem / 12; KTW = 24;
  } else if (bx < 768+288+288){
    int rem = bx - (768+288);
    src = headW; dst = headW_f; tk = rem % 24; tn = rem / 24; KTW = 48;
  } else {
    int rem = bx - (768+288+288);
    src = tailW; dst = tailW_f; tk = rem % 24; tn = rem / 24; KTW = 48;
  }
  int r0 = tk*64, c0 = tn*64;       // r0 along K, c0 along N(=768)
  __shared__ float t[64][65];
  #pragma unroll
  for (int q8 = 0; q8 < 16; q8++){
    int idx = q8*256 + tid;
    int rr = idx >> 6, cc = idx & 63;
    t[rr][cc] = src[(size_t)(r0+rr)*768 + c0+cc];
  }
  __syncthreads();
  #pragma unroll
  for (int q8 = 0; q8 < 16; q8++){
    int idx = q8*256 + tid;
    int li = idx & 511, sub = idx >> 9;
    int nt_l = sub >> 1, kt_l = sub & 1;
    int lane = li >> 3, e = li & 7;
    int kl = kt_l*32 + (lane>>4)*8 + e;
    int nl = nt_l*16 + (lane&15);
    dst[ ((size_t)(c0/16 + nt_l)*KTW + (r0/32 + kt_l))*512 + li ] = f2bf(t[kl][nl]);
  }
}

// ---------------- K2: ht_att -> bf16 flin (zero pad rows 552..559) ----------------
__global__ __launch_bounds__(256) void k_ht_att(const float* __restrict__ ent_att,
                                                const int* __restrict__ hts,
                                                unsigned short* __restrict__ htbf){
  int b = blockIdx.x & 3;
  int p = blockIdx.x >> 2;          // 0..559
  unsigned short* o = htbf + (size_t)b*HT_ABS;
  int l4 = threadIdx.x*4;
  if (p >= Pc){
    us4 z4 = {0,0,0,0};
    *(us4*)(o + flin_off(p, l4, 32)) = z4;
    return;
  }
  int r = b*Pc + p;
  int hi = hts[r*2+0], ti = hts[r*2+1];
  const float* eh = ent_att + (size_t)(b*Ec+hi)*Hc*Lc;
  const float* et = ent_att + (size_t)(b*Ec+ti)*Hc*Lc;
  __shared__ float raw[Lc];
  __shared__ float wsum[4];
  float4 s4 = {0.f,0.f,0.f,0.f};
  #pragma unroll
  for (int h = 0; h < Hc; h++){
    float4 e1 = *(const float4*)&eh[h*Lc + l4];
    float4 e2 = *(const float4*)&et[h*Lc + l4];
    s4.x = fmaf(e1.x,e2.x,s4.x); s4.y = fmaf(e1.y,e2.y,s4.y);
    s4.z = fmaf(e1.z,e2.z,s4.z); s4.w = fmaf(e1.w,e2.w,s4.w);
  }
  s4.x *= (1.0f/Hc); s4.y *= (1.0f/Hc); s4.z *= (1.0f/Hc); s4.w *= (1.0f/Hc);
  *(float4*)&raw[l4] = s4;
  float lsum = s4.x+s4.y+s4.z+s4.w;
  for (int off = 32; off; off >>= 1) lsum += __shfl_down(lsum, off);
  if ((threadIdx.x & 63) == 0) wsum[threadIdx.x>>6] = lsum;
  __syncthreads();
  float inv = 1.0f/(wsum[0]+wsum[1]+wsum[2]+wsum[3] + 1e-5f);
  float4 rv = *(const float4*)&raw[l4];
  us4 v4;
  v4[0] = f2bf(rv.x*inv); v4[1] = f2bf(rv.y*inv);
  v4[2] = f2bf(rv.z*inv); v4[3] = f2bf(rv.w*inv);
  *(us4*)(o + flin_off(p, l4, 32)) = v4;
}

// ---------------- K4: flin MFMA GEMM, 2 m-frags/wave (32 rows) ----------------
struct FJob {
  const unsigned short* A1; const unsigned short* A2;
  const unsigned short* W;  const float* bias; void* C;
  int M; int mtmax; size_t Abs; size_t Wbs; int rowsPerBatch;
};

// CT: 0 = fp32 (+bias), 1 = fp32+bias+tanh -> fp16 row-major, 2 = bf16 flin (KTC=24)
template<int KT1, int KT2, int CT>
__global__ __launch_bounds__(256) void k_fgemm(FJob j0, FJob j1, int nx0){
  FJob j = (blockIdx.x < nx0) ? j0 : j1;
  int mbx = (blockIdx.x < nx0) ? blockIdx.x : blockIdx.x - nx0;
  const int KTW = KT1 + KT2;
  int z = blockIdx.z;
  int lane = threadIdx.x & 63, wid = threadIdx.x >> 6;
  int row16 = lane & 15, oct = lane >> 4;
  int rb = mbx*128 + wid*32;
  int mt0 = rb >> 4;       if (mt0 >= j.mtmax) mt0 = j.mtmax - 1;
  int mt1 = (rb >> 4) + 1; if (mt1 >= j.mtmax) mt1 = j.mtmax - 1;
  const unsigned short* ap0 = j.A1 + (size_t)z*j.Abs + (size_t)mt0*KT1*512 + lane*8;
  const unsigned short* ap1 = j.A1 + (size_t)z*j.Abs + (size_t)mt1*KT1*512 + lane*8;
  const unsigned short* wb = j.W  + (size_t)z*j.Wbs + (size_t)(blockIdx.y*4)*KTW*512 + lane*8;
  f32x4 acc[2][4];
  #pragma unroll
  for (int m = 0; m < 2; m++)
    #pragma unroll
    for (int n = 0; n < 4; n++) acc[m][n] = (f32x4){0.f,0.f,0.f,0.f};
  #pragma unroll 4
  for (int kt = 0; kt < KT1; kt++){
    short8 a0 = *(const short8*)(ap0 + (size_t)kt*512);
    short8 a1 = *(const short8*)(ap1 + (size_t)kt*512);
    #pragma unroll
    for (int n = 0; n < 4; n++){
      short8 bv = *(const short8*)(wb + (size_t)(n*KTW + kt)*512);
      acc[0][n] = __builtin_amdgcn_mfma_f32_16x16x32_bf16(a0, bv, acc[0][n], 0, 0, 0);
      acc[1][n] = __builtin_amdgcn_mfma_f32_16x16x32_bf16(a1, bv, acc[1][n], 0, 0, 0);
    }
  }
  if (KT2 > 0){
    const unsigned short* b0p = j.A2 + (size_t)mt0*KT2*512 + lane*8;
    const unsigned short* b1p = j.A2 + (size_t)mt1*KT2*512 + lane*8;
    #pragma unroll 4
    for (int kt = 0; kt < KT2; kt++){
      short8 a0 = *(const short8*)(b0p + (size_t)kt*512);
      short8 a1 = *(const short8*)(b1p + (size_t)kt*512);
      #pragma unroll
      for (int n = 0; n < 4; n++){
        short8 bv = *(const short8*)(wb + (size_t)(n*KTW + KT1 + kt)*512);
        acc[0][n] = __builtin_amdgcn_mfma_f32_16x16x32_bf16(a0, bv, acc[0][n], 0, 0, 0);
        acc[1][n] = __builtin_amdgcn_mfma_f32_16x16x32_bf16(a1, bv, acc[1][n], 0, 0, 0);
      }
    }
  }
  int colb = blockIdx.y*64;
  #pragma unroll
  for (int m = 0; m < 2; m++)
    #pragma unroll
    for (int n = 0; n < 4; n++)
      #pragma unroll
      for (int jj = 0; jj < 4; jj++){
        int r = rb + m*16 + oct*4 + jj;
        if (r < j.M){
          int col = colb + n*16 + row16;
          float v = acc[m][n][jj];
          if (CT <= 1 && j.bias) v += j.bias[col];
          int rg = z*j.rowsPerBatch + r;
          if (CT == 2){
            ((unsigned short*)j.C)[flin_off(rg, col, 24)] = f2bf(v);
          } else if (CT == 1){
            ((unsigned short*)j.C)[(size_t)rg*768 + col] = f2h(tanhf(v));
          } else {
            ((float*)j.C)[(size_t)rg*768 + col] = v;
          }
        }
      }
}

// ---------------- K6: pool, wave-per-r (no barriers) ----------------
__global__ __launch_bounds__(256) void k_pool(const float* __restrict__ kment,
                                              const float* __restrict__ ment,
                                              const float* __restrict__ q_c,
                                              const int* __restrict__ hts,
                                              unsigned short* __restrict__ h_bf,
                                              unsigned short* __restrict__ t_bf){
  int wid = threadIdx.x >> 6, lane = threadIdx.x & 63;
  int r = blockIdx.x*4 + wid;
  int b = r / Pc;
  float q[12];
  const float* qp = q_c + (size_t)r*Dc + lane;
  #pragma unroll
  for (int u = 0; u < 12; u++) q[u] = qp[u*64];
  const float invs = 0.03608439182435161f;  // 1/sqrt(768)
  #pragma unroll
  for (int side = 0; side < 2; side++){
    int e = hts[r*2+side];
    const float* kb = kment + (size_t)(b*Ec+e)*Mc*Dc + lane;
    const float* mb = ment  + (size_t)(b*Ec+e)*Mc*Dc;   // no +lane (d below includes lane)
    float part[Mc] = {0.f,0.f,0.f,0.f};
    #pragma unroll
    for (int m = 0; m < Mc; m++)
      #pragma unroll
      for (int u = 0; u < 12; u++)
        part[m] = fmaf(kb[m*Dc + u*64], q[u], part[m]);
    #pragma unroll
    for (int m = 0; m < Mc; m++)
      #pragma unroll
      for (int off = 1; off < 64; off <<= 1)
        part[m] += __shfl_xor(part[m], off);
    float mx = fmaxf(fmaxf(part[0],part[1]), fmaxf(part[2],part[3])) * invs;
    float w0 = expf(part[0]*invs - mx), w1 = expf(part[1]*invs - mx);
    float w2 = expf(part[2]*invs - mx), w3 = expf(part[3]*invs - mx);
    float isum = 1.0f/(w0+w1+w2+w3);
    w0 *= isum; w1 *= isum; w2 *= isum; w3 *= isum;
    unsigned short* o = side ? t_bf : h_bf;
    #pragma unroll
    for (int u = 0; u < 12; u++){
      int d = lane + u*64;
      float v = w0*mb[d] + w1*mb[Dc+d] + w2*mb[2*Dc+d] + w3*mb[3*Dc+d];
      o[flin_off(r, d, 24)] = f2bf(v);
    }
  }
}

// ---------------- K8: MFMA bilinear fp16, 2 m-frags/wave, KSPL=24 (r7 config) ----------------
// grid = mb(18) x kb(24); block 4 waves x 32 rows = 128 rows
__global__ __launch_bounds__(256) void k_bilinear_mfma(
    const unsigned short* __restrict__ hs16, const unsigned short* __restrict__ ts16,
    const unsigned short* __restrict__ Wbf,
    float* __restrict__ partial)
{
  int mb = blockIdx.x / KSPL;
  int kb = blockIdx.x % KSPL;
  int k  = kb >> 1;
  int i0 = (kb & 1) * 32;

  int tid  = threadIdx.x;
  int lane = tid & 63;
  int wid  = tid >> 6;
  int row16 = lane & 15;
  int oct   = lane >> 4;

  int rbase = mb*128 + wid*32;

  __shared__ __align__(16) unsigned short Wlds[2][8960];

  f16x8 tsh[2][2];  // [m][jhalf]
  f16x8 hsh[2][4];  // [m][q], i = q*8 + e
  #pragma unroll
  for (int m = 0; m < 2; m++){
    int r = rbase + m*16 + row16; if (r > Rc-1) r = Rc-1;
    const unsigned short* tp = ts16 + (size_t)r*EMBc + k*64;
    tsh[m][0] = __builtin_bit_cast(f16x8, *(const short8*)(tp + oct*8));
    tsh[m][1] = __builtin_bit_cast(f16x8, *(const short8*)(tp + 32 + oct*8));
    const unsigned short* hp = hs16 + (size_t)r*EMBc + k*64 + i0;
    #pragma unroll
    for (int q = 0; q < 4; q++)
      hsh[m][q] = __builtin_bit_cast(f16x8, *(const short8*)(hp + q*8));
  }

  const char* wsrc = (const char*)(Wbf + ((size_t)(k*128 + i0*2))*4480);

  #pragma unroll
  for (int rr = 0; rr < 5; rr++){
    int u = tid + rr*256;
    if (u < 1120)
      __builtin_amdgcn_global_load_lds(
        (const __attribute__((address_space(1))) unsigned int*)(wsrc + (size_t)u*16),
        (__attribute__((address_space(3))) unsigned int*)((char*)&Wlds[0][0] + u*16),
        16, 0, 0);
  }

  f32x4 acc[2][7];
  #pragma unroll
  for (int m = 0; m < 2; m++)
    #pragma unroll
    for (int n = 0; n < 7; n++) acc[m][n] = (f32x4){0.f,0.f,0.f,0.f};

  __syncthreads();   // pair 0 staged

  #pragma unroll
  for (int cp = 0; cp < 32; cp++){
    int cur = cp & 1;
    if (cp < 31){
      const char* nsrc = wsrc + (size_t)(cp+1)*17920;
      #pragma unroll
      for (int rr = 0; rr < 5; rr++){
        int u = tid + rr*256;
        if (u < 1120)
          __builtin_amdgcn_global_load_lds(
            (const __attribute__((address_space(1))) unsigned int*)(nsrc + (size_t)u*16),
            (__attribute__((address_space(3))) unsigned int*)((char*)&Wlds[cur^1][0] + u*16),
            16, 0, 0);
      }
    }
    #pragma unroll
    for (int half = 0; half < 2; half++){
      f16x8 af[2];
      #pragma unroll
      for (int m = 0; m < 2; m++){
        _Float16 hv = hsh[m][cp>>3][cp&7];       // static after full unroll
        f16x8 hvb = {hv,hv,hv,hv,hv,hv,hv,hv};
        af[m] = tsh[m][half] * hvb;              // 4x v_pk_mul_f16
      }
      #pragma unroll
      for (int n = 0; n < 7; n++){
        f16x8 bfr = __builtin_bit_cast(f16x8,
            *(const short8*)&Wlds[cur][half*4480 + (n*16 + row16)*40 + oct*8]);
        acc[0][n] = __builtin_amdgcn_mfma_f32_16x16x32_f16(af[0], bfr, acc[0][n], 0, 0, 0);
        acc[1][n] = __builtin_amdgcn_mfma_f32_16x16x32_f16(af[1], bfr, acc[1][n], 0, 0, 0);
      }
    }
    __syncthreads();
  }

  float* pk = partial + (size_t)kb*Rc*NLc;
  #pragma unroll
  for (int m = 0; m < 2; m++){
    #pragma unroll
    for (int n = 0; n < 7; n++){
      #pragma unroll
      for (int j = 0; j < 4; j++){
        int r = rbase + m*16 + oct*4 + j;
        int col = n*16 + row16;
        if (r < Rc && col < NLc)
          pk[(size_t)r*NLc + col] = acc[m][n][j];
      }
    }
  }
}

// ---------------- K9: sum partials + bias ----------------
__global__ __launch_bounds__(256) void k_reduce(const float* __restrict__ partial,
                                                const float* __restrict__ bilb,
                                                float* __restrict__ out){
  int idx = blockIdx.x*256 + threadIdx.x;
  if (idx >= Rc*NLc) return;
  int n = idx % NLc;
  float s = bilb[n];
  #pragma unroll
  for (int ks = 0; ks < KSPL; ks++) s += partial[(size_t)ks*Rc*NLc + idx];
  out[idx] = s;
}

extern "C" void kernel_launch(void* const* d_in, const int* in_sizes, int n_in,
                              void* d_out, int out_size, void* d_ws, size_t ws_size,
                              hipStream_t stream){
  const float* seq   = (const float*)d_in[0];
  const float* att   = (const float*)d_in[1];
  const float* W_q   = (const float*)d_in[2];
  const float* W_k   = (const float*)d_in[3];
  const float* headW = (const float*)d_in[4];
  const float* headb = (const float*)d_in[5];
  const float* tailW = (const float*)d_in[6];
  const float* tailb = (const float*)d_in[7];
  const float* bilW  = (const float*)d_in[8];
  const float* bilb  = (const float*)d_in[9];
  const int*   mpos  = (const int*)d_in[10];
  const int*   hts   = (const int*)d_in[11];
  float* out = (float*)d_out;

  float* ws = (float*)d_ws;
  float* ent_att = ws;                                      // 1,179,648 f
  float* q_c     = ws + 1179648;                            // 1,695,744 f
  float* kment   = q_c + 1695744;                           //   294,912 f
  float* ment    = kment + 294912;                          //   294,912 f
  unsigned short* seqf    = (unsigned short*)(ment + 294912);   // 3,145,728 sh
  unsigned short* htbf    = seqf + 3145728;                     // 2,293,760 sh
  unsigned short* rs_bf   = htbf + 4*HT_ABS;                    // 1,695,744 sh
  unsigned short* ment_bf = rs_bf + 1695744;                    //   294,912 sh
  unsigned short* h_bf    = ment_bf + 294912;                   // 1,695,744 sh
  unsigned short* t_bf    = h_bf + 1695744;                     // 1,695,744 sh
  unsigned short* Wq_f    = t_bf + 1695744;                     //   589,824 sh
  unsigned short* Wk_f    = Wq_f + 589824;                      //   589,824 sh
  unsigned short* headW_f = Wk_f + 589824;                      // 1,179,648 sh
  unsigned short* tailW_f = headW_f + 1179648;                  // 1,179,648 sh
  unsigned short* hs16 = tailW_f + 1179648;                 // 1,695,744 sh (fp16 row-major)
  unsigned short* ts16 = hs16 + 1695744;                    // 1,695,744 sh
  unsigned short* Wbf  = ts16 + 1695744;                    // 6,881,280 sh (fp16)
  float* partial = ws;   // 24*2208*97 = 5,140,224 f, overlaps dead prefix region

  k_prep   <<<4320, 256, 0, stream>>>(bilW, Wbf, seq, seqf, W_q, Wq_f, W_k, Wk_f,
                                      headW, headW_f, tailW, tailW_f,
                                      att, mpos, ent_att, ment, ment_bf);
  k_ht_att <<<4*560, 256, 0, stream>>>(ent_att, hts, htbf);
  {
    FJob jrs = { htbf, nullptr, seqf, nullptr, rs_bf, Pc, 35,
                 (size_t)HT_ABS, (size_t)(48*32*512), Pc };
    k_fgemm<32,0,2><<<dim3(5,12,4), 256, 0, stream>>>(jrs, jrs, 5);
  }
  {
    FJob jq = { rs_bf,   nullptr, Wq_f, nullptr, q_c,   Rc,       138, 0, 0, 0 };
    FJob jk = { ment_bf, nullptr, Wk_f, nullptr, kment, Bc*Ec*Mc,  24, 0, 0, 0 };
    k_fgemm<24,0,0><<<dim3(21,12), 256, 0, stream>>>(jq, jk, 18);
  }
  k_pool   <<<Rc/4, 256, 0, stream>>>(kment, ment, q_c, hts, h_bf, t_bf);
  {
    FJob jh = { h_bf, rs_bf, headW_f, headb, hs16, Rc, 138, 0, 0, 0 };
    FJob jt = { t_bf, rs_bf, tailW_f, tailb, ts16, Rc, 138, 0, 0, 0 };
    k_fgemm<24,24,1><<<dim3(36,12), 256, 0, stream>>>(jh, jt, 18);
  }
  k_bilinear_mfma<<<18*KSPL, 256, 0, stream>>>(hs16, ts16, Wbf, partial);
  k_reduce <<<(Rc*NLc+255)/256, 256, 0, stream>>>(partial, bilb, out);
}

// Round 11
// 164.632 us; speedup vs baseline: 1.3074x; 1.0461x over previous
//
#include <hip/hip_runtime.h>
#include <hip/hip_bf16.h>
#include <math.h>

#define Bc 4
#define Lc 1024
#define Dc 768
#define Hc 12
#define Ec 24
#define Mc 4
#define Pc 552
#define EMBc 768
#define NLc 97
#define Rc (Bc*Pc)      // 2208
#define KSPL 48         // bilinear: 12 k-blocks x 4 i-splits of 16
#define HT_ABS (35*32*512)   // htbf flin per-batch stride (shorts)

typedef __attribute__((ext_vector_type(4))) float f32x4;
typedef __attribute__((ext_vector_type(8))) short short8;
typedef __attribute__((ext_vector_type(4))) unsigned short us4;
typedef _Float16 f16x8 __attribute__((ext_vector_type(8)));

static __device__ __forceinline__ unsigned short f2bf(float x){
  unsigned int u = __float_as_uint(x);
  unsigned int r = u + 0x7fffu + ((u >> 16) & 1u);   // RNE
  return (unsigned short)(r >> 16);
}
static __device__ __forceinline__ unsigned short f2h(float x){
  _Float16 h = (_Float16)x;
  return __builtin_bit_cast(unsigned short, h);
}
static __device__ __forceinline__ float h2f(unsigned short x){
  return (float)__builtin_bit_cast(_Float16, x);
}
// flin index: row r, k-index kk, KT = K/32 chunks
static __device__ __forceinline__ size_t flin_off(int r, int kk, int KT){
  return ((size_t)(r>>4)*KT + (kk>>5))*512 + (size_t)((((kk&31)>>3)*16 + (r&15))*8) + (kk&7);
}

// ---------------- K0: weight prep + ent_att + mention gather (one launch) ----------------
__global__ __launch_bounds__(256) void k_prep(const float* __restrict__ bilW, unsigned short* __restrict__ Wbf,
                                              const float* __restrict__ seq, unsigned short* __restrict__ seqf,
                                              const float* __restrict__ W_q, unsigned short* __restrict__ Wq_f,
                                              const float* __restrict__ W_k, unsigned short* __restrict__ Wk_f,
                                              const float* __restrict__ headW, unsigned short* __restrict__ headW_f,
                                              const float* __restrict__ tailW, unsigned short* __restrict__ tailW_f,
                                              const float* __restrict__ att, const int* __restrict__ mpos,
                                              float* __restrict__ ent_att,
                                              float* __restrict__ ment, unsigned short* __restrict__ ment_bf){
  int bx = blockIdx.x;
  int tid = threadIdx.x;
  if (bx < 1536){
    const float* Ws = bilW + (size_t)bx*32*NLc;
    unsigned short* o = Wbf + (size_t)bx*4480;
    for (int idx = tid; idx < 112*32; idx += 256){
      int n = idx % 112, kk = idx / 112;
      float v = (n < NLc) ? Ws[(size_t)kk*NLc + n] : 0.f;
      o[n*40 + kk] = f2h(v);
    }
    return;
  }
  if (bx >= 3168){                  // ent_att + gather
    int blk = bx - 3168;            // (b*E+e)*H + h, 1152 blocks
    int h  = blk % Hc;
    int be = blk / Hc;
    int b  = be / Ec;
    int p0 = mpos[be*Mc+0]+1, p1 = mpos[be*Mc+1]+1;
    int p2 = mpos[be*Mc+2]+1, p3 = mpos[be*Mc+3]+1;
    const float* ab = att + ((size_t)b*Hc + h)*Lc*Lc;
    const float* a0 = ab + (size_t)p0*Lc;
    const float* a1 = ab + (size_t)p1*Lc;
    const float* a2 = ab + (size_t)p2*Lc;
    const float* a3 = ab + (size_t)p3*Lc;
    float* o = ent_att + (size_t)blk*Lc;
    for (int l = tid; l < Lc; l += 256)
      o[l] = 0.25f*(a0[l]+a1[l]+a2[l]+a3[l]);
    int gidx = blk*256 + tid;       // over B*E*M*D
    int d = gidx % Dc;
    int bem = gidx / Dc;
    int bb = bem / (Ec*Mc);
    int pos = mpos[bem] + 1;
    float v = seq[((size_t)bb*Lc + pos)*Dc + d];
    ment[gidx] = v;
    ment_bf[flin_off(bem, d, 24)] = f2bf(v);
    return;
  }
  bx -= 1536;
  const float* src; unsigned short* dst; int tk, tn, KTW;
  if (bx < 768){                     // seq [1024x768] x4 -> flin KTW=32
    int z = bx / 192, rem = bx % 192;
    src = seq + (size_t)z*Lc*Dc; dst = seqf + (size_t)z*(Dc/16)*(Lc/32)*512;
    tk = rem % 16; tn = rem / 16; KTW = 32;
  } else if (bx < 768+144){
    int rem = bx - 768;
    src = W_q; dst = Wq_f; tk = rem % 12; tn = rem / 12; KTW = 24;
  } else if (bx < 768+288){
    int rem = bx - (768+144);
    src = W_k; dst = Wk_f; tk = rem % 12; tn = rem / 12; KTW = 24;
  } else if (bx < 768+288+288){
    int rem = bx - (768+288);
    src = headW; dst = headW_f; tk = rem % 24; tn = rem / 24; KTW = 48;
  } else {
    int rem = bx - (768+288+288);
    src = tailW; dst = tailW_f; tk = rem % 24; tn = rem / 24; KTW = 48;
  }
  int r0 = tk*64, c0 = tn*64;       // r0 along K, c0 along N(=768)
  __shared__ float t[64][65];
  #pragma unroll
  for (int q8 = 0; q8 < 16; q8++){
    int idx = q8*256 + tid;
    int rr = idx >> 6, cc = idx & 63;
    t[rr][cc] = src[(size_t)(r0+rr)*768 + c0+cc];
  }
  __syncthreads();
  #pragma unroll
  for (int q8 = 0; q8 < 16; q8++){
    int idx = q8*256 + tid;
    int li = idx & 511, sub = idx >> 9;
    int nt_l = sub >> 1, kt_l = sub & 1;
    int lane = li >> 3, e = li & 7;
    int kl = kt_l*32 + (lane>>4)*8 + e;
    int nl = nt_l*16 + (lane&15);
    dst[ ((size_t)(c0/16 + nt_l)*KTW + (r0/32 + kt_l))*512 + li ] = f2bf(t[kl][nl]);
  }
}

// ---------------- K2: ht_att -> bf16 flin (zero pad rows 552..559) ----------------
__global__ __launch_bounds__(256) void k_ht_att(const float* __restrict__ ent_att,
                                                const int* __restrict__ hts,
                                                unsigned short* __restrict__ htbf){
  int b = blockIdx.x & 3;
  int p = blockIdx.x >> 2;          // 0..559
  unsigned short* o = htbf + (size_t)b*HT_ABS;
  int l4 = threadIdx.x*4;
  if (p >= Pc){
    us4 z4 = {0,0,0,0};
    *(us4*)(o + flin_off(p, l4, 32)) = z4;
    return;
  }
  int r = b*Pc + p;
  int hi = hts[r*2+0], ti = hts[r*2+1];
  const float* eh = ent_att + (size_t)(b*Ec+hi)*Hc*Lc;
  const float* et = ent_att + (size_t)(b*Ec+ti)*Hc*Lc;
  __shared__ float raw[Lc];
  __shared__ float wsum[4];
  float4 s4 = {0.f,0.f,0.f,0.f};
  #pragma unroll
  for (int h = 0; h < Hc; h++){
    float4 e1 = *(const float4*)&eh[h*Lc + l4];
    float4 e2 = *(const float4*)&et[h*Lc + l4];
    s4.x = fmaf(e1.x,e2.x,s4.x); s4.y = fmaf(e1.y,e2.y,s4.y);
    s4.z = fmaf(e1.z,e2.z,s4.z); s4.w = fmaf(e1.w,e2.w,s4.w);
  }
  s4.x *= (1.0f/Hc); s4.y *= (1.0f/Hc); s4.z *= (1.0f/Hc); s4.w *= (1.0f/Hc);
  *(float4*)&raw[l4] = s4;
  float lsum = s4.x+s4.y+s4.z+s4.w;
  for (int off = 32; off; off >>= 1) lsum += __shfl_down(lsum, off);
  if ((threadIdx.x & 63) == 0) wsum[threadIdx.x>>6] = lsum;
  __syncthreads();
  float inv = 1.0f/(wsum[0]+wsum[1]+wsum[2]+wsum[3] + 1e-5f);
  float4 rv = *(const float4*)&raw[l4];
  us4 v4;
  v4[0] = f2bf(rv.x*inv); v4[1] = f2bf(rv.y*inv);
  v4[2] = f2bf(rv.z*inv); v4[3] = f2bf(rv.w*inv);
  *(us4*)(o + flin_off(p, l4, 32)) = v4;
}

// ---------------- K4: flin MFMA GEMM, 2 m-frags x NT n-tiles per wave ----------------
struct FJob {
  const unsigned short* A1; const unsigned short* A2;
  const unsigned short* W;  const float* bias; void* C;
  int M; int mtmax; size_t Abs; size_t Wbs; int rowsPerBatch;
};

// CT: 0 = fp32 (+bias), 1 = fp32+bias+tanh -> fp16 row-major, 2 = bf16 flin (KTC=24)
template<int KT1, int KT2, int CT, int NT>
__global__ __launch_bounds__(256) void k_fgemm(FJob j0, FJob j1, int nx0){
  FJob j = (blockIdx.x < nx0) ? j0 : j1;
  int mbx = (blockIdx.x < nx0) ? blockIdx.x : blockIdx.x - nx0;
  const int KTW = KT1 + KT2;
  int z = blockIdx.z;
  int lane = threadIdx.x & 63, wid = threadIdx.x >> 6;
  int row16 = lane & 15, oct = lane >> 4;
  int rb = mbx*128 + wid*32;
  int mt0 = rb >> 4;       if (mt0 >= j.mtmax) mt0 = j.mtmax - 1;
  int mt1 = (rb >> 4) + 1; if (mt1 >= j.mtmax) mt1 = j.mtmax - 1;
  const unsigned short* ap0 = j.A1 + (size_t)z*j.Abs + (size_t)mt0*KT1*512 + lane*8;
  const unsigned short* ap1 = j.A1 + (size_t)z*j.Abs + (size_t)mt1*KT1*512 + lane*8;
  const unsigned short* wb = j.W  + (size_t)z*j.Wbs + (size_t)(blockIdx.y*NT)*KTW*512 + lane*8;
  f32x4 acc[2][NT];
  #pragma unroll
  for (int m = 0; m < 2; m++)
    #pragma unroll
    for (int n = 0; n < NT; n++) acc[m][n] = (f32x4){0.f,0.f,0.f,0.f};
  #pragma unroll 4
  for (int kt = 0; kt < KT1; kt++){
    short8 a0 = *(const short8*)(ap0 + (size_t)kt*512);
    short8 a1 = *(const short8*)(ap1 + (size_t)kt*512);
    #pragma unroll
    for (int n = 0; n < NT; n++){
      short8 bv = *(const short8*)(wb + (size_t)(n*KTW + kt)*512);
      acc[0][n] = __builtin_amdgcn_mfma_f32_16x16x32_bf16(a0, bv, acc[0][n], 0, 0, 0);
      acc[1][n] = __builtin_amdgcn_mfma_f32_16x16x32_bf16(a1, bv, acc[1][n], 0, 0, 0);
    }
  }
  if (KT2 > 0){
    const unsigned short* b0p = j.A2 + (size_t)mt0*KT2*512 + lane*8;
    const unsigned short* b1p = j.A2 + (size_t)mt1*KT2*512 + lane*8;
    #pragma unroll 4
    for (int kt = 0; kt < KT2; kt++){
      short8 a0 = *(const short8*)(b0p + (size_t)kt*512);
      short8 a1 = *(const short8*)(b1p + (size_t)kt*512);
      #pragma unroll
      for (int n = 0; n < NT; n++){
        short8 bv = *(const short8*)(wb + (size_t)(n*KTW + KT1 + kt)*512);
        acc[0][n] = __builtin_amdgcn_mfma_f32_16x16x32_bf16(a0, bv, acc[0][n], 0, 0, 0);
        acc[1][n] = __builtin_amdgcn_mfma_f32_16x16x32_bf16(a1, bv, acc[1][n], 0, 0, 0);
      }
    }
  }
  int colb = blockIdx.y*(NT*16);
  #pragma unroll
  for (int m = 0; m < 2; m++)
    #pragma unroll
    for (int n = 0; n < NT; n++)
      #pragma unroll
      for (int jj = 0; jj < 4; jj++){
        int r = rb + m*16 + oct*4 + jj;
        if (r < j.M){
          int col = colb + n*16 + row16;
          float v = acc[m][n][jj];
          if (CT <= 1 && j.bias) v += j.bias[col];
          int rg = z*j.rowsPerBatch + r;
          if (CT == 2){
            ((unsigned short*)j.C)[flin_off(rg, col, 24)] = f2bf(v);
          } else if (CT == 1){
            ((unsigned short*)j.C)[(size_t)rg*768 + col] = f2h(tanhf(v));
          } else {
            ((float*)j.C)[(size_t)rg*768 + col] = v;
          }
        }
      }
}

// ---------------- K6: pool, wave-per-r (no barriers) ----------------
__global__ __launch_bounds__(256) void k_pool(const float* __restrict__ kment,
                                              const float* __restrict__ ment,
                                              const float* __restrict__ q_c,
                                              const int* __restrict__ hts,
                                              unsigned short* __restrict__ h_bf,
                                              unsigned short* __restrict__ t_bf){
  int wid = threadIdx.x >> 6, lane = threadIdx.x & 63;
  int r = blockIdx.x*4 + wid;
  int b = r / Pc;
  float q[12];
  const float* qp = q_c + (size_t)r*Dc + lane;
  #pragma unroll
  for (int u = 0; u < 12; u++) q[u] = qp[u*64];
  const float invs = 0.03608439182435161f;  // 1/sqrt(768)
  #pragma unroll
  for (int side = 0; side < 2; side++){
    int e = hts[r*2+side];
    const float* kb = kment + (size_t)(b*Ec+e)*Mc*Dc + lane;
    const float* mb = ment  + (size_t)(b*Ec+e)*Mc*Dc;   // no +lane (d below includes lane)
    float part[Mc] = {0.f,0.f,0.f,0.f};
    #pragma unroll
    for (int m = 0; m < Mc; m++)
      #pragma unroll
      for (int u = 0; u < 12; u++)
        part[m] = fmaf(kb[m*Dc + u*64], q[u], part[m]);
    #pragma unroll
    for (int m = 0; m < Mc; m++)
      #pragma unroll
      for (int off = 1; off < 64; off <<= 1)
        part[m] += __shfl_xor(part[m], off);
    float mx = fmaxf(fmaxf(part[0],part[1]), fmaxf(part[2],part[3])) * invs;
    float w0 = expf(part[0]*invs - mx), w1 = expf(part[1]*invs - mx);
    float w2 = expf(part[2]*invs - mx), w3 = expf(part[3]*invs - mx);
    float isum = 1.0f/(w0+w1+w2+w3);
    w0 *= isum; w1 *= isum; w2 *= isum; w3 *= isum;
    unsigned short* o = side ? t_bf : h_bf;
    #pragma unroll
    for (int u = 0; u < 12; u++){
      int d = lane + u*64;
      float v = w0*mb[d] + w1*mb[Dc+d] + w2*mb[2*Dc+d] + w3*mb[3*Dc+d];
      o[flin_off(r, d, 24)] = f2bf(v);
    }
  }
}

// ---------------- K8: MFMA bilinear fp16, 4 m-frags/wave, KSPL=48, fp16 partial ----------------
// grid = mb(9) x kb(48); block 4 waves x 64 rows = 256 rows (r9-validated structure)
__global__ __launch_bounds__(256) void k_bilinear_mfma(
    const unsigned short* __restrict__ hs16, const unsigned short* __restrict__ ts16,
    const unsigned short* __restrict__ Wbf,
    unsigned short* __restrict__ partial)
{
  int mb = blockIdx.x / KSPL;
  int kb = blockIdx.x % KSPL;
  int k  = kb >> 2;             // EMB block 0..11
  int i0 = (kb & 3) * 16;       // i sub-range (16 wide)

  int tid  = threadIdx.x;
  int lane = tid & 63;
  int wid  = tid >> 6;
  int row16 = lane & 15;
  int oct   = lane >> 4;

  int rbase = mb*256 + wid*64;

  __shared__ __align__(16) unsigned short Wlds[2][8960];

  f16x8 tsh[4][2];  // [m][jhalf]
  f16x8 hsh[4][2];  // [m][q], i = q*8 + e  (16 i-values)
  #pragma unroll
  for (int m = 0; m < 4; m++){
    int r = rbase + m*16 + row16; if (r > Rc-1) r = Rc-1;
    const unsigned short* tp = ts16 + (size_t)r*EMBc + k*64;
    tsh[m][0] = __builtin_bit_cast(f16x8, *(const short8*)(tp + oct*8));
    tsh[m][1] = __builtin_bit_cast(f16x8, *(const short8*)(tp + 32 + oct*8));
    const unsigned short* hp = hs16 + (size_t)r*EMBc + k*64 + i0;
    hsh[m][0] = __builtin_bit_cast(f16x8, *(const short8*)(hp));
    hsh[m][1] = __builtin_bit_cast(f16x8, *(const short8*)(hp + 8));
  }

  const char* wsrc = (const char*)(Wbf + ((size_t)(k*128 + i0*2))*4480);

  #pragma unroll
  for (int rr = 0; rr < 5; rr++){
    int u = tid + rr*256;
    if (u < 1120)
      __builtin_amdgcn_global_load_lds(
        (const __attribute__((address_space(1))) unsigned int*)(wsrc + (size_t)u*16),
        (__attribute__((address_space(3))) unsigned int*)((char*)&Wlds[0][0] + u*16),
        16, 0, 0);
  }

  f32x4 acc[4][7];
  #pragma unroll
  for (int m = 0; m < 4; m++)
    #pragma unroll
    for (int n = 0; n < 7; n++) acc[m][n] = (f32x4){0.f,0.f,0.f,0.f};

  __syncthreads();   // pair 0 staged

  #pragma unroll
  for (int cp = 0; cp < 16; cp++){    // pair cp = chunks (i=cp, jh=0/1)
    int cur = cp & 1;
    if (cp < 15){
      const char* nsrc = wsrc + (size_t)(cp+1)*17920;
      #pragma unroll
      for (int rr = 0; rr < 5; rr++){
        int u = tid + rr*256;
        if (u < 1120)
          __builtin_amdgcn_global_load_lds(
            (const __attribute__((address_space(1))) unsigned int*)(nsrc + (size_t)u*16),
            (__attribute__((address_space(3))) unsigned int*)((char*)&Wlds[cur^1][0] + u*16),
            16, 0, 0);
      }
    }
    #pragma unroll
    for (int half = 0; half < 2; half++){
      f16x8 af[4];
      #pragma unroll
      for (int m = 0; m < 4; m++){
        _Float16 hv = hsh[m][cp>>3][cp&7];       // static after full unroll
        f16x8 hvb = {hv,hv,hv,hv,hv,hv,hv,hv};
        af[m] = tsh[m][half] * hvb;              // 4x v_pk_mul_f16
      }
      #pragma unroll
      for (int n = 0; n < 7; n++){
        f16x8 bfr = __builtin_bit_cast(f16x8,
            *(const short8*)&Wlds[cur][half*4480 + (n*16 + row16)*40 + oct*8]);
        #pragma unroll
        for (int m = 0; m < 4; m++)
          acc[m][n] = __builtin_amdgcn_mfma_f32_16x16x32_f16(af[m], bfr, acc[m][n], 0, 0, 0);
      }
    }
    __syncthreads();
  }

  unsigned short* pk = partial + (size_t)kb*Rc*NLc;
  #pragma unroll
  for (int m = 0; m < 4; m++){
    #pragma unroll
    for (int n = 0; n < 7; n++){
      #pragma unroll
      for (int j = 0; j < 4; j++){
        int r = rbase + m*16 + oct*4 + j;
        int col = n*16 + row16;
        if (r < Rc && col < NLc)
          pk[(size_t)r*NLc + col] = f2h(acc[m][n][j]);
      }
    }
  }
}

// ---------------- K9: sum fp16 partials + bias ----------------
__global__ __launch_bounds__(256) void k_reduce(const unsigned short* __restrict__ partial,
                                                const float* __restrict__ bilb,
                                                float* __restrict__ out){
  int idx = blockIdx.x*256 + threadIdx.x;
  if (idx >= Rc*NLc) return;
  int n = idx % NLc;
  float s = bilb[n];
  #pragma unroll
  for (int ks = 0; ks < KSPL; ks++) s += h2f(partial[(size_t)ks*Rc*NLc + idx]);
  out[idx] = s;
}

extern "C" void kernel_launch(void* const* d_in, const int* in_sizes, int n_in,
                              void* d_out, int out_size, void* d_ws, size_t ws_size,
                              hipStream_t stream){
  const float* seq   = (const float*)d_in[0];
  const float* att   = (const float*)d_in[1];
  const float* W_q   = (const float*)d_in[2];
  const float* W_k   = (const float*)d_in[3];
  const float* headW = (const float*)d_in[4];
  const float* headb = (const float*)d_in[5];
  const float* tailW = (const float*)d_in[6];
  const float* tailb = (const float*)d_in[7];
  const float* bilW  = (const float*)d_in[8];
  const float* bilb  = (const float*)d_in[9];
  const int*   mpos  = (const int*)d_in[10];
  const int*   hts   = (const int*)d_in[11];
  float* out = (float*)d_out;

  float* ws = (float*)d_ws;
  float* ent_att = ws;                                      // 1,179,648 f
  float* q_c     = ws + 1179648;                            // 1,695,744 f
  float* kment   = q_c + 1695744;                           //   294,912 f
  float* ment    = kment + 294912;                          //   294,912 f
  unsigned short* seqf    = (unsigned short*)(ment + 294912);   // 3,145,728 sh
  unsigned short* htbf    = seqf + 3145728;                     // 2,293,760 sh
  unsigned short* rs_bf   = htbf + 4*HT_ABS;                    // 1,695,744 sh
  unsigned short* ment_bf = rs_bf + 1695744;                    //   294,912 sh
  unsigned short* h_bf    = ment_bf + 294912;                   // 1,695,744 sh
  unsigned short* t_bf    = h_bf + 1695744;                     // 1,695,744 sh
  unsigned short* Wq_f    = t_bf + 1695744;                     //   589,824 sh
  unsigned short* Wk_f    = Wq_f + 589824;                      //   589,824 sh
  unsigned short* headW_f = Wk_f + 589824;                      // 1,179,648 sh
  unsigned short* tailW_f = headW_f + 1179648;                  // 1,179,648 sh
  unsigned short* hs16 = tailW_f + 1179648;                 // 1,695,744 sh (fp16 row-major)
  unsigned short* ts16 = hs16 + 1695744;                    // 1,695,744 sh
  unsigned short* Wbf  = ts16 + 1695744;                    // 6,881,280 sh (fp16)
  unsigned short* partial = (unsigned short*)ws;
  // fp16 partial: 48*2208*97 = 10,280,448 sh = 20.6 MB; prefix region (ent_att..tailW_f,
  // all dead before the bilinear) spans ~42 MB: safe.

  k_prep   <<<4320, 256, 0, stream>>>(bilW, Wbf, seq, seqf, W_q, Wq_f, W_k, Wk_f,
                                      headW, headW_f, tailW, tailW_f,
                                      att, mpos, ent_att, ment, ment_bf);
  k_ht_att <<<4*560, 256, 0, stream>>>(ent_att, hts, htbf);
  {
    FJob jrs = { htbf, nullptr, seqf, nullptr, rs_bf, Pc, 35,
                 (size_t)HT_ABS, (size_t)(48*32*512), Pc };
    k_fgemm<32,0,2,2><<<dim3(5,24,4), 256, 0, stream>>>(jrs, jrs, 5);
  }
  {
    FJob jq = { rs_bf,   nullptr, Wq_f, nullptr, q_c,   Rc,       138, 0, 0, 0 };
    FJob jk = { ment_bf, nullptr, Wk_f, nullptr, kment, Bc*Ec*Mc,  24, 0, 0, 0 };
    k_fgemm<24,0,0,2><<<dim3(21,24), 256, 0, stream>>>(jq, jk, 18);
  }
  k_pool   <<<Rc/4, 256, 0, stream>>>(kment, ment, q_c, hts, h_bf, t_bf);
  {
    FJob jh = { h_bf, rs_bf, headW_f, headb, hs16, Rc, 138, 0, 0, 0 };
    FJob jt = { t_bf, rs_bf, tailW_f, tailb, ts16, Rc, 138, 0, 0, 0 };
    k_fgemm<24,24,1,2><<<dim3(36,24), 256, 0, stream>>>(jh, jt, 18);
  }
  k_bilinear_mfma<<<9*KSPL, 256, 0, stream>>>(hs16, ts16, Wbf, partial);
  k_reduce <<<(Rc*NLc+255)/256, 256, 0, stream>>>(partial, bilb, out);
}

// Round 12
// 146.580 us; speedup vs baseline: 1.4685x; 1.1232x over previous
//
#include <hip/hip_runtime.h>
#include <hip/hip_bf16.h>
#include <math.h>

#define Bc 4
#define Lc 1024
#define Dc 768
#define Hc 12
#define Ec 24
#define Mc 4
#define Pc 552
#define EMBc 768
#define NLc 97
#define Rc (Bc*Pc)      // 2208
#define KSPL 48         // bilinear: 12 k-blocks x 4 i-splits of 16
#define HT_ABS (35*32*512)   // htbf flin per-batch stride (shorts)

typedef __attribute__((ext_vector_type(4))) float f32x4;
typedef __attribute__((ext_vector_type(8))) short short8;
typedef __attribute__((ext_vector_type(4))) unsigned short us4;
typedef _Float16 f16x8 __attribute__((ext_vector_type(8)));

static __device__ __forceinline__ unsigned short f2bf(float x){
  unsigned int u = __float_as_uint(x);
  unsigned int r = u + 0x7fffu + ((u >> 16) & 1u);   // RNE
  return (unsigned short)(r >> 16);
}
static __device__ __forceinline__ unsigned short f2h(float x){
  _Float16 h = (_Float16)x;
  return __builtin_bit_cast(unsigned short, h);
}
static __device__ __forceinline__ float h2f(unsigned short x){
  return (float)__builtin_bit_cast(_Float16, x);
}
// flin index: row r, k-index kk, KT = K/32 chunks
static __device__ __forceinline__ size_t flin_off(int r, int kk, int KT){
  return ((size_t)(r>>4)*KT + (kk>>5))*512 + (size_t)((((kk&31)>>3)*16 + (r&15))*8) + (kk&7);
}

// ---------------- K0: weight prep + ent_att + mention gather (one launch) ----------------
__global__ __launch_bounds__(256) void k_prep(const float* __restrict__ bilW, unsigned short* __restrict__ Wbf,
                                              const float* __restrict__ seq, unsigned short* __restrict__ seqf,
                                              const float* __restrict__ W_q, unsigned short* __restrict__ Wq_f,
                                              const float* __restrict__ W_k, unsigned short* __restrict__ Wk_f,
                                              const float* __restrict__ headW, unsigned short* __restrict__ headW_f,
                                              const float* __restrict__ tailW, unsigned short* __restrict__ tailW_f,
                                              const float* __restrict__ att, const int* __restrict__ mpos,
                                              float* __restrict__ ent_att,
                                              float* __restrict__ ment, unsigned short* __restrict__ ment_bf){
  int bx = blockIdx.x;
  int tid = threadIdx.x;
  __shared__ float t[64][65];     // shared by both transpose path and bilW path (aliased)
  if (bx < 1536){
    // bilW chunk -> fp16 [n=112][kk=40], LDS-staged for coalesced R and W.
    const float* Ws = bilW + (size_t)bx*32*NLc;   // 3104 contiguous floats
    unsigned short* o = Wbf + (size_t)bx*4480;
    float* w = &t[0][0];                          // 3104 <= 4160
    for (int idx = tid; idx < 32*NLc; idx += 256)
      w[idx] = Ws[idx];                           // flat, fully coalesced
    __syncthreads();
    #pragma unroll
    for (int q8 = 0; q8 < 18; q8++){
      int idx = q8*256 + tid;
      if (idx < 4480){
        int n = idx / 40, kk = idx - n*40;
        float v = (kk < 32 && n < NLc) ? w[kk*NLc + n] : 0.f;  // banks conflict-free (97%32==1)
        o[idx] = f2h(v);                          // thread-linear: fully coalesced
      }
    }
    return;
  }
  if (bx >= 3168){                  // ent_att + gather
    int blk = bx - 3168;            // (b*E+e)*H + h, 1152 blocks
    int h  = blk % Hc;
    int be = blk / Hc;
    int b  = be / Ec;
    int p0 = mpos[be*Mc+0]+1, p1 = mpos[be*Mc+1]+1;
    int p2 = mpos[be*Mc+2]+1, p3 = mpos[be*Mc+3]+1;
    const float* ab = att + ((size_t)b*Hc + h)*Lc*Lc;
    const float* a0 = ab + (size_t)p0*Lc;
    const float* a1 = ab + (size_t)p1*Lc;
    const float* a2 = ab + (size_t)p2*Lc;
    const float* a3 = ab + (size_t)p3*Lc;
    float* o = ent_att + (size_t)blk*Lc;
    int l4 = tid*4;                 // 256*4 == Lc
    float4 v0 = *(const float4*)(a0 + l4);
    float4 v1 = *(const float4*)(a1 + l4);
    float4 v2 = *(const float4*)(a2 + l4);
    float4 v3 = *(const float4*)(a3 + l4);
    float4 ov;
    ov.x = 0.25f*(v0.x+v1.x+v2.x+v3.x);
    ov.y = 0.25f*(v0.y+v1.y+v2.y+v3.y);
    ov.z = 0.25f*(v0.z+v1.z+v2.z+v3.z);
    ov.w = 0.25f*(v0.w+v1.w+v2.w+v3.w);
    *(float4*)(o + l4) = ov;
    int gidx = blk*256 + tid;       // over B*E*M*D
    int d = gidx % Dc;
    int bem = gidx / Dc;
    int bb = bem / (Ec*Mc);
    int pos = mpos[bem] + 1;
    float v = seq[((size_t)bb*Lc + pos)*Dc + d];
    ment[gidx] = v;
    ment_bf[flin_off(bem, d, 24)] = f2bf(v);
    return;
  }
  bx -= 1536;
  const float* src; unsigned short* dst; int tk, tn, KTW;
  if (bx < 768){                     // seq [1024x768] x4 -> flin KTW=32
    int z = bx / 192, rem = bx % 192;
    src = seq + (size_t)z*Lc*Dc; dst = seqf + (size_t)z*(Dc/16)*(Lc/32)*512;
    tk = rem % 16; tn = rem / 16; KTW = 32;
  } else if (bx < 768+144){
    int rem = bx - 768;
    src = W_q; dst = Wq_f; tk = rem % 12; tn = rem / 12; KTW = 24;
  } else if (bx < 768+288){
    int rem = bx - (768+144);
    src = W_k; dst = Wk_f; tk = rem % 12; tn = rem / 12; KTW = 24;
  } else if (bx < 768+288+288){
    int rem = bx - (768+288);
    src = headW; dst = headW_f; tk = rem % 24; tn = rem / 24; KTW = 48;
  } else {
    int rem = bx - (768+288+288);
    src = tailW; dst = tailW_f; tk = rem % 24; tn = rem / 24; KTW = 48;
  }
  int r0 = tk*64, c0 = tn*64;       // r0 along K, c0 along N(=768)
  #pragma unroll
  for (int q8 = 0; q8 < 16; q8++){
    int idx = q8*256 + tid;
    int rr = idx >> 6, cc = idx & 63;
    t[rr][cc] = src[(size_t)(r0+rr)*768 + c0+cc];
  }
  __syncthreads();
  #pragma unroll
  for (int q8 = 0; q8 < 16; q8++){
    int idx = q8*256 + tid;
    int li = idx & 511, sub = idx >> 9;
    int nt_l = sub >> 1, kt_l = sub & 1;
    int lane = li >> 3, e = li & 7;
    int kl = kt_l*32 + (lane>>4)*8 + e;
    int nl = nt_l*16 + (lane&15);
    dst[ ((size_t)(c0/16 + nt_l)*KTW + (r0/32 + kt_l))*512 + li ] = f2bf(t[kl][nl]);
  }
}

// ---------------- K2: ht_att -> bf16 flin (zero pad rows 552..559) ----------------
__global__ __launch_bounds__(256) void k_ht_att(const float* __restrict__ ent_att,
                                                const int* __restrict__ hts,
                                                unsigned short* __restrict__ htbf){
  int b = blockIdx.x & 3;
  int p = blockIdx.x >> 2;          // 0..559
  unsigned short* o = htbf + (size_t)b*HT_ABS;
  int l4 = threadIdx.x*4;
  if (p >= Pc){
    us4 z4 = {0,0,0,0};
    *(us4*)(o + flin_off(p, l4, 32)) = z4;
    return;
  }
  int r = b*Pc + p;
  int hi = hts[r*2+0], ti = hts[r*2+1];
  const float* eh = ent_att + (size_t)(b*Ec+hi)*Hc*Lc;
  const float* et = ent_att + (size_t)(b*Ec+ti)*Hc*Lc;
  __shared__ float raw[Lc];
  __shared__ float wsum[4];
  float4 s4 = {0.f,0.f,0.f,0.f};
  #pragma unroll
  for (int h = 0; h < Hc; h++){
    float4 e1 = *(const float4*)&eh[h*Lc + l4];
    float4 e2 = *(const float4*)&et[h*Lc + l4];
    s4.x = fmaf(e1.x,e2.x,s4.x); s4.y = fmaf(e1.y,e2.y,s4.y);
    s4.z = fmaf(e1.z,e2.z,s4.z); s4.w = fmaf(e1.w,e2.w,s4.w);
  }
  s4.x *= (1.0f/Hc); s4.y *= (1.0f/Hc); s4.z *= (1.0f/Hc); s4.w *= (1.0f/Hc);
  *(float4*)&raw[l4] = s4;
  float lsum = s4.x+s4.y+s4.z+s4.w;
  for (int off = 32; off; off >>= 1) lsum += __shfl_down(lsum, off);
  if ((threadIdx.x & 63) == 0) wsum[threadIdx.x>>6] = lsum;
  __syncthreads();
  float inv = 1.0f/(wsum[0]+wsum[1]+wsum[2]+wsum[3] + 1e-5f);
  float4 rv = *(const float4*)&raw[l4];
  us4 v4;
  v4[0] = f2bf(rv.x*inv); v4[1] = f2bf(rv.y*inv);
  v4[2] = f2bf(rv.z*inv); v4[3] = f2bf(rv.w*inv);
  *(us4*)(o + flin_off(p, l4, 32)) = v4;
}

// ---------------- K4: flin MFMA GEMM, 2 m-frags x NT n-tiles per wave ----------------
struct FJob {
  const unsigned short* A1; const unsigned short* A2;
  const unsigned short* W;  const float* bias; void* C;
  int M; int mtmax; size_t Abs; size_t Wbs; int rowsPerBatch;
};

// CT: 0 = fp32 (+bias), 1 = fp32+bias+tanh -> fp16 row-major, 2 = bf16 flin (KTC=24)
template<int KT1, int KT2, int CT, int NT>
__global__ __launch_bounds__(256) void k_fgemm(FJob j0, FJob j1, int nx0){
  FJob j = (blockIdx.x < nx0) ? j0 : j1;
  int mbx = (blockIdx.x < nx0) ? blockIdx.x : blockIdx.x - nx0;
  const int KTW = KT1 + KT2;
  int z = blockIdx.z;
  int lane = threadIdx.x & 63, wid = threadIdx.x >> 6;
  int row16 = lane & 15, oct = lane >> 4;
  int rb = mbx*128 + wid*32;
  int mt0 = rb >> 4;       if (mt0 >= j.mtmax) mt0 = j.mtmax - 1;
  int mt1 = (rb >> 4) + 1; if (mt1 >= j.mtmax) mt1 = j.mtmax - 1;
  const unsigned short* ap0 = j.A1 + (size_t)z*j.Abs + (size_t)mt0*KT1*512 + lane*8;
  const unsigned short* ap1 = j.A1 + (size_t)z*j.Abs + (size_t)mt1*KT1*512 + lane*8;
  const unsigned short* wb = j.W  + (size_t)z*j.Wbs + (size_t)(blockIdx.y*NT)*KTW*512 + lane*8;
  f32x4 acc[2][NT];
  #pragma unroll
  for (int m = 0; m < 2; m++)
    #pragma unroll
    for (int n = 0; n < NT; n++) acc[m][n] = (f32x4){0.f,0.f,0.f,0.f};
  #pragma unroll 4
  for (int kt = 0; kt < KT1; kt++){
    short8 a0 = *(const short8*)(ap0 + (size_t)kt*512);
    short8 a1 = *(const short8*)(ap1 + (size_t)kt*512);
    #pragma unroll
    for (int n = 0; n < NT; n++){
      short8 bv = *(const short8*)(wb + (size_t)(n*KTW + kt)*512);
      acc[0][n] = __builtin_amdgcn_mfma_f32_16x16x32_bf16(a0, bv, acc[0][n], 0, 0, 0);
      acc[1][n] = __builtin_amdgcn_mfma_f32_16x16x32_bf16(a1, bv, acc[1][n], 0, 0, 0);
    }
  }
  if (KT2 > 0){
    const unsigned short* b0p = j.A2 + (size_t)mt0*KT2*512 + lane*8;
    const unsigned short* b1p = j.A2 + (size_t)mt1*KT2*512 + lane*8;
    #pragma unroll 4
    for (int kt = 0; kt < KT2; kt++){
      short8 a0 = *(const short8*)(b0p + (size_t)kt*512);
      short8 a1 = *(const short8*)(b1p + (size_t)kt*512);
      #pragma unroll
      for (int n = 0; n < NT; n++){
        short8 bv = *(const short8*)(wb + (size_t)(n*KTW + KT1 + kt)*512);
        acc[0][n] = __builtin_amdgcn_mfma_f32_16x16x32_bf16(a0, bv, acc[0][n], 0, 0, 0);
        acc[1][n] = __builtin_amdgcn_mfma_f32_16x16x32_bf16(a1, bv, acc[1][n], 0, 0, 0);
      }
    }
  }
  int colb = blockIdx.y*(NT*16);
  #pragma unroll
  for (int m = 0; m < 2; m++)
    #pragma unroll
    for (int n = 0; n < NT; n++)
      #pragma unroll
      for (int jj = 0; jj < 4; jj++){
        int r = rb + m*16 + oct*4 + jj;
        if (r < j.M){
          int col = colb + n*16 + row16;
          float v = acc[m][n][jj];
          if (CT <= 1 && j.bias) v += j.bias[col];
          int rg = z*j.rowsPerBatch + r;
          if (CT == 2){
            ((unsigned short*)j.C)[flin_off(rg, col, 24)] = f2bf(v);
          } else if (CT == 1){
            ((unsigned short*)j.C)[(size_t)rg*768 + col] = f2h(tanhf(v));
          } else {
            ((float*)j.C)[(size_t)rg*768 + col] = v;
          }
        }
      }
}

// ---------------- K6: pool, wave-per-r (no barriers) ----------------
__global__ __launch_bounds__(256) void k_pool(const float* __restrict__ kment,
                                              const float* __restrict__ ment,
                                              const float* __restrict__ q_c,
                                              const int* __restrict__ hts,
                                              unsigned short* __restrict__ h_bf,
                                              unsigned short* __restrict__ t_bf){
  int wid = threadIdx.x >> 6, lane = threadIdx.x & 63;
  int r = blockIdx.x*4 + wid;
  int b = r / Pc;
  float q[12];
  const float* qp = q_c + (size_t)r*Dc + lane;
  #pragma unroll
  for (int u = 0; u < 12; u++) q[u] = qp[u*64];
  const float invs = 0.03608439182435161f;  // 1/sqrt(768)
  #pragma unroll
  for (int side = 0; side < 2; side++){
    int e = hts[r*2+side];
    const float* kb = kment + (size_t)(b*Ec+e)*Mc*Dc + lane;
    const float* mb = ment  + (size_t)(b*Ec+e)*Mc*Dc;   // no +lane (d below includes lane)
    float part[Mc] = {0.f,0.f,0.f,0.f};
    #pragma unroll
    for (int m = 0; m < Mc; m++)
      #pragma unroll
      for (int u = 0; u < 12; u++)
        part[m] = fmaf(kb[m*Dc + u*64], q[u], part[m]);
    #pragma unroll
    for (int m = 0; m < Mc; m++)
      #pragma unroll
      for (int off = 1; off < 64; off <<= 1)
        part[m] += __shfl_xor(part[m], off);
    float mx = fmaxf(fmaxf(part[0],part[1]), fmaxf(part[2],part[3])) * invs;
    float w0 = expf(part[0]*invs - mx), w1 = expf(part[1]*invs - mx);
    float w2 = expf(part[2]*invs - mx), w3 = expf(part[3]*invs - mx);
    float isum = 1.0f/(w0+w1+w2+w3);
    w0 *= isum; w1 *= isum; w2 *= isum; w3 *= isum;
    unsigned short* o = side ? t_bf : h_bf;
    #pragma unroll
    for (int u = 0; u < 12; u++){
      int d = lane + u*64;
      float v = w0*mb[d] + w1*mb[Dc+d] + w2*mb[2*Dc+d] + w3*mb[3*Dc+d];
      o[flin_off(r, d, 24)] = f2bf(v);
    }
  }
}

// ---------------- K8: MFMA bilinear fp16, 4 m-frags/wave, KSPL=48, fp16 partial ----------------
// grid = mb(9) x kb(48); block 4 waves x 64 rows = 256 rows
__global__ __launch_bounds__(256) void k_bilinear_mfma(
    const unsigned short* __restrict__ hs16, const unsigned short* __restrict__ ts16,
    const unsigned short* __restrict__ Wbf,
    unsigned short* __restrict__ partial)
{
  int mb = blockIdx.x / KSPL;
  int kb = blockIdx.x % KSPL;
  int k  = kb >> 2;             // EMB block 0..11
  int i0 = (kb & 3) * 16;       // i sub-range (16 wide)

  int tid  = threadIdx.x;
  int lane = tid & 63;
  int wid  = tid >> 6;
  int row16 = lane & 15;
  int oct   = lane >> 4;

  int rbase = mb*256 + wid*64;

  __shared__ __align__(16) unsigned short Wlds[2][8960];

  f16x8 tsh[4][2];  // [m][jhalf]
  f16x8 hsh[4][2];  // [m][q], i = q*8 + e  (16 i-values)
  #pragma unroll
  for (int m = 0; m < 4; m++){
    int r = rbase + m*16 + row16; if (r > Rc-1) r = Rc-1;
    const unsigned short* tp = ts16 + (size_t)r*EMBc + k*64;
    tsh[m][0] = __builtin_bit_cast(f16x8, *(const short8*)(tp + oct*8));
    tsh[m][1] = __builtin_bit_cast(f16x8, *(const short8*)(tp + 32 + oct*8));
    const unsigned short* hp = hs16 + (size_t)r*EMBc + k*64 + i0;
    hsh[m][0] = __builtin_bit_cast(f16x8, *(const short8*)(hp));
    hsh[m][1] = __builtin_bit_cast(f16x8, *(const short8*)(hp + 8));
  }

  const char* wsrc = (const char*)(Wbf + ((size_t)(k*128 + i0*2))*4480);

  #pragma unroll
  for (int rr = 0; rr < 5; rr++){
    int u = tid + rr*256;
    if (u < 1120)
      __builtin_amdgcn_global_load_lds(
        (const __attribute__((address_space(1))) unsigned int*)(wsrc + (size_t)u*16),
        (__attribute__((address_space(3))) unsigned int*)((char*)&Wlds[0][0] + u*16),
        16, 0, 0);
  }

  f32x4 acc[4][7];
  #pragma unroll
  for (int m = 0; m < 4; m++)
    #pragma unroll
    for (int n = 0; n < 7; n++) acc[m][n] = (f32x4){0.f,0.f,0.f,0.f};

  __syncthreads();   // pair 0 staged

  #pragma unroll
  for (int cp = 0; cp < 16; cp++){    // pair cp = chunks (i=cp, jh=0/1)
    int cur = cp & 1;
    if (cp < 15){
      const char* nsrc = wsrc + (size_t)(cp+1)*17920;
      #pragma unroll
      for (int rr = 0; rr < 5; rr++){
        int u = tid + rr*256;
        if (u < 1120)
          __builtin_amdgcn_global_load_lds(
            (const __attribute__((address_space(1))) unsigned int*)(nsrc + (size_t)u*16),
            (__attribute__((address_space(3))) unsigned int*)((char*)&Wlds[cur^1][0] + u*16),
            16, 0, 0);
      }
    }
    #pragma unroll
    for (int half = 0; half < 2; half++){
      f16x8 af[4];
      #pragma unroll
      for (int m = 0; m < 4; m++){
        _Float16 hv = hsh[m][cp>>3][cp&7];       // static after full unroll
        f16x8 hvb = {hv,hv,hv,hv,hv,hv,hv,hv};
        af[m] = tsh[m][half] * hvb;              // 4x v_pk_mul_f16
      }
      #pragma unroll
      for (int n = 0; n < 7; n++){
        f16x8 bfr = __builtin_bit_cast(f16x8,
            *(const short8*)&Wlds[cur][half*4480 + (n*16 + row16)*40 + oct*8]);
        #pragma unroll
        for (int m = 0; m < 4; m++)
          acc[m][n] = __builtin_amdgcn_mfma_f32_16x16x32_f16(af[m], bfr, acc[m][n], 0, 0, 0);
      }
    }
    __syncthreads();
  }

  unsigned short* pk = partial + (size_t)kb*Rc*NLc;
  #pragma unroll
  for (int m = 0; m < 4; m++){
    #pragma unroll
    for (int n = 0; n < 7; n++){
      #pragma unroll
      for (int j = 0; j < 4; j++){
        int r = rbase + m*16 + oct*4 + j;
        int col = n*16 + row16;
        if (r < Rc && col < NLc)
          pk[(size_t)r*NLc + col] = f2h(acc[m][n][j]);
      }
    }
  }
}

// ---------------- K9: sum fp16 partials + bias ----------------
__global__ __launch_bounds__(256) void k_reduce(const unsigned short* __restrict__ partial,
                                                const float* __restrict__ bilb,
                                                float* __restrict__ out){
  int idx = blockIdx.x*256 + threadIdx.x;
  if (idx >= Rc*NLc) return;
  int n = idx % NLc;
  float s = bilb[n];
  #pragma unroll
  for (int ks = 0; ks < KSPL; ks++) s += h2f(partial[(size_t)ks*Rc*NLc + idx]);
  out[idx] = s;
}

extern "C" void kernel_launch(void* const* d_in, const int* in_sizes, int n_in,
                              void* d_out, int out_size, void* d_ws, size_t ws_size,
                              hipStream_t stream){
  const float* seq   = (const float*)d_in[0];
  const float* att   = (const float*)d_in[1];
  const float* W_q   = (const float*)d_in[2];
  const float* W_k   = (const float*)d_in[3];
  const float* headW = (const float*)d_in[4];
  const float* headb = (const float*)d_in[5];
  const float* tailW = (const float*)d_in[6];
  const float* tailb = (const float*)d_in[7];
  const float* bilW  = (const float*)d_in[8];
  const float* bilb  = (const float*)d_in[9];
  const int*   mpos  = (const int*)d_in[10];
  const int*   hts   = (const int*)d_in[11];
  float* out = (float*)d_out;

  float* ws = (float*)d_ws;
  float* ent_att = ws;                                      // 1,179,648 f
  float* q_c     = ws + 1179648;                            // 1,695,744 f
  float* kment   = q_c + 1695744;                           //   294,912 f
  float* ment    = kment + 294912;                          //   294,912 f
  unsigned short* seqf    = (unsigned short*)(ment + 294912);   // 3,145,728 sh
  unsigned short* htbf    = seqf + 3145728;                     // 2,293,760 sh
  unsigned short* rs_bf   = htbf + 4*HT_ABS;                    // 1,695,744 sh
  unsigned short* ment_bf = rs_bf + 1695744;                    //   294,912 sh
  unsigned short* h_bf    = ment_bf + 294912;                   // 1,695,744 sh
  unsigned short* t_bf    = h_bf + 1695744;                     // 1,695,744 sh
  unsigned short* Wq_f    = t_bf + 1695744;                     //   589,824 sh
  unsigned short* Wk_f    = Wq_f + 589824;                      //   589,824 sh
  unsigned short* headW_f = Wk_f + 589824;                      // 1,179,648 sh
  unsigned short* tailW_f = headW_f + 1179648;                  // 1,179,648 sh
  unsigned short* hs16 = tailW_f + 1179648;                 // 1,695,744 sh (fp16 row-major)
  unsigned short* ts16 = hs16 + 1695744;                    // 1,695,744 sh
  unsigned short* Wbf  = ts16 + 1695744;                    // 6,881,280 sh (fp16)
  unsigned short* partial = (unsigned short*)ws;
  // fp16 partial: 48*2208*97 = 10,280,448 sh = 20.6 MB; dead prefix spans ~42 MB: safe.

  k_prep   <<<4320, 256, 0, stream>>>(bilW, Wbf, seq, seqf, W_q, Wq_f, W_k, Wk_f,
                                      headW, headW_f, tailW, tailW_f,
                                      att, mpos, ent_att, ment, ment_bf);
  k_ht_att <<<4*560, 256, 0, stream>>>(ent_att, hts, htbf);
  {
    FJob jrs = { htbf, nullptr, seqf, nullptr, rs_bf, Pc, 35,
                 (size_t)HT_ABS, (size_t)(48*32*512), Pc };
    k_fgemm<32,0,2,2><<<dim3(5,24,4), 256, 0, stream>>>(jrs, jrs, 5);
  }
  {
    FJob jq = { rs_bf,   nullptr, Wq_f, nullptr, q_c,   Rc,       138, 0, 0, 0 };
    FJob jk = { ment_bf, nullptr, Wk_f, nullptr, kment, Bc*Ec*Mc,  24, 0, 0, 0 };
    k_fgemm<24,0,0,2><<<dim3(21,24), 256, 0, stream>>>(jq, jk, 18);
  }
  k_pool   <<<Rc/4, 256, 0, stream>>>(kment, ment, q_c, hts, h_bf, t_bf);
  {
    FJob jh = { h_bf, rs_bf, headW_f, headb, hs16, Rc, 138, 0, 0, 0 };
    FJob jt = { t_bf, rs_bf, tailW_f, tailb, ts16, Rc, 138, 0, 0, 0 };
    k_fgemm<24,24,1,2><<<dim3(36,24), 256, 0, stream>>>(jh, jt, 18);
  }
  k_bilinear_mfma<<<9*KSPL, 256, 0, stream>>>(hs16, ts16, Wbf, partial);
  k_reduce <<<(Rc*NLc+255)/256, 256, 0, stream>>>(partial, bilb, out);
}

// Round 13
// 134.144 us; speedup vs baseline: 1.6046x; 1.0927x over previous
//
#include <hip/hip_runtime.h>
#include <hip/hip_bf16.h>
#include <math.h>

#define Bc 4
#define Lc 1024
#define Dc 768
#define Hc 12
#define Ec 24
#define Mc 4
#define Pc 552
#define EMBc 768
#define NLc 97
#define Rc (Bc*Pc)      // 2208
#define KSPL 48         // bilinear: 12 k-blocks x 4 i-splits of 16
#define HT_ABS (35*32*512)   // htbf flin per-batch stride (shorts)

typedef __attribute__((ext_vector_type(4))) float f32x4;
typedef __attribute__((ext_vector_type(8))) short short8;
typedef __attribute__((ext_vector_type(4))) unsigned short us4;
typedef _Float16 f16x8 __attribute__((ext_vector_type(8)));

static __device__ __forceinline__ unsigned short f2bf(float x){
  unsigned int u = __float_as_uint(x);
  unsigned int r = u + 0x7fffu + ((u >> 16) & 1u);   // RNE
  return (unsigned short)(r >> 16);
}
static __device__ __forceinline__ unsigned short f2h(float x){
  _Float16 h = (_Float16)x;
  return __builtin_bit_cast(unsigned short, h);
}
static __device__ __forceinline__ float h2f(unsigned short x){
  return (float)__builtin_bit_cast(_Float16, x);
}
// flin index: row r, k-index kk, KT = K/32 chunks
static __device__ __forceinline__ size_t flin_off(int r, int kk, int KT){
  return ((size_t)(r>>4)*KT + (kk>>5))*512 + (size_t)((((kk&31)>>3)*16 + (r&15))*8) + (kk&7);
}

// ---------------- K0: weight prep + ent_att + mention gather (one launch) ----------------
__global__ __launch_bounds__(256) void k_prep(const float* __restrict__ bilW, unsigned short* __restrict__ Wbf,
                                              const float* __restrict__ seq, unsigned short* __restrict__ seqf,
                                              const float* __restrict__ W_q, unsigned short* __restrict__ Wq_f,
                                              const float* __restrict__ W_k, unsigned short* __restrict__ Wk_f,
                                              const float* __restrict__ headW, unsigned short* __restrict__ headW_f,
                                              const float* __restrict__ tailW, unsigned short* __restrict__ tailW_f,
                                              const float* __restrict__ att, const int* __restrict__ mpos,
                                              float* __restrict__ ent_att,
                                              unsigned short* __restrict__ ment_bf){
  int bx = blockIdx.x;
  int tid = threadIdx.x;
  __shared__ float t[64][65];     // shared by transpose path and bilW path
  if (bx < 1536){
    // bilW chunk -> fp16 [n=112][kk=40], LDS-staged for coalesced R and W.
    const float* Ws = bilW + (size_t)bx*32*NLc;   // 3104 contiguous floats
    unsigned short* o = Wbf + (size_t)bx*4480;
    float* w = &t[0][0];                          // 3104 <= 4160
    for (int idx = tid; idx < 32*NLc; idx += 256)
      w[idx] = Ws[idx];
    __syncthreads();
    #pragma unroll
    for (int q8 = 0; q8 < 18; q8++){
      int idx = q8*256 + tid;
      if (idx < 4480){
        int n = idx / 40, kk = idx - n*40;
        float v = (kk < 32 && n < NLc) ? w[kk*NLc + n] : 0.f;
        o[idx] = f2h(v);
      }
    }
    return;
  }
  if (bx >= 3168){                  // ent_att + gather
    int blk = bx - 3168;            // (b*E+e)*H + h, 1152 blocks
    int h  = blk % Hc;
    int be = blk / Hc;
    int b  = be / Ec;
    int p0 = mpos[be*Mc+0]+1, p1 = mpos[be*Mc+1]+1;
    int p2 = mpos[be*Mc+2]+1, p3 = mpos[be*Mc+3]+1;
    const float* ab = att + ((size_t)b*Hc + h)*Lc*Lc;
    const float* a0 = ab + (size_t)p0*Lc;
    const float* a1 = ab + (size_t)p1*Lc;
    const float* a2 = ab + (size_t)p2*Lc;
    const float* a3 = ab + (size_t)p3*Lc;
    float* o = ent_att + (size_t)blk*Lc;
    int l4 = tid*4;
    float4 v0 = *(const float4*)(a0 + l4);
    float4 v1 = *(const float4*)(a1 + l4);
    float4 v2 = *(const float4*)(a2 + l4);
    float4 v3 = *(const float4*)(a3 + l4);
    float4 ov;
    ov.x = 0.25f*(v0.x+v1.x+v2.x+v3.x);
    ov.y = 0.25f*(v0.y+v1.y+v2.y+v3.y);
    ov.z = 0.25f*(v0.z+v1.z+v2.z+v3.z);
    ov.w = 0.25f*(v0.w+v1.w+v2.w+v3.w);
    *(float4*)(o + l4) = ov;
    int gidx = blk*256 + tid;       // over B*E*M*D
    int d = gidx % Dc;
    int bem = gidx / Dc;
    int bb = bem / (Ec*Mc);
    int pos = mpos[bem] + 1;
    float v = seq[((size_t)bb*Lc + pos)*Dc + d];
    ment_bf[flin_off(bem, d, 24)] = f2bf(v);
    return;
  }
  bx -= 1536;
  const float* src; unsigned short* dst; int tk, tn, KTW;
  if (bx < 768){                     // seq [1024x768] x4 -> flin KTW=32
    int z = bx / 192, rem = bx % 192;
    src = seq + (size_t)z*Lc*Dc; dst = seqf + (size_t)z*(Dc/16)*(Lc/32)*512;
    tk = rem % 16; tn = rem / 16; KTW = 32;
  } else if (bx < 768+144){
    int rem = bx - 768;
    src = W_q; dst = Wq_f; tk = rem % 12; tn = rem / 12; KTW = 24;
  } else if (bx < 768+288){
    int rem = bx - (768+144);
    src = W_k; dst = Wk_f; tk = rem % 12; tn = rem / 12; KTW = 24;
  } else if (bx < 768+288+288){
    int rem = bx - (768+288);
    src = headW; dst = headW_f; tk = rem % 24; tn = rem / 24; KTW = 48;
  } else {
    int rem = bx - (768+288+288);
    src = tailW; dst = tailW_f; tk = rem % 24; tn = rem / 24; KTW = 48;
  }
  int r0 = tk*64, c0 = tn*64;       // r0 along K, c0 along N(=768)
  #pragma unroll
  for (int q8 = 0; q8 < 16; q8++){
    int idx = q8*256 + tid;
    int rr = idx >> 6, cc = idx & 63;
    t[rr][cc] = src[(size_t)(r0+rr)*768 + c0+cc];
  }
  __syncthreads();
  #pragma unroll
  for (int q8 = 0; q8 < 16; q8++){
    int idx = q8*256 + tid;
    int li = idx & 511, sub = idx >> 9;
    int nt_l = sub >> 1, kt_l = sub & 1;
    int lane = li >> 3, e = li & 7;
    int kl = kt_l*32 + (lane>>4)*8 + e;
    int nl = nt_l*16 + (lane&15);
    dst[ ((size_t)(c0/16 + nt_l)*KTW + (r0/32 + kt_l))*512 + li ] = f2bf(t[kl][nl]);
  }
}

// ---------------- K2: ht_att -> bf16 flin (zero pad rows 552..559) ----------------
__global__ __launch_bounds__(256) void k_ht_att(const float* __restrict__ ent_att,
                                                const int* __restrict__ hts,
                                                unsigned short* __restrict__ htbf){
  int b = blockIdx.x & 3;
  int p = blockIdx.x >> 2;          // 0..559
  unsigned short* o = htbf + (size_t)b*HT_ABS;
  int l4 = threadIdx.x*4;
  if (p >= Pc){
    us4 z4 = {0,0,0,0};
    *(us4*)(o + flin_off(p, l4, 32)) = z4;
    return;
  }
  int r = b*Pc + p;
  int hi = hts[r*2+0], ti = hts[r*2+1];
  const float* eh = ent_att + (size_t)(b*Ec+hi)*Hc*Lc;
  const float* et = ent_att + (size_t)(b*Ec+ti)*Hc*Lc;
  __shared__ float raw[Lc];
  __shared__ float wsum[4];
  float4 s4 = {0.f,0.f,0.f,0.f};
  #pragma unroll
  for (int h = 0; h < Hc; h++){
    float4 e1 = *(const float4*)&eh[h*Lc + l4];
    float4 e2 = *(const float4*)&et[h*Lc + l4];
    s4.x = fmaf(e1.x,e2.x,s4.x); s4.y = fmaf(e1.y,e2.y,s4.y);
    s4.z = fmaf(e1.z,e2.z,s4.z); s4.w = fmaf(e1.w,e2.w,s4.w);
  }
  s4.x *= (1.0f/Hc); s4.y *= (1.0f/Hc); s4.z *= (1.0f/Hc); s4.w *= (1.0f/Hc);
  *(float4*)&raw[l4] = s4;
  float lsum = s4.x+s4.y+s4.z+s4.w;
  for (int off = 32; off; off >>= 1) lsum += __shfl_down(lsum, off);
  if ((threadIdx.x & 63) == 0) wsum[threadIdx.x>>6] = lsum;
  __syncthreads();
  float inv = 1.0f/(wsum[0]+wsum[1]+wsum[2]+wsum[3] + 1e-5f);
  float4 rv = *(const float4*)&raw[l4];
  us4 v4;
  v4[0] = f2bf(rv.x*inv); v4[1] = f2bf(rv.y*inv);
  v4[2] = f2bf(rv.z*inv); v4[3] = f2bf(rv.w*inv);
  *(us4*)(o + flin_off(p, l4, 32)) = v4;
}

// ---------------- K4: flin MFMA GEMM, multi-job, runtime W k-stride ----------------
struct FJob {
  const unsigned short* A1; const unsigned short* W; const float* bias; void* C;
  int M; int mtmax; int Wktw; int rowsPerBatch;
  size_t Abs; size_t Wbs;
};
struct FJobs {
  FJob j[6]; int xs[7]; int n;
};

// CT: 0 = fp32 (+bias), 2 = bf16 flin (KTC=24)
template<int KT1, int CT, int NT>
__global__ __launch_bounds__(256) void k_fgemmN(FJobs P){
  int jx = 0;
  for (int tjob = 1; tjob < P.n; tjob++)
    if ((int)blockIdx.x >= P.xs[tjob]) jx = tjob;
  FJob j = P.j[jx];
  int mbx = blockIdx.x - P.xs[jx];
  int z = blockIdx.z;
  int lane = threadIdx.x & 63, wid = threadIdx.x >> 6;
  int row16 = lane & 15, oct = lane >> 4;
  int rb = mbx*128 + wid*32;
  int mt0 = rb >> 4;       if (mt0 >= j.mtmax) mt0 = j.mtmax - 1;
  int mt1 = (rb >> 4) + 1; if (mt1 >= j.mtmax) mt1 = j.mtmax - 1;
  const unsigned short* ap0 = j.A1 + (size_t)z*j.Abs + (size_t)mt0*KT1*512 + lane*8;
  const unsigned short* ap1 = j.A1 + (size_t)z*j.Abs + (size_t)mt1*KT1*512 + lane*8;
  const unsigned short* wb = j.W + (size_t)z*j.Wbs + (size_t)(blockIdx.y*NT)*j.Wktw*512 + lane*8;
  f32x4 acc[2][NT];
  #pragma unroll
  for (int m = 0; m < 2; m++)
    #pragma unroll
    for (int n = 0; n < NT; n++) acc[m][n] = (f32x4){0.f,0.f,0.f,0.f};
  #pragma unroll 4
  for (int kt = 0; kt < KT1; kt++){
    short8 a0 = *(const short8*)(ap0 + (size_t)kt*512);
    short8 a1 = *(const short8*)(ap1 + (size_t)kt*512);
    #pragma unroll
    for (int n = 0; n < NT; n++){
      short8 bv = *(const short8*)(wb + (size_t)(n*j.Wktw + kt)*512);
      acc[0][n] = __builtin_amdgcn_mfma_f32_16x16x32_bf16(a0, bv, acc[0][n], 0, 0, 0);
      acc[1][n] = __builtin_amdgcn_mfma_f32_16x16x32_bf16(a1, bv, acc[1][n], 0, 0, 0);
    }
  }
  int colb = blockIdx.y*(NT*16);
  #pragma unroll
  for (int m = 0; m < 2; m++)
    #pragma unroll
    for (int n = 0; n < NT; n++)
      #pragma unroll
      for (int jj = 0; jj < 4; jj++){
        int r = rb + m*16 + oct*4 + jj;
        if (r < j.M){
          int col = colb + n*16 + row16;
          float v = acc[m][n][jj];
          if (CT == 0 && j.bias) v += j.bias[col];
          int rg = z*j.rowsPerBatch + r;
          if (CT == 2){
            ((unsigned short*)j.C)[flin_off(rg, col, 24)] = f2bf(v);
          } else {
            ((float*)j.C)[(size_t)rg*768 + col] = v;
          }
        }
      }
}

// ---------------- K6: pool v2 — softmax weights + distributed head/tail combine ----------------
// hs16[r] = tanh(rsWh[r] + sum_m w_m * mWh[(b,e),m] + headb); same for tail.
__global__ __launch_bounds__(256) void k_pool(const float* __restrict__ kment,
                                              const float* __restrict__ q_c,
                                              const float* __restrict__ rsWh,
                                              const float* __restrict__ rsWt,
                                              const float* __restrict__ mWh,
                                              const float* __restrict__ mWt,
                                              const float* __restrict__ headb,
                                              const float* __restrict__ tailb,
                                              const int* __restrict__ hts,
                                              unsigned short* __restrict__ hs16,
                                              unsigned short* __restrict__ ts16){
  int wid = threadIdx.x >> 6, lane = threadIdx.x & 63;
  int r = blockIdx.x*4 + wid;
  int b = r / Pc;
  float q[12];
  const float* qp = q_c + (size_t)r*Dc + lane;
  #pragma unroll
  for (int u = 0; u < 12; u++) q[u] = qp[u*64];
  const float invs = 0.03608439182435161f;  // 1/sqrt(768)
  #pragma unroll
  for (int side = 0; side < 2; side++){
    int e = hts[r*2+side];
    const float* kb = kment + (size_t)(b*Ec+e)*Mc*Dc + lane;
    float part[Mc] = {0.f,0.f,0.f,0.f};
    #pragma unroll
    for (int m = 0; m < Mc; m++)
      #pragma unroll
      for (int u = 0; u < 12; u++)
        part[m] = fmaf(kb[m*Dc + u*64], q[u], part[m]);
    #pragma unroll
    for (int m = 0; m < Mc; m++)
      #pragma unroll
      for (int off = 1; off < 64; off <<= 1)
        part[m] += __shfl_xor(part[m], off);
    float mx = fmaxf(fmaxf(part[0],part[1]), fmaxf(part[2],part[3])) * invs;
    float w0 = expf(part[0]*invs - mx), w1 = expf(part[1]*invs - mx);
    float w2 = expf(part[2]*invs - mx), w3 = expf(part[3]*invs - mx);
    float isum = 1.0f/(w0+w1+w2+w3);
    w0 *= isum; w1 *= isum; w2 *= isum; w3 *= isum;
    const float* mW  = (side ? mWt  : mWh) + (size_t)(b*Ec+e)*Mc*Dc;   // 4 rows x 768
    const float* rsW = (side ? rsWt : rsWh) + (size_t)r*Dc;
    const float* bias = side ? tailb : headb;
    unsigned short* o = (side ? ts16 : hs16) + (size_t)r*Dc;
    #pragma unroll
    for (int u = 0; u < 12; u++){
      int d = lane + u*64;
      float v = rsW[d] + bias[d]
              + w0*mW[d] + w1*mW[Dc+d] + w2*mW[2*Dc+d] + w3*mW[3*Dc+d];
      o[d] = f2h(tanhf(v));
    }
  }
}

// ---------------- K8: MFMA bilinear fp16, 4 m-frags/wave, KSPL=48, fp16 partial ----------------
// grid = mb(9) x kb(48); block 4 waves x 64 rows = 256 rows
__global__ __launch_bounds__(256) void k_bilinear_mfma(
    const unsigned short* __restrict__ hs16, const unsigned short* __restrict__ ts16,
    const unsigned short* __restrict__ Wbf,
    unsigned short* __restrict__ partial)
{
  int mb = blockIdx.x / KSPL;
  int kb = blockIdx.x % KSPL;
  int k  = kb >> 2;             // EMB block 0..11
  int i0 = (kb & 3) * 16;       // i sub-range (16 wide)

  int tid  = threadIdx.x;
  int lane = tid & 63;
  int wid  = tid >> 6;
  int row16 = lane & 15;
  int oct   = lane >> 4;

  int rbase = mb*256 + wid*64;

  __shared__ __align__(16) unsigned short Wlds[2][8960];

  f16x8 tsh[4][2];  // [m][jhalf]
  f16x8 hsh[4][2];  // [m][q], i = q*8 + e  (16 i-values)
  #pragma unroll
  for (int m = 0; m < 4; m++){
    int r = rbase + m*16 + row16; if (r > Rc-1) r = Rc-1;
    const unsigned short* tp = ts16 + (size_t)r*EMBc + k*64;
    tsh[m][0] = __builtin_bit_cast(f16x8, *(const short8*)(tp + oct*8));
    tsh[m][1] = __builtin_bit_cast(f16x8, *(const short8*)(tp + 32 + oct*8));
    const unsigned short* hp = hs16 + (size_t)r*EMBc + k*64 + i0;
    hsh[m][0] = __builtin_bit_cast(f16x8, *(const short8*)(hp));
    hsh[m][1] = __builtin_bit_cast(f16x8, *(const short8*)(hp + 8));
  }

  const char* wsrc = (const char*)(Wbf + ((size_t)(k*128 + i0*2))*4480);

  #pragma unroll
  for (int rr = 0; rr < 5; rr++){
    int u = tid + rr*256;
    if (u < 1120)
      __builtin_amdgcn_global_load_lds(
        (const __attribute__((address_space(1))) unsigned int*)(wsrc + (size_t)u*16),
        (__attribute__((address_space(3))) unsigned int*)((char*)&Wlds[0][0] + u*16),
        16, 0, 0);
  }

  f32x4 acc[4][7];
  #pragma unroll
  for (int m = 0; m < 4; m++)
    #pragma unroll
    for (int n = 0; n < 7; n++) acc[m][n] = (f32x4){0.f,0.f,0.f,0.f};

  __syncthreads();   // pair 0 staged

  #pragma unroll
  for (int cp = 0; cp < 16; cp++){    // pair cp = chunks (i=cp, jh=0/1)
    int cur = cp & 1;
    if (cp < 15){
      const char* nsrc = wsrc + (size_t)(cp+1)*17920;
      #pragma unroll
      for (int rr = 0; rr < 5; rr++){
        int u = tid + rr*256;
        if (u < 1120)
          __builtin_amdgcn_global_load_lds(
            (const __attribute__((address_space(1))) unsigned int*)(nsrc + (size_t)u*16),
            (__attribute__((address_space(3))) unsigned int*)((char*)&Wlds[cur^1][0] + u*16),
            16, 0, 0);
      }
    }
    #pragma unroll
    for (int half = 0; half < 2; half++){
      f16x8 af[4];
      #pragma unroll
      for (int m = 0; m < 4; m++){
        _Float16 hv = hsh[m][cp>>3][cp&7];       // static after full unroll
        f16x8 hvb = {hv,hv,hv,hv,hv,hv,hv,hv};
        af[m] = tsh[m][half] * hvb;              // 4x v_pk_mul_f16
      }
      #pragma unroll
      for (int n = 0; n < 7; n++){
        f16x8 bfr = __builtin_bit_cast(f16x8,
            *(const short8*)&Wlds[cur][half*4480 + (n*16 + row16)*40 + oct*8]);
        #pragma unroll
        for (int m = 0; m < 4; m++)
          acc[m][n] = __builtin_amdgcn_mfma_f32_16x16x32_f16(af[m], bfr, acc[m][n], 0, 0, 0);
      }
    }
    __syncthreads();
  }

  unsigned short* pk = partial + (size_t)kb*Rc*NLc;
  #pragma unroll
  for (int m = 0; m < 4; m++){
    #pragma unroll
    for (int n = 0; n < 7; n++){
      #pragma unroll
      for (int j = 0; j < 4; j++){
        int r = rbase + m*16 + oct*4 + j;
        int col = n*16 + row16;
        if (r < Rc && col < NLc)
          pk[(size_t)r*NLc + col] = f2h(acc[m][n][j]);
      }
    }
  }
}

// ---------------- K9: sum fp16 partials + bias ----------------
__global__ __launch_bounds__(256) void k_reduce(const unsigned short* __restrict__ partial,
                                                const float* __restrict__ bilb,
                                                float* __restrict__ out){
  int idx = blockIdx.x*256 + threadIdx.x;
  if (idx >= Rc*NLc) return;
  int n = idx % NLc;
  float s = bilb[n];
  #pragma unroll
  for (int ks = 0; ks < KSPL; ks++) s += h2f(partial[(size_t)ks*Rc*NLc + idx]);
  out[idx] = s;
}

extern "C" void kernel_launch(void* const* d_in, const int* in_sizes, int n_in,
                              void* d_out, int out_size, void* d_ws, size_t ws_size,
                              hipStream_t stream){
  const float* seq   = (const float*)d_in[0];
  const float* att   = (const float*)d_in[1];
  const float* W_q   = (const float*)d_in[2];
  const float* W_k   = (const float*)d_in[3];
  const float* headW = (const float*)d_in[4];
  const float* headb = (const float*)d_in[5];
  const float* tailW = (const float*)d_in[6];
  const float* tailb = (const float*)d_in[7];
  const float* bilW  = (const float*)d_in[8];
  const float* bilb  = (const float*)d_in[9];
  const int*   mpos  = (const int*)d_in[10];
  const int*   hts   = (const int*)d_in[11];
  float* out = (float*)d_out;

  float* ws = (float*)d_ws;
  float* ent_att = ws;                                      // 1,179,648 f
  float* q_c     = ws + 1179648;                            // 1,695,744 f
  float* kment   = q_c + 1695744;                           //   294,912 f
  float* ment_unused = kment + 294912;                      //   294,912 f (layout keep)
  unsigned short* seqf    = (unsigned short*)(ment_unused + 294912); // 3,145,728 sh
  unsigned short* htbf    = seqf + 3145728;                     // 2,293,760 sh
  unsigned short* rs_bf   = htbf + 4*HT_ABS;                    // 1,695,744 sh
  unsigned short* ment_bf = rs_bf + 1695744;                    //   294,912 sh
  unsigned short* Wq_f    = ment_bf + 294912;                   //   589,824 sh
  unsigned short* Wk_f    = Wq_f + 589824;                      //   589,824 sh
  unsigned short* headW_f = Wk_f + 589824;                      // 1,179,648 sh
  unsigned short* tailW_f = headW_f + 1179648;                  // 1,179,648 sh
  unsigned short* hs16 = tailW_f + 1179648;                 // 1,695,744 sh (fp16 row-major)
  unsigned short* ts16 = hs16 + 1695744;                    // 1,695,744 sh
  unsigned short* Wbf  = ts16 + 1695744;                    // 6,881,280 sh (fp16)
  float* rsWh = (float*)(Wbf + 6881280);                    // 1,695,744 f
  float* rsWt = rsWh + 1695744;                             // 1,695,744 f
  float* mWh  = rsWt + 1695744;                             //   294,912 f
  float* mWt  = mWh + 294912;                               //   294,912 f
  unsigned short* partial = (unsigned short*)ws;
  // fp16 partial: 48*2208*97 = 10,280,448 sh = 20.6 MB; overlapped region
  // (ent_att, q_c, kment, seqf, htbf head) is all dead before the bilinear: safe.

  k_prep   <<<4320, 256, 0, stream>>>(bilW, Wbf, seq, seqf, W_q, Wq_f, W_k, Wk_f,
                                      headW, headW_f, tailW, tailW_f,
                                      att, mpos, ent_att, ment_bf);
  k_ht_att <<<4*560, 256, 0, stream>>>(ent_att, hts, htbf);
  {
    FJobs P{};
    P.j[0] = { htbf, seqf, nullptr, rs_bf, Pc, 35, 32, Pc,
               (size_t)HT_ABS, (size_t)(48*32*512) };
    P.xs[0] = 0; P.xs[1] = 5; P.n = 1;
    k_fgemmN<32,2,2><<<dim3(5,24,4), 256, 0, stream>>>(P);
  }
  {
    FJobs P{};
    P.j[0] = { rs_bf,   Wq_f,              nullptr, q_c,   Rc,  138, 24, 0, 0, 0 };
    P.j[1] = { ment_bf, Wk_f,              nullptr, kment, 384,  24, 24, 0, 0, 0 };
    P.j[2] = { rs_bf,   headW_f + 24*512,  nullptr, rsWh,  Rc,  138, 48, 0, 0, 0 };
    P.j[3] = { rs_bf,   tailW_f + 24*512,  nullptr, rsWt,  Rc,  138, 48, 0, 0, 0 };
    P.j[4] = { ment_bf, headW_f,           nullptr, mWh,   384,  24, 48, 0, 0, 0 };
    P.j[5] = { ment_bf, tailW_f,           nullptr, mWt,   384,  24, 48, 0, 0, 0 };
    P.xs[0]=0; P.xs[1]=18; P.xs[2]=21; P.xs[3]=39; P.xs[4]=57; P.xs[5]=60; P.xs[6]=63;
    P.n = 6;
    k_fgemmN<24,0,2><<<dim3(63,24), 256, 0, stream>>>(P);
  }
  k_pool   <<<Rc/4, 256, 0, stream>>>(kment, q_c, rsWh, rsWt, mWh, mWt,
                                      headb, tailb, hts, hs16, ts16);
  k_bilinear_mfma<<<9*KSPL, 256, 0, stream>>>(hs16, ts16, Wbf, partial);
  k_reduce <<<(Rc*NLc+255)/256, 256, 0, stream>>>(partial, bilb, out);
}

// Round 14
// 130.383 us; speedup vs baseline: 1.6509x; 1.0288x over previous
//
#include <hip/hip_runtime.h>
#include <hip/hip_bf16.h>
#include <math.h>

#define Bc 4
#define Lc 1024
#define Dc 768
#define Hc 12
#define Ec 24
#define Mc 4
#define Pc 552
#define EMBc 768
#define NLc 97
#define Rc (Bc*Pc)      // 2208
#define KSPL 48         // bilinear: 12 k-blocks x 4 i-splits of 16
#define HT_ABS (35*32*512)   // htbf flin per-batch stride (shorts)

typedef __attribute__((ext_vector_type(4))) float f32x4;
typedef __attribute__((ext_vector_type(8))) short short8;
typedef __attribute__((ext_vector_type(4))) unsigned short us4;
typedef _Float16 f16x8 __attribute__((ext_vector_type(8)));

static __device__ __forceinline__ unsigned short f2bf(float x){
  unsigned int u = __float_as_uint(x);
  unsigned int r = u + 0x7fffu + ((u >> 16) & 1u);   // RNE
  return (unsigned short)(r >> 16);
}
static __device__ __forceinline__ unsigned short f2h(float x){
  _Float16 h = (_Float16)x;
  return __builtin_bit_cast(unsigned short, h);
}
static __device__ __forceinline__ float h2f(unsigned short x){
  return (float)__builtin_bit_cast(_Float16, x);
}
// flin index: row r, k-index kk, KT = K/32 chunks
static __device__ __forceinline__ size_t flin_off(int r, int kk, int KT){
  return ((size_t)(r>>4)*KT + (kk>>5))*512 + (size_t)((((kk&31)>>3)*16 + (r&15))*8) + (kk&7);
}

// ---------------- K0: weight prep + ent_att + mention gather (one launch) ----------------
__global__ __launch_bounds__(256) void k_prep(const float* __restrict__ bilW, unsigned short* __restrict__ Wbf,
                                              const float* __restrict__ seq, unsigned short* __restrict__ seqf,
                                              const float* __restrict__ W_q, unsigned short* __restrict__ Wq_f,
                                              const float* __restrict__ W_k, unsigned short* __restrict__ Wk_f,
                                              const float* __restrict__ headW, unsigned short* __restrict__ headW_f,
                                              const float* __restrict__ tailW, unsigned short* __restrict__ tailW_f,
                                              const float* __restrict__ att, const int* __restrict__ mpos,
                                              float* __restrict__ ent_att,
                                              unsigned short* __restrict__ ment_bf){
  int bx = blockIdx.x;
  int tid = threadIdx.x;
  __shared__ float t[64][65];     // shared by transpose path and bilW path
  if (bx < 1536){
    const float* Ws = bilW + (size_t)bx*32*NLc;   // 3104 contiguous floats
    unsigned short* o = Wbf + (size_t)bx*4480;
    float* w = &t[0][0];                          // 3104 <= 4160
    for (int idx = tid; idx < 32*NLc; idx += 256)
      w[idx] = Ws[idx];
    __syncthreads();
    #pragma unroll
    for (int q8 = 0; q8 < 18; q8++){
      int idx = q8*256 + tid;
      if (idx < 4480){
        int n = idx / 40, kk = idx - n*40;
        float v = (kk < 32 && n < NLc) ? w[kk*NLc + n] : 0.f;
        o[idx] = f2h(v);
      }
    }
    return;
  }
  if (bx >= 3168){                  // ent_att + gather
    int blk = bx - 3168;            // (b*E+e)*H + h, 1152 blocks
    int h  = blk % Hc;
    int be = blk / Hc;
    int b  = be / Ec;
    int p0 = mpos[be*Mc+0]+1, p1 = mpos[be*Mc+1]+1;
    int p2 = mpos[be*Mc+2]+1, p3 = mpos[be*Mc+3]+1;
    const float* ab = att + ((size_t)b*Hc + h)*Lc*Lc;
    const float* a0 = ab + (size_t)p0*Lc;
    const float* a1 = ab + (size_t)p1*Lc;
    const float* a2 = ab + (size_t)p2*Lc;
    const float* a3 = ab + (size_t)p3*Lc;
    float* o = ent_att + (size_t)blk*Lc;
    int l4 = tid*4;
    float4 v0 = *(const float4*)(a0 + l4);
    float4 v1 = *(const float4*)(a1 + l4);
    float4 v2 = *(const float4*)(a2 + l4);
    float4 v3 = *(const float4*)(a3 + l4);
    float4 ov;
    ov.x = 0.25f*(v0.x+v1.x+v2.x+v3.x);
    ov.y = 0.25f*(v0.y+v1.y+v2.y+v3.y);
    ov.z = 0.25f*(v0.z+v1.z+v2.z+v3.z);
    ov.w = 0.25f*(v0.w+v1.w+v2.w+v3.w);
    *(float4*)(o + l4) = ov;
    int gidx = blk*256 + tid;       // over B*E*M*D
    int d = gidx % Dc;
    int bem = gidx / Dc;
    int bb = bem / (Ec*Mc);
    int pos = mpos[bem] + 1;
    float v = seq[((size_t)bb*Lc + pos)*Dc + d];
    ment_bf[flin_off(bem, d, 24)] = f2bf(v);
    return;
  }
  bx -= 1536;
  const float* src; unsigned short* dst; int tk, tn, KTW;
  if (bx < 768){                     // seq [1024x768] x4 -> flin KTW=32
    int z = bx / 192, rem = bx % 192;
    src = seq + (size_t)z*Lc*Dc; dst = seqf + (size_t)z*(Dc/16)*(Lc/32)*512;
    tk = rem % 16; tn = rem / 16; KTW = 32;
  } else if (bx < 768+144){
    int rem = bx - 768;
    src = W_q; dst = Wq_f; tk = rem % 12; tn = rem / 12; KTW = 24;
  } else if (bx < 768+288){
    int rem = bx - (768+144);
    src = W_k; dst = Wk_f; tk = rem % 12; tn = rem / 12; KTW = 24;
  } else if (bx < 768+288+288){
    int rem = bx - (768+288);
    src = headW; dst = headW_f; tk = rem % 24; tn = rem / 24; KTW = 48;
  } else {
    int rem = bx - (768+288+288);
    src = tailW; dst = tailW_f; tk = rem % 24; tn = rem / 24; KTW = 48;
  }
  int r0 = tk*64, c0 = tn*64;       // r0 along K, c0 along N(=768)
  #pragma unroll
  for (int q8 = 0; q8 < 16; q8++){
    int idx = q8*256 + tid;
    int rr = idx >> 6, cc = idx & 63;
    t[rr][cc] = src[(size_t)(r0+rr)*768 + c0+cc];
  }
  __syncthreads();
  #pragma unroll
  for (int q8 = 0; q8 < 16; q8++){
    int idx = q8*256 + tid;
    int li = idx & 511, sub = idx >> 9;
    int nt_l = sub >> 1, kt_l = sub & 1;
    int lane = li >> 3, e = li & 7;
    int kl = kt_l*32 + (lane>>4)*8 + e;
    int nl = nt_l*16 + (lane&15);
    dst[ ((size_t)(c0/16 + nt_l)*KTW + (r0/32 + kt_l))*512 + li ] = f2bf(t[kl][nl]);
  }
}

// ---------------- K2: ht_att -> bf16 flin (zero pad rows 552..559) ----------------
__global__ __launch_bounds__(256) void k_ht_att(const float* __restrict__ ent_att,
                                                const int* __restrict__ hts,
                                                unsigned short* __restrict__ htbf){
  int b = blockIdx.x & 3;
  int p = blockIdx.x >> 2;          // 0..559
  unsigned short* o = htbf + (size_t)b*HT_ABS;
  int l4 = threadIdx.x*4;
  if (p >= Pc){
    us4 z4 = {0,0,0,0};
    *(us4*)(o + flin_off(p, l4, 32)) = z4;
    return;
  }
  int r = b*Pc + p;
  int hi = hts[r*2+0], ti = hts[r*2+1];
  const float* eh = ent_att + (size_t)(b*Ec+hi)*Hc*Lc;
  const float* et = ent_att + (size_t)(b*Ec+ti)*Hc*Lc;
  __shared__ float raw[Lc];
  __shared__ float wsum[4];
  float4 s4 = {0.f,0.f,0.f,0.f};
  #pragma unroll
  for (int h = 0; h < Hc; h++){
    float4 e1 = *(const float4*)&eh[h*Lc + l4];
    float4 e2 = *(const float4*)&et[h*Lc + l4];
    s4.x = fmaf(e1.x,e2.x,s4.x); s4.y = fmaf(e1.y,e2.y,s4.y);
    s4.z = fmaf(e1.z,e2.z,s4.z); s4.w = fmaf(e1.w,e2.w,s4.w);
  }
  s4.x *= (1.0f/Hc); s4.y *= (1.0f/Hc); s4.z *= (1.0f/Hc); s4.w *= (1.0f/Hc);
  *(float4*)&raw[l4] = s4;
  float lsum = s4.x+s4.y+s4.z+s4.w;
  for (int off = 32; off; off >>= 1) lsum += __shfl_down(lsum, off);
  if ((threadIdx.x & 63) == 0) wsum[threadIdx.x>>6] = lsum;
  __syncthreads();
  float inv = 1.0f/(wsum[0]+wsum[1]+wsum[2]+wsum[3] + 1e-5f);
  float4 rv = *(const float4*)&raw[l4];
  us4 v4;
  v4[0] = f2bf(rv.x*inv); v4[1] = f2bf(rv.y*inv);
  v4[2] = f2bf(rv.z*inv); v4[3] = f2bf(rv.w*inv);
  *(us4*)(o + flin_off(p, l4, 32)) = v4;
}

// ---------------- K4: flin MFMA GEMM, multi-job, W panel staged in LDS ----------------
struct FJob {
  const unsigned short* A1; const unsigned short* W; const float* bias; void* C;
  int M; int mtmax; int Wktw; int rowsPerBatch;
  size_t Abs; size_t Wbs;
};
struct FJobs {
  FJob j[6]; int xs[7]; int n;
};

// CT: 0 = fp32 (+bias), 2 = bf16 flin (KTC=24)
template<int KT1, int CT, int NT>
__global__ __launch_bounds__(256) void k_fgemmN(FJobs P){
  int tid = threadIdx.x;
  int jx = 0;
  for (int tjob = 1; tjob < P.n; tjob++)
    if ((int)blockIdx.x >= P.xs[tjob]) jx = tjob;
  FJob j = P.j[jx];
  int mbx = blockIdx.x - P.xs[jx];
  int z = blockIdx.z;
  int lane = tid & 63, wid = tid >> 6;
  int row16 = lane & 15, oct = lane >> 4;

  // ---- stage W panel (NT x KT1 frags) into LDS, shared by all 4 waves ----
  __shared__ __align__(16) unsigned short Wlds[NT*KT1*512];
  {
    const unsigned short* wpan = j.W + (size_t)z*j.Wbs + (size_t)(blockIdx.y*NT)*j.Wktw*512;
    constexpr int UNITS = NT*KT1*64;          // 16B units
    #pragma unroll
    for (int it = 0; it < UNITS/256; ++it){
      int u = it*256 + tid;
      int f = u >> 6;                          // frag index
      int n = f / KT1, kt = f - n*KT1;
      size_t so = (((size_t)(n*j.Wktw + kt)) << 9) + (size_t)((u & 63) << 3);
      __builtin_amdgcn_global_load_lds(
          (const __attribute__((address_space(1))) unsigned int*)(wpan + so),
          (__attribute__((address_space(3))) unsigned int*)((char*)Wlds + (size_t)u*16),
          16, 0, 0);
    }
  }

  int rb = mbx*128 + wid*32;
  int mt0 = rb >> 4;       if (mt0 >= j.mtmax) mt0 = j.mtmax - 1;
  int mt1 = (rb >> 4) + 1; if (mt1 >= j.mtmax) mt1 = j.mtmax - 1;
  const unsigned short* ap0 = j.A1 + (size_t)z*j.Abs + (size_t)mt0*KT1*512 + lane*8;
  const unsigned short* ap1 = j.A1 + (size_t)z*j.Abs + (size_t)mt1*KT1*512 + lane*8;
  f32x4 acc[2][NT];
  #pragma unroll
  for (int m = 0; m < 2; m++)
    #pragma unroll
    for (int n = 0; n < NT; n++) acc[m][n] = (f32x4){0.f,0.f,0.f,0.f};

  __syncthreads();    // W staged (drains vmcnt)

  #pragma unroll 4
  for (int kt = 0; kt < KT1; kt++){
    short8 a0 = *(const short8*)(ap0 + (size_t)kt*512);
    short8 a1 = *(const short8*)(ap1 + (size_t)kt*512);
    #pragma unroll
    for (int n = 0; n < NT; n++){
      short8 bv = *(const short8*)&Wlds[(n*KT1 + kt)*512 + lane*8];
      acc[0][n] = __builtin_amdgcn_mfma_f32_16x16x32_bf16(a0, bv, acc[0][n], 0, 0, 0);
      acc[1][n] = __builtin_amdgcn_mfma_f32_16x16x32_bf16(a1, bv, acc[1][n], 0, 0, 0);
    }
  }
  int colb = blockIdx.y*(NT*16);
  #pragma unroll
  for (int m = 0; m < 2; m++)
    #pragma unroll
    for (int n = 0; n < NT; n++)
      #pragma unroll
      for (int jj = 0; jj < 4; jj++){
        int r = rb + m*16 + oct*4 + jj;
        if (r < j.M){
          int col = colb + n*16 + row16;
          float v = acc[m][n][jj];
          if (CT == 0 && j.bias) v += j.bias[col];
          int rg = z*j.rowsPerBatch + r;
          if (CT == 2){
            ((unsigned short*)j.C)[flin_off(rg, col, 24)] = f2bf(v);
          } else {
            ((float*)j.C)[(size_t)rg*768 + col] = v;
          }
        }
      }
}

// ---------------- K6: pool v2 — softmax weights + distributed head/tail combine ----------------
__global__ __launch_bounds__(256) void k_pool(const float* __restrict__ kment,
                                              const float* __restrict__ q_c,
                                              const float* __restrict__ rsWh,
                                              const float* __restrict__ rsWt,
                                              const float* __restrict__ mWh,
                                              const float* __restrict__ mWt,
                                              const float* __restrict__ headb,
                                              const float* __restrict__ tailb,
                                              const int* __restrict__ hts,
                                              unsigned short* __restrict__ hs16,
                                              unsigned short* __restrict__ ts16){
  int wid = threadIdx.x >> 6, lane = threadIdx.x & 63;
  int r = blockIdx.x*4 + wid;
  int b = r / Pc;
  float q[12];
  const float* qp = q_c + (size_t)r*Dc + lane;
  #pragma unroll
  for (int u = 0; u < 12; u++) q[u] = qp[u*64];
  const float invs = 0.03608439182435161f;  // 1/sqrt(768)
  #pragma unroll
  for (int side = 0; side < 2; side++){
    int e = hts[r*2+side];
    const float* kb = kment + (size_t)(b*Ec+e)*Mc*Dc + lane;
    float part[Mc] = {0.f,0.f,0.f,0.f};
    #pragma unroll
    for (int m = 0; m < Mc; m++)
      #pragma unroll
      for (int u = 0; u < 12; u++)
        part[m] = fmaf(kb[m*Dc + u*64], q[u], part[m]);
    #pragma unroll
    for (int m = 0; m < Mc; m++)
      #pragma unroll
      for (int off = 1; off < 64; off <<= 1)
        part[m] += __shfl_xor(part[m], off);
    float mx = fmaxf(fmaxf(part[0],part[1]), fmaxf(part[2],part[3])) * invs;
    float w0 = expf(part[0]*invs - mx), w1 = expf(part[1]*invs - mx);
    float w2 = expf(part[2]*invs - mx), w3 = expf(part[3]*invs - mx);
    float isum = 1.0f/(w0+w1+w2+w3);
    w0 *= isum; w1 *= isum; w2 *= isum; w3 *= isum;
    const float* mW  = (side ? mWt  : mWh) + (size_t)(b*Ec+e)*Mc*Dc;
    const float* rsW = (side ? rsWt : rsWh) + (size_t)r*Dc;
    const float* bias = side ? tailb : headb;
    unsigned short* o = (side ? ts16 : hs16) + (size_t)r*Dc;
    #pragma unroll
    for (int u = 0; u < 12; u++){
      int d = lane + u*64;
      float v = rsW[d] + bias[d]
              + w0*mW[d] + w1*mW[Dc+d] + w2*mW[2*Dc+d] + w3*mW[3*Dc+d];
      o[d] = f2h(tanhf(v));
    }
  }
}

// ---------------- K8: MFMA bilinear fp16, 4 m-frags/wave, KSPL=48, fp16 partial ----------------
__global__ __launch_bounds__(256) void k_bilinear_mfma(
    const unsigned short* __restrict__ hs16, const unsigned short* __restrict__ ts16,
    const unsigned short* __restrict__ Wbf,
    unsigned short* __restrict__ partial)
{
  int mb = blockIdx.x / KSPL;
  int kb = blockIdx.x % KSPL;
  int k  = kb >> 2;             // EMB block 0..11
  int i0 = (kb & 3) * 16;       // i sub-range (16 wide)

  int tid  = threadIdx.x;
  int lane = tid & 63;
  int wid  = tid >> 6;
  int row16 = lane & 15;
  int oct   = lane >> 4;

  int rbase = mb*256 + wid*64;

  __shared__ __align__(16) unsigned short Wlds[2][8960];

  f16x8 tsh[4][2];  // [m][jhalf]
  f16x8 hsh[4][2];  // [m][q], i = q*8 + e  (16 i-values)
  #pragma unroll
  for (int m = 0; m < 4; m++){
    int r = rbase + m*16 + row16; if (r > Rc-1) r = Rc-1;
    const unsigned short* tp = ts16 + (size_t)r*EMBc + k*64;
    tsh[m][0] = __builtin_bit_cast(f16x8, *(const short8*)(tp + oct*8));
    tsh[m][1] = __builtin_bit_cast(f16x8, *(const short8*)(tp + 32 + oct*8));
    const unsigned short* hp = hs16 + (size_t)r*EMBc + k*64 + i0;
    hsh[m][0] = __builtin_bit_cast(f16x8, *(const short8*)(hp));
    hsh[m][1] = __builtin_bit_cast(f16x8, *(const short8*)(hp + 8));
  }

  const char* wsrc = (const char*)(Wbf + ((size_t)(k*128 + i0*2))*4480);

  #pragma unroll
  for (int rr = 0; rr < 5; rr++){
    int u = tid + rr*256;
    if (u < 1120)
      __builtin_amdgcn_global_load_lds(
        (const __attribute__((address_space(1))) unsigned int*)(wsrc + (size_t)u*16),
        (__attribute__((address_space(3))) unsigned int*)((char*)&Wlds[0][0] + u*16),
        16, 0, 0);
  }

  f32x4 acc[4][7];
  #pragma unroll
  for (int m = 0; m < 4; m++)
    #pragma unroll
    for (int n = 0; n < 7; n++) acc[m][n] = (f32x4){0.f,0.f,0.f,0.f};

  __syncthreads();   // pair 0 staged

  #pragma unroll
  for (int cp = 0; cp < 16; cp++){    // pair cp = chunks (i=cp, jh=0/1)
    int cur = cp & 1;
    if (cp < 15){
      const char* nsrc = wsrc + (size_t)(cp+1)*17920;
      #pragma unroll
      for (int rr = 0; rr < 5; rr++){
        int u = tid + rr*256;
        if (u < 1120)
          __builtin_amdgcn_global_load_lds(
            (const __attribute__((address_space(1))) unsigned int*)(nsrc + (size_t)u*16),
            (__attribute__((address_space(3))) unsigned int*)((char*)&Wlds[cur^1][0] + u*16),
            16, 0, 0);
      }
    }
    #pragma unroll
    for (int half = 0; half < 2; half++){
      f16x8 af[4];
      #pragma unroll
      for (int m = 0; m < 4; m++){
        _Float16 hv = hsh[m][cp>>3][cp&7];       // static after full unroll
        f16x8 hvb = {hv,hv,hv,hv,hv,hv,hv,hv};
        af[m] = tsh[m][half] * hvb;              // 4x v_pk_mul_f16
      }
      #pragma unroll
      for (int n = 0; n < 7; n++){
        f16x8 bfr = __builtin_bit_cast(f16x8,
            *(const short8*)&Wlds[cur][half*4480 + (n*16 + row16)*40 + oct*8]);
        #pragma unroll
        for (int m = 0; m < 4; m++)
          acc[m][n] = __builtin_amdgcn_mfma_f32_16x16x32_f16(af[m], bfr, acc[m][n], 0, 0, 0);
      }
    }
    __syncthreads();
  }

  unsigned short* pk = partial + (size_t)kb*Rc*NLc;
  #pragma unroll
  for (int m = 0; m < 4; m++){
    #pragma unroll
    for (int n = 0; n < 7; n++){
      #pragma unroll
      for (int j = 0; j < 4; j++){
        int r = rbase + m*16 + oct*4 + j;
        int col = n*16 + row16;
        if (r < Rc && col < NLc)
          pk[(size_t)r*NLc + col] = f2h(acc[m][n][j]);
      }
    }
  }
}

// ---------------- K9: sum fp16 partials + bias ----------------
__global__ __launch_bounds__(256) void k_reduce(const unsigned short* __restrict__ partial,
                                                const float* __restrict__ bilb,
                                                float* __restrict__ out){
  int idx = blockIdx.x*256 + threadIdx.x;
  if (idx >= Rc*NLc) return;
  int n = idx % NLc;
  float s = bilb[n];
  #pragma unroll
  for (int ks = 0; ks < KSPL; ks++) s += h2f(partial[(size_t)ks*Rc*NLc + idx]);
  out[idx] = s;
}

extern "C" void kernel_launch(void* const* d_in, const int* in_sizes, int n_in,
                              void* d_out, int out_size, void* d_ws, size_t ws_size,
                              hipStream_t stream){
  const float* seq   = (const float*)d_in[0];
  const float* att   = (const float*)d_in[1];
  const float* W_q   = (const float*)d_in[2];
  const float* W_k   = (const float*)d_in[3];
  const float* headW = (const float*)d_in[4];
  const float* headb = (const float*)d_in[5];
  const float* tailW = (const float*)d_in[6];
  const float* tailb = (const float*)d_in[7];
  const float* bilW  = (const float*)d_in[8];
  const float* bilb  = (const float*)d_in[9];
  const int*   mpos  = (const int*)d_in[10];
  const int*   hts   = (const int*)d_in[11];
  float* out = (float*)d_out;

  float* ws = (float*)d_ws;
  float* ent_att = ws;                                      // 1,179,648 f
  float* q_c     = ws + 1179648;                            // 1,695,744 f
  float* kment   = q_c + 1695744;                           //   294,912 f
  float* ment_unused = kment + 294912;                      //   294,912 f (layout keep)
  unsigned short* seqf    = (unsigned short*)(ment_unused + 294912); // 3,145,728 sh
  unsigned short* htbf    = seqf + 3145728;                     // 2,293,760 sh
  unsigned short* rs_bf   = htbf + 4*HT_ABS;                    // 1,695,744 sh
  unsigned short* ment_bf = rs_bf + 1695744;                    //   294,912 sh
  unsigned short* Wq_f    = ment_bf + 294912;                   //   589,824 sh
  unsigned short* Wk_f    = Wq_f + 589824;                      //   589,824 sh
  unsigned short* headW_f = Wk_f + 589824;                      // 1,179,648 sh
  unsigned short* tailW_f = headW_f + 1179648;                  // 1,179,648 sh
  unsigned short* hs16 = tailW_f + 1179648;                 // 1,695,744 sh (fp16 row-major)
  unsigned short* ts16 = hs16 + 1695744;                    // 1,695,744 sh
  unsigned short* Wbf  = ts16 + 1695744;                    // 6,881,280 sh (fp16)
  float* rsWh = (float*)(Wbf + 6881280);                    // 1,695,744 f
  float* rsWt = rsWh + 1695744;                             // 1,695,744 f
  float* mWh  = rsWt + 1695744;                             //   294,912 f
  float* mWt  = mWh + 294912;                               //   294,912 f
  unsigned short* partial = (unsigned short*)ws;
  // fp16 partial: 48*2208*97 = 10,280,448 sh = 20.6 MB; overlapped region is dead
  // before the bilinear: safe.

  k_prep   <<<4320, 256, 0, stream>>>(bilW, Wbf, seq, seqf, W_q, Wq_f, W_k, Wk_f,
                                      headW, headW_f, tailW, tailW_f,
                                      att, mpos, ent_att, ment_bf);
  k_ht_att <<<4*560, 256, 0, stream>>>(ent_att, hts, htbf);
  {
    FJobs P{};
    P.j[0] = { htbf, seqf, nullptr, rs_bf, Pc, 35, 32, Pc,
               (size_t)HT_ABS, (size_t)(48*32*512) };
    P.xs[0] = 0; P.xs[1] = 5; P.n = 1;
    k_fgemmN<32,2,2><<<dim3(5,24,4), 256, 0, stream>>>(P);
  }
  {
    FJobs P{};
    P.j[0] = { rs_bf,   Wq_f,              nullptr, q_c,   Rc,  138, 24, 0, 0, 0 };
    P.j[1] = { ment_bf, Wk_f,              nullptr, kment, 384,  24, 24, 0, 0, 0 };
    P.j[2] = { rs_bf,   headW_f + 24*512,  nullptr, rsWh,  Rc,  138, 48, 0, 0, 0 };
    P.j[3] = { rs_bf,   tailW_f + 24*512,  nullptr, rsWt,  Rc,  138, 48, 0, 0, 0 };
    P.j[4] = { ment_bf, headW_f,           nullptr, mWh,   384,  24, 48, 0, 0, 0 };
    P.j[5] = { ment_bf, tailW_f,           nullptr, mWt,   384,  24, 48, 0, 0, 0 };
    P.xs[0]=0; P.xs[1]=18; P.xs[2]=21; P.xs[3]=39; P.xs[4]=57; P.xs[5]=60; P.xs[6]=63;
    P.n = 6;
    k_fgemmN<24,0,2><<<dim3(63,24), 256, 0, stream>>>(P);
  }
  k_pool   <<<Rc/4, 256, 0, stream>>>(kment, q_c, rsWh, rsWt, mWh, mWt,
                                      headb, tailb, hts, hs16, ts16);
  k_bilinear_mfma<<<9*KSPL, 256, 0, stream>>>(hs16, ts16, Wbf, partial);
  k_reduce <<<(Rc*NLc+255)/256, 256, 0, stream>>>(partial, bilb, out);
}

// Round 15
// 122.315 us; speedup vs baseline: 1.7598x; 1.0660x over previous
//
#include <hip/hip_runtime.h>
#include <hip/hip_bf16.h>
#include <math.h>

#define Bc 4
#define Lc 1024
#define Dc 768
#define Hc 12
#define Ec 24
#define Mc 4
#define Pc 552
#define EMBc 768
#define NLc 97
#define Rc (Bc*Pc)      // 2208
#define KSPL 48         // bilinear: 12 k-blocks x 4 i-splits of 16
#define HT_ABS (35*32*512)   // htbf flin per-batch stride (shorts)

typedef __attribute__((ext_vector_type(4))) float f32x4;
typedef __attribute__((ext_vector_type(8))) short short8;
typedef __attribute__((ext_vector_type(4))) unsigned short us4;
typedef _Float16 f16x8 __attribute__((ext_vector_type(8)));

static __device__ __forceinline__ unsigned short f2bf(float x){
  unsigned int u = __float_as_uint(x);
  unsigned int r = u + 0x7fffu + ((u >> 16) & 1u);   // RNE
  return (unsigned short)(r >> 16);
}
static __device__ __forceinline__ unsigned short f2h(float x){
  _Float16 h = (_Float16)x;
  return __builtin_bit_cast(unsigned short, h);
}
static __device__ __forceinline__ float h2f(unsigned short x){
  return (float)__builtin_bit_cast(_Float16, x);
}
// flin index: row r, k-index kk, KT = K/32 chunks
static __device__ __forceinline__ size_t flin_off(int r, int kk, int KT){
  return ((size_t)(r>>4)*KT + (kk>>5))*512 + (size_t)((((kk&31)>>3)*16 + (r&15))*8) + (kk&7);
}

// ---------------- K0: weight prep + ent_att + mention gather (one launch) ----------------
__global__ __launch_bounds__(256) void k_prep(const float* __restrict__ bilW, unsigned short* __restrict__ Wbf,
                                              const float* __restrict__ seq, unsigned short* __restrict__ seqf,
                                              const float* __restrict__ W_q, unsigned short* __restrict__ Wq_f,
                                              const float* __restrict__ W_k, unsigned short* __restrict__ Wk_f,
                                              const float* __restrict__ headW, unsigned short* __restrict__ headW_f,
                                              const float* __restrict__ tailW, unsigned short* __restrict__ tailW_f,
                                              const float* __restrict__ att, const int* __restrict__ mpos,
                                              float* __restrict__ ent_att,
                                              unsigned short* __restrict__ ment_bf){
  int bx = blockIdx.x;
  int tid = threadIdx.x;
  __shared__ float t[64][65];     // shared by transpose path and bilW path
  if (bx < 1536){
    const float* Ws = bilW + (size_t)bx*32*NLc;   // 3104 contiguous floats
    unsigned short* o = Wbf + (size_t)bx*4480;
    float* w = &t[0][0];                          // 3104 <= 4160
    for (int idx = tid; idx < 32*NLc; idx += 256)
      w[idx] = Ws[idx];
    __syncthreads();
    #pragma unroll
    for (int q8 = 0; q8 < 18; q8++){
      int idx = q8*256 + tid;
      if (idx < 4480){
        int n = idx / 40, kk = idx - n*40;
        float v = (kk < 32 && n < NLc) ? w[kk*NLc + n] : 0.f;
        o[idx] = f2h(v);
      }
    }
    return;
  }
  if (bx >= 3168){                  // ent_att + gather
    int blk = bx - 3168;            // (b*E+e)*H + h, 1152 blocks
    int h  = blk % Hc;
    int be = blk / Hc;
    int b  = be / Ec;
    int p0 = mpos[be*Mc+0]+1, p1 = mpos[be*Mc+1]+1;
    int p2 = mpos[be*Mc+2]+1, p3 = mpos[be*Mc+3]+1;
    const float* ab = att + ((size_t)b*Hc + h)*Lc*Lc;
    const float* a0 = ab + (size_t)p0*Lc;
    const float* a1 = ab + (size_t)p1*Lc;
    const float* a2 = ab + (size_t)p2*Lc;
    const float* a3 = ab + (size_t)p3*Lc;
    float* o = ent_att + (size_t)blk*Lc;
    int l4 = tid*4;
    float4 v0 = *(const float4*)(a0 + l4);
    float4 v1 = *(const float4*)(a1 + l4);
    float4 v2 = *(const float4*)(a2 + l4);
    float4 v3 = *(const float4*)(a3 + l4);
    float4 ov;
    ov.x = 0.25f*(v0.x+v1.x+v2.x+v3.x);
    ov.y = 0.25f*(v0.y+v1.y+v2.y+v3.y);
    ov.z = 0.25f*(v0.z+v1.z+v2.z+v3.z);
    ov.w = 0.25f*(v0.w+v1.w+v2.w+v3.w);
    *(float4*)(o + l4) = ov;
    int gidx = blk*256 + tid;       // over B*E*M*D
    int d = gidx % Dc;
    int bem = gidx / Dc;
    int bb = bem / (Ec*Mc);
    int pos = mpos[bem] + 1;
    float v = seq[((size_t)bb*Lc + pos)*Dc + d];
    ment_bf[flin_off(bem, d, 24)] = f2bf(v);
    return;
  }
  bx -= 1536;
  const float* src; unsigned short* dst; int tk, tn, KTW;
  if (bx < 768){                     // seq [1024x768] x4 -> flin KTW=32
    int z = bx / 192, rem = bx % 192;
    src = seq + (size_t)z*Lc*Dc; dst = seqf + (size_t)z*(Dc/16)*(Lc/32)*512;
    tk = rem % 16; tn = rem / 16; KTW = 32;
  } else if (bx < 768+144){
    int rem = bx - 768;
    src = W_q; dst = Wq_f; tk = rem % 12; tn = rem / 12; KTW = 24;
  } else if (bx < 768+288){
    int rem = bx - (768+144);
    src = W_k; dst = Wk_f; tk = rem % 12; tn = rem / 12; KTW = 24;
  } else if (bx < 768+288+288){
    int rem = bx - (768+288);
    src = headW; dst = headW_f; tk = rem % 24; tn = rem / 24; KTW = 48;
  } else {
    int rem = bx - (768+288+288);
    src = tailW; dst = tailW_f; tk = rem % 24; tn = rem / 24; KTW = 48;
  }
  int r0 = tk*64, c0 = tn*64;       // r0 along K, c0 along N(=768)
  #pragma unroll
  for (int q8 = 0; q8 < 16; q8++){
    int idx = q8*256 + tid;
    int rr = idx >> 6, cc = idx & 63;
    t[rr][cc] = src[(size_t)(r0+rr)*768 + c0+cc];
  }
  __syncthreads();
  #pragma unroll
  for (int q8 = 0; q8 < 16; q8++){
    int idx = q8*256 + tid;
    int li = idx & 511, sub = idx >> 9;
    int nt_l = sub >> 1, kt_l = sub & 1;
    int lane = li >> 3, e = li & 7;
    int kl = kt_l*32 + (lane>>4)*8 + e;
    int nl = nt_l*16 + (lane&15);
    dst[ ((size_t)(c0/16 + nt_l)*KTW + (r0/32 + kt_l))*512 + li ] = f2bf(t[kl][nl]);
  }
}

// ---------------- K2: ht_att -> bf16 flin (zero pad rows 552..559) ----------------
__global__ __launch_bounds__(256) void k_ht_att(const float* __restrict__ ent_att,
                                                const int* __restrict__ hts,
                                                unsigned short* __restrict__ htbf){
  int b = blockIdx.x & 3;
  int p = blockIdx.x >> 2;          // 0..559
  unsigned short* o = htbf + (size_t)b*HT_ABS;
  int l4 = threadIdx.x*4;
  if (p >= Pc){
    us4 z4 = {0,0,0,0};
    *(us4*)(o + flin_off(p, l4, 32)) = z4;
    return;
  }
  int r = b*Pc + p;
  int hi = hts[r*2+0], ti = hts[r*2+1];
  const float* eh = ent_att + (size_t)(b*Ec+hi)*Hc*Lc;
  const float* et = ent_att + (size_t)(b*Ec+ti)*Hc*Lc;
  __shared__ float raw[Lc];
  __shared__ float wsum[4];
  float4 s4 = {0.f,0.f,0.f,0.f};
  #pragma unroll
  for (int h = 0; h < Hc; h++){
    float4 e1 = *(const float4*)&eh[h*Lc + l4];
    float4 e2 = *(const float4*)&et[h*Lc + l4];
    s4.x = fmaf(e1.x,e2.x,s4.x); s4.y = fmaf(e1.y,e2.y,s4.y);
    s4.z = fmaf(e1.z,e2.z,s4.z); s4.w = fmaf(e1.w,e2.w,s4.w);
  }
  s4.x *= (1.0f/Hc); s4.y *= (1.0f/Hc); s4.z *= (1.0f/Hc); s4.w *= (1.0f/Hc);
  *(float4*)&raw[l4] = s4;
  float lsum = s4.x+s4.y+s4.z+s4.w;
  for (int off = 32; off; off >>= 1) lsum += __shfl_down(lsum, off);
  if ((threadIdx.x & 63) == 0) wsum[threadIdx.x>>6] = lsum;
  __syncthreads();
  float inv = 1.0f/(wsum[0]+wsum[1]+wsum[2]+wsum[3] + 1e-5f);
  float4 rv = *(const float4*)&raw[l4];
  us4 v4;
  v4[0] = f2bf(rv.x*inv); v4[1] = f2bf(rv.y*inv);
  v4[2] = f2bf(rv.z*inv); v4[3] = f2bf(rv.w*inv);
  *(us4*)(o + flin_off(p, l4, 32)) = v4;
}

// ---------------- K4: flin MFMA GEMM, multi-job, K-chunked W staging in LDS ----------------
struct FJob {
  const unsigned short* A1; const unsigned short* W; const float* bias; void* C;
  int M; int mtmax; int Wktw; int rowsPerBatch;
  size_t Abs; size_t Wbs;
};
struct FJobs {
  FJob j[6]; int xs[7]; int n;
};

// CT: 0 = fp32 (+bias), 2 = bf16 flin (KTC=24), 3 = fp16 row-major
template<int KT1, int CT, int NT, int KCH>
__global__ __launch_bounds__(256) void k_fgemmN(FJobs P){
  int tid = threadIdx.x;
  int jx = 0;
  for (int tjob = 1; tjob < P.n; tjob++)
    if ((int)blockIdx.x >= P.xs[tjob]) jx = tjob;
  FJob j = P.j[jx];
  int mbx = blockIdx.x - P.xs[jx];
  int z = blockIdx.z;
  int lane = tid & 63, wid = tid >> 6;
  int row16 = lane & 15, oct = lane >> 4;

  __shared__ __align__(16) unsigned short Wlds[NT*KCH*512];
  const unsigned short* wpan = j.W + (size_t)z*j.Wbs + (size_t)(blockIdx.y*NT)*j.Wktw*512;

  int rb = mbx*128 + wid*32;
  int mt0 = rb >> 4;       if (mt0 >= j.mtmax) mt0 = j.mtmax - 1;
  int mt1 = (rb >> 4) + 1; if (mt1 >= j.mtmax) mt1 = j.mtmax - 1;
  const unsigned short* ap0 = j.A1 + (size_t)z*j.Abs + (size_t)mt0*KT1*512 + lane*8;
  const unsigned short* ap1 = j.A1 + (size_t)z*j.Abs + (size_t)mt1*KT1*512 + lane*8;
  f32x4 acc[2][NT];
  #pragma unroll
  for (int m = 0; m < 2; m++)
    #pragma unroll
    for (int n = 0; n < NT; n++) acc[m][n] = (f32x4){0.f,0.f,0.f,0.f};

  #pragma unroll
  for (int kc = 0; kc < KT1/KCH; kc++){
    {
      constexpr int UNITS = NT*KCH*64;          // 16B units
      #pragma unroll
      for (int it = 0; it < UNITS/256; ++it){
        int u = it*256 + tid;
        int f = u >> 6;                          // frag index within chunk
        int n = f / KCH, kt = f - n*KCH;
        size_t so = (((size_t)(n*j.Wktw + kc*KCH + kt)) << 9) + (size_t)((u & 63) << 3);
        __builtin_amdgcn_global_load_lds(
            (const __attribute__((address_space(1))) unsigned int*)(wpan + so),
            (__attribute__((address_space(3))) unsigned int*)((char*)Wlds + (size_t)u*16),
            16, 0, 0);
      }
    }
    __syncthreads();    // chunk staged (drains vmcnt)
    #pragma unroll 4
    for (int k2 = 0; k2 < KCH; k2++){
      int kt = kc*KCH + k2;
      short8 a0 = *(const short8*)(ap0 + (size_t)kt*512);
      short8 a1 = *(const short8*)(ap1 + (size_t)kt*512);
      #pragma unroll
      for (int n = 0; n < NT; n++){
        short8 bv = *(const short8*)&Wlds[(n*KCH + k2)*512 + lane*8];
        acc[0][n] = __builtin_amdgcn_mfma_f32_16x16x32_bf16(a0, bv, acc[0][n], 0, 0, 0);
        acc[1][n] = __builtin_amdgcn_mfma_f32_16x16x32_bf16(a1, bv, acc[1][n], 0, 0, 0);
      }
    }
    if (kc + 1 < KT1/KCH) __syncthreads();   // all reads done before re-stage
  }

  int colb = blockIdx.y*(NT*16);
  #pragma unroll
  for (int m = 0; m < 2; m++)
    #pragma unroll
    for (int n = 0; n < NT; n++)
      #pragma unroll
      for (int jj = 0; jj < 4; jj++){
        int r = rb + m*16 + oct*4 + jj;
        if (r < j.M){
          int col = colb + n*16 + row16;
          float v = acc[m][n][jj];
          if (CT == 0 && j.bias) v += j.bias[col];
          int rg = z*j.rowsPerBatch + r;
          if (CT == 2){
            ((unsigned short*)j.C)[flin_off(rg, col, 24)] = f2bf(v);
          } else if (CT == 3){
            ((unsigned short*)j.C)[(size_t)rg*768 + col] = f2h(v);
          } else {
            ((float*)j.C)[(size_t)rg*768 + col] = v;
          }
        }
      }
}

// ---------------- K6: pool v2 (fp16 inputs) ----------------
__global__ __launch_bounds__(256) void k_pool(const unsigned short* __restrict__ km16,
                                              const unsigned short* __restrict__ q16,
                                              const unsigned short* __restrict__ rsWh16,
                                              const unsigned short* __restrict__ rsWt16,
                                              const unsigned short* __restrict__ mWh16,
                                              const unsigned short* __restrict__ mWt16,
                                              const float* __restrict__ headb,
                                              const float* __restrict__ tailb,
                                              const int* __restrict__ hts,
                                              unsigned short* __restrict__ hs16,
                                              unsigned short* __restrict__ ts16){
  int wid = threadIdx.x >> 6, lane = threadIdx.x & 63;
  int r = blockIdx.x*4 + wid;
  int b = r / Pc;
  float q[12];
  const unsigned short* qp = q16 + (size_t)r*Dc + lane;
  #pragma unroll
  for (int u = 0; u < 12; u++) q[u] = h2f(qp[u*64]);
  const float invs = 0.03608439182435161f;  // 1/sqrt(768)
  #pragma unroll
  for (int side = 0; side < 2; side++){
    int e = hts[r*2+side];
    const unsigned short* kb = km16 + (size_t)(b*Ec+e)*Mc*Dc + lane;
    float part[Mc] = {0.f,0.f,0.f,0.f};
    #pragma unroll
    for (int m = 0; m < Mc; m++)
      #pragma unroll
      for (int u = 0; u < 12; u++)
        part[m] = fmaf(h2f(kb[m*Dc + u*64]), q[u], part[m]);
    #pragma unroll
    for (int m = 0; m < Mc; m++)
      #pragma unroll
      for (int off = 1; off < 64; off <<= 1)
        part[m] += __shfl_xor(part[m], off);
    float mx = fmaxf(fmaxf(part[0],part[1]), fmaxf(part[2],part[3])) * invs;
    float w0 = expf(part[0]*invs - mx), w1 = expf(part[1]*invs - mx);
    float w2 = expf(part[2]*invs - mx), w3 = expf(part[3]*invs - mx);
    float isum = 1.0f/(w0+w1+w2+w3);
    w0 *= isum; w1 *= isum; w2 *= isum; w3 *= isum;
    const unsigned short* mW  = (side ? mWt16  : mWh16) + (size_t)(b*Ec+e)*Mc*Dc;
    const unsigned short* rsW = (side ? rsWt16 : rsWh16) + (size_t)r*Dc;
    const float* bias = side ? tailb : headb;
    unsigned short* o = (side ? ts16 : hs16) + (size_t)r*Dc;
    #pragma unroll
    for (int u = 0; u < 12; u++){
      int d = lane + u*64;
      float v = h2f(rsW[d]) + bias[d]
              + w0*h2f(mW[d]) + w1*h2f(mW[Dc+d]) + w2*h2f(mW[2*Dc+d]) + w3*h2f(mW[3*Dc+d]);
      o[d] = f2h(tanhf(v));
    }
  }
}

// ---------------- K8: MFMA bilinear fp16, 4 m-frags/wave, KSPL=48, fp16 partial ----------------
__global__ __launch_bounds__(256) void k_bilinear_mfma(
    const unsigned short* __restrict__ hs16, const unsigned short* __restrict__ ts16,
    const unsigned short* __restrict__ Wbf,
    unsigned short* __restrict__ partial)
{
  int mb = blockIdx.x / KSPL;
  int kb = blockIdx.x % KSPL;
  int k  = kb >> 2;             // EMB block 0..11
  int i0 = (kb & 3) * 16;       // i sub-range (16 wide)

  int tid  = threadIdx.x;
  int lane = tid & 63;
  int wid  = tid >> 6;
  int row16 = lane & 15;
  int oct   = lane >> 4;

  int rbase = mb*256 + wid*64;

  __shared__ __align__(16) unsigned short Wlds[2][8960];

  f16x8 tsh[4][2];  // [m][jhalf]
  f16x8 hsh[4][2];  // [m][q], i = q*8 + e  (16 i-values)
  #pragma unroll
  for (int m = 0; m < 4; m++){
    int r = rbase + m*16 + row16; if (r > Rc-1) r = Rc-1;
    const unsigned short* tp = ts16 + (size_t)r*EMBc + k*64;
    tsh[m][0] = __builtin_bit_cast(f16x8, *(const short8*)(tp + oct*8));
    tsh[m][1] = __builtin_bit_cast(f16x8, *(const short8*)(tp + 32 + oct*8));
    const unsigned short* hp = hs16 + (size_t)r*EMBc + k*64 + i0;
    hsh[m][0] = __builtin_bit_cast(f16x8, *(const short8*)(hp));
    hsh[m][1] = __builtin_bit_cast(f16x8, *(const short8*)(hp + 8));
  }

  const char* wsrc = (const char*)(Wbf + ((size_t)(k*128 + i0*2))*4480);

  #pragma unroll
  for (int rr = 0; rr < 5; rr++){
    int u = tid + rr*256;
    if (u < 1120)
      __builtin_amdgcn_global_load_lds(
        (const __attribute__((address_space(1))) unsigned int*)(wsrc + (size_t)u*16),
        (__attribute__((address_space(3))) unsigned int*)((char*)&Wlds[0][0] + u*16),
        16, 0, 0);
  }

  f32x4 acc[4][7];
  #pragma unroll
  for (int m = 0; m < 4; m++)
    #pragma unroll
    for (int n = 0; n < 7; n++) acc[m][n] = (f32x4){0.f,0.f,0.f,0.f};

  __syncthreads();   // pair 0 staged

  #pragma unroll
  for (int cp = 0; cp < 16; cp++){    // pair cp = chunks (i=cp, jh=0/1)
    int cur = cp & 1;
    if (cp < 15){
      const char* nsrc = wsrc + (size_t)(cp+1)*17920;
      #pragma unroll
      for (int rr = 0; rr < 5; rr++){
        int u = tid + rr*256;
        if (u < 1120)
          __builtin_amdgcn_global_load_lds(
            (const __attribute__((address_space(1))) unsigned int*)(nsrc + (size_t)u*16),
            (__attribute__((address_space(3))) unsigned int*)((char*)&Wlds[cur^1][0] + u*16),
            16, 0, 0);
      }
    }
    #pragma unroll
    for (int half = 0; half < 2; half++){
      f16x8 af[4];
      #pragma unroll
      for (int m = 0; m < 4; m++){
        _Float16 hv = hsh[m][cp>>3][cp&7];       // static after full unroll
        f16x8 hvb = {hv,hv,hv,hv,hv,hv,hv,hv};
        af[m] = tsh[m][half] * hvb;              // 4x v_pk_mul_f16
      }
      #pragma unroll
      for (int n = 0; n < 7; n++){
        f16x8 bfr = __builtin_bit_cast(f16x8,
            *(const short8*)&Wlds[cur][half*4480 + (n*16 + row16)*40 + oct*8]);
        #pragma unroll
        for (int m = 0; m < 4; m++)
          acc[m][n] = __builtin_amdgcn_mfma_f32_16x16x32_f16(af[m], bfr, acc[m][n], 0, 0, 0);
      }
    }
    __syncthreads();
  }

  unsigned short* pk = partial + (size_t)kb*Rc*NLc;
  #pragma unroll
  for (int m = 0; m < 4; m++){
    #pragma unroll
    for (int n = 0; n < 7; n++){
      #pragma unroll
      for (int j = 0; j < 4; j++){
        int r = rbase + m*16 + oct*4 + j;
        int col = n*16 + row16;
        if (r < Rc && col < NLc)
          pk[(size_t)r*NLc + col] = f2h(acc[m][n][j]);
      }
    }
  }
}

// ---------------- K9: sum fp16 partials + bias ----------------
__global__ __launch_bounds__(256) void k_reduce(const unsigned short* __restrict__ partial,
                                                const float* __restrict__ bilb,
                                                float* __restrict__ out){
  int idx = blockIdx.x*256 + threadIdx.x;
  if (idx >= Rc*NLc) return;
  int n = idx % NLc;
  float s = bilb[n];
  #pragma unroll
  for (int ks = 0; ks < KSPL; ks++) s += h2f(partial[(size_t)ks*Rc*NLc + idx]);
  out[idx] = s;
}

extern "C" void kernel_launch(void* const* d_in, const int* in_sizes, int n_in,
                              void* d_out, int out_size, void* d_ws, size_t ws_size,
                              hipStream_t stream){
  const float* seq   = (const float*)d_in[0];
  const float* att   = (const float*)d_in[1];
  const float* W_q   = (const float*)d_in[2];
  const float* W_k   = (const float*)d_in[3];
  const float* headW = (const float*)d_in[4];
  const float* headb = (const float*)d_in[5];
  const float* tailW = (const float*)d_in[6];
  const float* tailb = (const float*)d_in[7];
  const float* bilW  = (const float*)d_in[8];
  const float* bilb  = (const float*)d_in[9];
  const int*   mpos  = (const int*)d_in[10];
  const int*   hts   = (const int*)d_in[11];
  float* out = (float*)d_out;

  float* ws = (float*)d_ws;
  float* ent_att = ws;                                      // 1,179,648 f (= 2,359,296 sh)
  unsigned short* base = (unsigned short*)(ws + 1179648);
  unsigned short* q16     = base;                           // 1,695,744 sh
  unsigned short* km16    = q16 + 1695744;                  //   294,912 sh
  unsigned short* seqf    = km16 + 294912;                  // 3,145,728 sh
  unsigned short* htbf    = seqf + 3145728;                 // 2,293,760 sh (4*HT_ABS)
  unsigned short* rs_bf   = htbf + 4*HT_ABS;                // 1,695,744 sh
  unsigned short* ment_bf = rs_bf + 1695744;                //   294,912 sh
  unsigned short* Wq_f    = ment_bf + 294912;               //   589,824 sh
  unsigned short* Wk_f    = Wq_f + 589824;                  //   589,824 sh
  unsigned short* headW_f = Wk_f + 589824;                  // 1,179,648 sh
  unsigned short* tailW_f = headW_f + 1179648;              // 1,179,648 sh
  unsigned short* hs16    = tailW_f + 1179648;              // 1,695,744 sh (offset 15.3M sh)
  unsigned short* ts16    = hs16 + 1695744;
  unsigned short* Wbf     = ts16 + 1695744;                 // 6,881,280 sh
  unsigned short* rsWh16  = Wbf + 6881280;                  // 1,695,744 sh
  unsigned short* rsWt16  = rsWh16 + 1695744;               // 1,695,744 sh
  unsigned short* mWh16   = rsWt16 + 1695744;               //   294,912 sh
  unsigned short* mWt16   = mWh16 + 294912;                 //   294,912 sh
  unsigned short* partial = (unsigned short*)ws;
  // fp16 partial: 48*2208*97 = 10,280,448 sh = 20.6 MB; region [ws .. hs16) spans
  // 30.6 MB and is all dead before the bilinear: safe.

  k_prep   <<<4320, 256, 0, stream>>>(bilW, Wbf, seq, seqf, W_q, Wq_f, W_k, Wk_f,
                                      headW, headW_f, tailW, tailW_f,
                                      att, mpos, ent_att, ment_bf);
  k_ht_att <<<4*560, 256, 0, stream>>>(ent_att, hts, htbf);
  {
    FJobs P{};
    P.j[0] = { htbf, seqf, nullptr, rs_bf, Pc, 35, 32, Pc,
               (size_t)HT_ABS, (size_t)(48*32*512) };
    P.xs[0] = 0; P.xs[1] = 5; P.n = 1;
    k_fgemmN<32,2,2,32><<<dim3(5,24,4), 256, 0, stream>>>(P);
  }
  {
    FJobs P{};
    P.j[0] = { rs_bf,   Wq_f,              nullptr, q16,    Rc,  138, 24, 0, 0, 0 };
    P.j[1] = { ment_bf, Wk_f,              nullptr, km16,   384,  24, 24, 0, 0, 0 };
    P.j[2] = { rs_bf,   headW_f + 24*512,  nullptr, rsWh16, Rc,  138, 48, 0, 0, 0 };
    P.j[3] = { rs_bf,   tailW_f + 24*512,  nullptr, rsWt16, Rc,  138, 48, 0, 0, 0 };
    P.j[4] = { ment_bf, headW_f,           nullptr, mWh16,  384,  24, 48, 0, 0, 0 };
    P.j[5] = { ment_bf, tailW_f,           nullptr, mWt16,  384,  24, 48, 0, 0, 0 };
    P.xs[0]=0; P.xs[1]=18; P.xs[2]=21; P.xs[3]=39; P.xs[4]=57; P.xs[5]=60; P.xs[6]=63;
    P.n = 6;
    k_fgemmN<24,3,4,12><<<dim3(63,12), 256, 0, stream>>>(P);
  }
  k_pool   <<<Rc/4, 256, 0, stream>>>(km16, q16, rsWh16, rsWt16, mWh16, mWt16,
                                      headb, tailb, hts, hs16, ts16);
  k_bilinear_mfma<<<9*KSPL, 256, 0, stream>>>(hs16, ts16, Wbf, partial);
  k_reduce <<<(Rc*NLc+255)/256, 256, 0, stream>>>(partial, bilb, out);
}

// Round 16
// 122.174 us; speedup vs baseline: 1.7618x; 1.0012x over previous
//
#include <hip/hip_runtime.h>
#include <hip/hip_bf16.h>
#include <math.h>

#define Bc 4
#define Lc 1024
#define Dc 768
#define Hc 12
#define Ec 24
#define Mc 4
#define Pc 552
#define EMBc 768
#define NLc 97
#define Rc (Bc*Pc)      // 2208
#define KSPL 48         // bilinear: 12 k-blocks x 4 i-splits of 16
#define HT_ABS (35*32*512)   // htbf flin per-batch stride (shorts)

typedef __attribute__((ext_vector_type(4))) float f32x4;
typedef __attribute__((ext_vector_type(8))) short short8;
typedef __attribute__((ext_vector_type(4))) unsigned short us4;
typedef _Float16 f16x8 __attribute__((ext_vector_type(8)));

static __device__ __forceinline__ unsigned short f2bf(float x){
  unsigned int u = __float_as_uint(x);
  unsigned int r = u + 0x7fffu + ((u >> 16) & 1u);   // RNE
  return (unsigned short)(r >> 16);
}
static __device__ __forceinline__ unsigned short f2h(float x){
  _Float16 h = (_Float16)x;
  return __builtin_bit_cast(unsigned short, h);
}
static __device__ __forceinline__ float h2f(unsigned short x){
  return (float)__builtin_bit_cast(_Float16, x);
}
// flin index: row r, k-index kk, KT = K/32 chunks
static __device__ __forceinline__ size_t flin_off(int r, int kk, int KT){
  return ((size_t)(r>>4)*KT + (kk>>5))*512 + (size_t)((((kk&31)>>3)*16 + (r&15))*8) + (kk&7);
}

// ---------------- K0: weight prep + ent_att + mention gather (one launch) ----------------
__global__ __launch_bounds__(256) void k_prep(const float* __restrict__ bilW, unsigned short* __restrict__ Wbf,
                                              const float* __restrict__ seq, unsigned short* __restrict__ seqf,
                                              const float* __restrict__ W_q, unsigned short* __restrict__ Wq_f,
                                              const float* __restrict__ W_k, unsigned short* __restrict__ Wk_f,
                                              const float* __restrict__ headW, unsigned short* __restrict__ headW_f,
                                              const float* __restrict__ tailW, unsigned short* __restrict__ tailW_f,
                                              const float* __restrict__ att, const int* __restrict__ mpos,
                                              float* __restrict__ ent_att,
                                              unsigned short* __restrict__ ment_bf){
  int bx = blockIdx.x;
  int tid = threadIdx.x;
  __shared__ float t[64][65];     // shared by transpose path and bilW path
  if (bx < 1536){
    const float* Ws = bilW + (size_t)bx*32*NLc;   // 3104 contiguous floats
    unsigned short* o = Wbf + (size_t)bx*4480;
    float* w = &t[0][0];                          // 3104 <= 4160
    for (int idx = tid; idx < 32*NLc; idx += 256)
      w[idx] = Ws[idx];
    __syncthreads();
    #pragma unroll
    for (int q8 = 0; q8 < 18; q8++){
      int idx = q8*256 + tid;
      if (idx < 4480){
        int n = idx / 40, kk = idx - n*40;
        float v = (kk < 32 && n < NLc) ? w[kk*NLc + n] : 0.f;
        o[idx] = f2h(v);
      }
    }
    return;
  }
  if (bx >= 3168){                  // ent_att + gather
    int blk = bx - 3168;            // (b*E+e)*H + h, 1152 blocks
    int h  = blk % Hc;
    int be = blk / Hc;
    int b  = be / Ec;
    int p0 = mpos[be*Mc+0]+1, p1 = mpos[be*Mc+1]+1;
    int p2 = mpos[be*Mc+2]+1, p3 = mpos[be*Mc+3]+1;
    const float* ab = att + ((size_t)b*Hc + h)*Lc*Lc;
    const float* a0 = ab + (size_t)p0*Lc;
    const float* a1 = ab + (size_t)p1*Lc;
    const float* a2 = ab + (size_t)p2*Lc;
    const float* a3 = ab + (size_t)p3*Lc;
    float* o = ent_att + (size_t)blk*Lc;
    int l4 = tid*4;
    float4 v0 = *(const float4*)(a0 + l4);
    float4 v1 = *(const float4*)(a1 + l4);
    float4 v2 = *(const float4*)(a2 + l4);
    float4 v3 = *(const float4*)(a3 + l4);
    float4 ov;
    ov.x = 0.25f*(v0.x+v1.x+v2.x+v3.x);
    ov.y = 0.25f*(v0.y+v1.y+v2.y+v3.y);
    ov.z = 0.25f*(v0.z+v1.z+v2.z+v3.z);
    ov.w = 0.25f*(v0.w+v1.w+v2.w+v3.w);
    *(float4*)(o + l4) = ov;
    int gidx = blk*256 + tid;       // over B*E*M*D
    int d = gidx % Dc;
    int bem = gidx / Dc;
    int bb = bem / (Ec*Mc);
    int pos = mpos[bem] + 1;
    float v = seq[((size_t)bb*Lc + pos)*Dc + d];
    ment_bf[flin_off(bem, d, 24)] = f2bf(v);
    return;
  }
  bx -= 1536;
  const float* src; unsigned short* dst; int tk, tn, KTW;
  if (bx < 768){                     // seq [1024x768] x4 -> flin KTW=32
    int z = bx / 192, rem = bx % 192;
    src = seq + (size_t)z*Lc*Dc; dst = seqf + (size_t)z*(Dc/16)*(Lc/32)*512;
    tk = rem % 16; tn = rem / 16; KTW = 32;
  } else if (bx < 768+144){
    int rem = bx - 768;
    src = W_q; dst = Wq_f; tk = rem % 12; tn = rem / 12; KTW = 24;
  } else if (bx < 768+288){
    int rem = bx - (768+144);
    src = W_k; dst = Wk_f; tk = rem % 12; tn = rem / 12; KTW = 24;
  } else if (bx < 768+288+288){
    int rem = bx - (768+288);
    src = headW; dst = headW_f; tk = rem % 24; tn = rem / 24; KTW = 48;
  } else {
    int rem = bx - (768+288+288);
    src = tailW; dst = tailW_f; tk = rem % 24; tn = rem / 24; KTW = 48;
  }
  int r0 = tk*64, c0 = tn*64;       // r0 along K, c0 along N(=768)
  #pragma unroll
  for (int q8 = 0; q8 < 16; q8++){
    int idx = q8*256 + tid;
    int rr = idx >> 6, cc = idx & 63;
    t[rr][cc] = src[(size_t)(r0+rr)*768 + c0+cc];
  }
  __syncthreads();
  #pragma unroll
  for (int q8 = 0; q8 < 16; q8++){
    int idx = q8*256 + tid;
    int li = idx & 511, sub = idx >> 9;
    int nt_l = sub >> 1, kt_l = sub & 1;
    int lane = li >> 3, e = li & 7;
    int kl = kt_l*32 + (lane>>4)*8 + e;
    int nl = nt_l*16 + (lane&15);
    dst[ ((size_t)(c0/16 + nt_l)*KTW + (r0/32 + kt_l))*512 + li ] = f2bf(t[kl][nl]);
  }
}

// ---------------- K2: ht_att -> bf16 flin (zero pad rows 552..559) ----------------
__global__ __launch_bounds__(256) void k_ht_att(const float* __restrict__ ent_att,
                                                const int* __restrict__ hts,
                                                unsigned short* __restrict__ htbf){
  int b = blockIdx.x & 3;
  int p = blockIdx.x >> 2;          // 0..559
  unsigned short* o = htbf + (size_t)b*HT_ABS;
  int l4 = threadIdx.x*4;
  if (p >= Pc){
    us4 z4 = {0,0,0,0};
    *(us4*)(o + flin_off(p, l4, 32)) = z4;
    return;
  }
  int r = b*Pc + p;
  int hi = hts[r*2+0], ti = hts[r*2+1];
  const float* eh = ent_att + (size_t)(b*Ec+hi)*Hc*Lc;
  const float* et = ent_att + (size_t)(b*Ec+ti)*Hc*Lc;
  __shared__ float raw[Lc];
  __shared__ float wsum[4];
  float4 s4 = {0.f,0.f,0.f,0.f};
  #pragma unroll
  for (int h = 0; h < Hc; h++){
    float4 e1 = *(const float4*)&eh[h*Lc + l4];
    float4 e2 = *(const float4*)&et[h*Lc + l4];
    s4.x = fmaf(e1.x,e2.x,s4.x); s4.y = fmaf(e1.y,e2.y,s4.y);
    s4.z = fmaf(e1.z,e2.z,s4.z); s4.w = fmaf(e1.w,e2.w,s4.w);
  }
  s4.x *= (1.0f/Hc); s4.y *= (1.0f/Hc); s4.z *= (1.0f/Hc); s4.w *= (1.0f/Hc);
  *(float4*)&raw[l4] = s4;
  float lsum = s4.x+s4.y+s4.z+s4.w;
  for (int off = 32; off; off >>= 1) lsum += __shfl_down(lsum, off);
  if ((threadIdx.x & 63) == 0) wsum[threadIdx.x>>6] = lsum;
  __syncthreads();
  float inv = 1.0f/(wsum[0]+wsum[1]+wsum[2]+wsum[3] + 1e-5f);
  float4 rv = *(const float4*)&raw[l4];
  us4 v4;
  v4[0] = f2bf(rv.x*inv); v4[1] = f2bf(rv.y*inv);
  v4[2] = f2bf(rv.z*inv); v4[3] = f2bf(rv.w*inv);
  *(us4*)(o + flin_off(p, l4, 32)) = v4;
}

// ---------------- K4a: rs GEMM (flin MFMA, K-chunked W staging) ----------------
struct FJob {
  const unsigned short* A1; const unsigned short* W; const float* bias; void* C;
  int M; int mtmax; int Wktw; int rowsPerBatch;
  size_t Abs; size_t Wbs;
};

// CT: 2 = bf16 flin (KTC=24)
template<int KT1, int CT, int NT, int KCH>
__global__ __launch_bounds__(256) void k_fgemmN(FJob j){
  int tid = threadIdx.x;
  int mbx = blockIdx.x;
  int z = blockIdx.z;
  int lane = tid & 63, wid = tid >> 6;
  int row16 = lane & 15, oct = lane >> 4;

  __shared__ __align__(16) unsigned short Wlds[NT*KCH*512];
  const unsigned short* wpan = j.W + (size_t)z*j.Wbs + (size_t)(blockIdx.y*NT)*j.Wktw*512;

  int rb = mbx*128 + wid*32;
  int mt0 = rb >> 4;       if (mt0 >= j.mtmax) mt0 = j.mtmax - 1;
  int mt1 = (rb >> 4) + 1; if (mt1 >= j.mtmax) mt1 = j.mtmax - 1;
  const unsigned short* ap0 = j.A1 + (size_t)z*j.Abs + (size_t)mt0*KT1*512 + lane*8;
  const unsigned short* ap1 = j.A1 + (size_t)z*j.Abs + (size_t)mt1*KT1*512 + lane*8;
  f32x4 acc[2][NT];
  #pragma unroll
  for (int m = 0; m < 2; m++)
    #pragma unroll
    for (int n = 0; n < NT; n++) acc[m][n] = (f32x4){0.f,0.f,0.f,0.f};

  #pragma unroll
  for (int kc = 0; kc < KT1/KCH; kc++){
    {
      constexpr int UNITS = NT*KCH*64;          // 16B units
      #pragma unroll
      for (int it = 0; it < UNITS/256; ++it){
        int u = it*256 + tid;
        int f = u >> 6;                          // frag index within chunk
        int n = f / KCH, kt = f - n*KCH;
        size_t so = (((size_t)(n*j.Wktw + kc*KCH + kt)) << 9) + (size_t)((u & 63) << 3);
        __builtin_amdgcn_global_load_lds(
            (const __attribute__((address_space(1))) unsigned int*)(wpan + so),
            (__attribute__((address_space(3))) unsigned int*)((char*)Wlds + (size_t)u*16),
            16, 0, 0);
      }
    }
    __syncthreads();    // chunk staged (drains vmcnt)
    #pragma unroll 4
    for (int k2 = 0; k2 < KCH; k2++){
      int kt = kc*KCH + k2;
      short8 a0 = *(const short8*)(ap0 + (size_t)kt*512);
      short8 a1 = *(const short8*)(ap1 + (size_t)kt*512);
      #pragma unroll
      for (int n = 0; n < NT; n++){
        short8 bv = *(const short8*)&Wlds[(n*KCH + k2)*512 + lane*8];
        acc[0][n] = __builtin_amdgcn_mfma_f32_16x16x32_bf16(a0, bv, acc[0][n], 0, 0, 0);
        acc[1][n] = __builtin_amdgcn_mfma_f32_16x16x32_bf16(a1, bv, acc[1][n], 0, 0, 0);
      }
    }
    if (kc + 1 < KT1/KCH) __syncthreads();   // all reads done before re-stage
  }

  int colb = blockIdx.y*(NT*16);
  #pragma unroll
  for (int m = 0; m < 2; m++)
    #pragma unroll
    for (int n = 0; n < NT; n++)
      #pragma unroll
      for (int jj = 0; jj < 4; jj++){
        int r = rb + m*16 + oct*4 + jj;
        if (r < j.M){
          int col = colb + n*16 + row16;
          int rg = z*j.rowsPerBatch + r;
          ((unsigned short*)j.C)[flin_off(rg, col, 24)] = f2bf(acc[m][n][jj]);
        }
      }
}

// ---------------- K4b: fused 3-output GEMM (shared A, 3 W panels in LDS) ----------------
struct F3 {
  const unsigned short* A1;
  const unsigned short* W0; const unsigned short* W1; const unsigned short* W2;
  unsigned short* C0; unsigned short* C1; unsigned short* C2;
  int M; int mtmax; int ktw0; int ktw1; int ktw2;
};

template<int KT1, int NT, int KCH>
__global__ __launch_bounds__(256) void k_fgemm3(F3 j0, F3 j1, int nx0){
  int tid = threadIdx.x;
  F3 j = ((int)blockIdx.x < nx0) ? j0 : j1;
  int mbx = ((int)blockIdx.x < nx0) ? blockIdx.x : blockIdx.x - nx0;
  int lane = tid & 63, wid = tid >> 6;
  int row16 = lane & 15, oct = lane >> 4;
  const unsigned short* Ws[3] = { j.W0, j.W1, j.W2 };
  unsigned short* Cs[3] = { j.C0, j.C1, j.C2 };
  const int ktws[3] = { j.ktw0, j.ktw1, j.ktw2 };

  __shared__ __align__(16) unsigned short Wlds[3][NT*KCH*512];   // 3 x 24.6 KB

  int rb = mbx*128 + wid*32;
  int mt0 = rb >> 4;  if (mt0 >= j.mtmax) mt0 = j.mtmax - 1;
  int mt1 = mt0 + 1;  if (mt1 >= j.mtmax) mt1 = j.mtmax - 1;
  const unsigned short* ap0 = j.A1 + (size_t)mt0*KT1*512 + lane*8;
  const unsigned short* ap1 = j.A1 + (size_t)mt1*KT1*512 + lane*8;

  f32x4 acc[3][2][NT];
  #pragma unroll
  for (int s = 0; s < 3; s++)
    #pragma unroll
    for (int m = 0; m < 2; m++)
      #pragma unroll
      for (int n = 0; n < NT; n++) acc[s][m][n] = (f32x4){0.f,0.f,0.f,0.f};

  #pragma unroll
  for (int kc = 0; kc < KT1/KCH; kc++){
    #pragma unroll
    for (int s = 0; s < 3; s++){
      const unsigned short* wpan = Ws[s] + (size_t)(blockIdx.y*NT)*ktws[s]*512;
      constexpr int UNITS = NT*KCH*64;
      #pragma unroll
      for (int it = 0; it < UNITS/256; ++it){
        int u = it*256 + tid;
        int f = u >> 6;
        int n = f / KCH, kt = f - n*KCH;
        size_t so = (((size_t)(n*ktws[s] + kc*KCH + kt)) << 9) + (size_t)((u & 63) << 3);
        __builtin_amdgcn_global_load_lds(
            (const __attribute__((address_space(1))) unsigned int*)(wpan + so),
            (__attribute__((address_space(3))) unsigned int*)((char*)&Wlds[s][0] + (size_t)u*16),
            16, 0, 0);
      }
    }
    __syncthreads();    // chunks staged (drains vmcnt)
    #pragma unroll 2
    for (int k2 = 0; k2 < KCH; k2++){
      int kt = kc*KCH + k2;
      short8 a0 = *(const short8*)(ap0 + (size_t)kt*512);
      short8 a1 = *(const short8*)(ap1 + (size_t)kt*512);
      #pragma unroll
      for (int s = 0; s < 3; s++)
        #pragma unroll
        for (int n = 0; n < NT; n++){
          short8 bv = *(const short8*)&Wlds[s][(n*KCH + k2)*512 + lane*8];
          acc[s][0][n] = __builtin_amdgcn_mfma_f32_16x16x32_bf16(a0, bv, acc[s][0][n], 0, 0, 0);
          acc[s][1][n] = __builtin_amdgcn_mfma_f32_16x16x32_bf16(a1, bv, acc[s][1][n], 0, 0, 0);
        }
    }
    if (kc + 1 < KT1/KCH) __syncthreads();
  }

  int colb = blockIdx.y*(NT*16);
  #pragma unroll
  for (int s = 0; s < 3; s++)
    #pragma unroll
    for (int m = 0; m < 2; m++)
      #pragma unroll
      for (int n = 0; n < NT; n++)
        #pragma unroll
        for (int jj = 0; jj < 4; jj++){
          int r = rb + m*16 + oct*4 + jj;
          if (r < j.M){
            int col = colb + n*16 + row16;
            Cs[s][(size_t)r*768 + col] = f2h(acc[s][m][n][jj]);
          }
        }
}

// ---------------- K6: pool v2 (fp16 inputs) ----------------
__global__ __launch_bounds__(256) void k_pool(const unsigned short* __restrict__ km16,
                                              const unsigned short* __restrict__ q16,
                                              const unsigned short* __restrict__ rsWh16,
                                              const unsigned short* __restrict__ rsWt16,
                                              const unsigned short* __restrict__ mWh16,
                                              const unsigned short* __restrict__ mWt16,
                                              const float* __restrict__ headb,
                                              const float* __restrict__ tailb,
                                              const int* __restrict__ hts,
                                              unsigned short* __restrict__ hs16,
                                              unsigned short* __restrict__ ts16){
  int wid = threadIdx.x >> 6, lane = threadIdx.x & 63;
  int r = blockIdx.x*4 + wid;
  int b = r / Pc;
  float q[12];
  const unsigned short* qp = q16 + (size_t)r*Dc + lane;
  #pragma unroll
  for (int u = 0; u < 12; u++) q[u] = h2f(qp[u*64]);
  const float invs = 0.03608439182435161f;  // 1/sqrt(768)
  #pragma unroll
  for (int side = 0; side < 2; side++){
    int e = hts[r*2+side];
    const unsigned short* kb = km16 + (size_t)(b*Ec+e)*Mc*Dc + lane;
    float part[Mc] = {0.f,0.f,0.f,0.f};
    #pragma unroll
    for (int m = 0; m < Mc; m++)
      #pragma unroll
      for (int u = 0; u < 12; u++)
        part[m] = fmaf(h2f(kb[m*Dc + u*64]), q[u], part[m]);
    #pragma unroll
    for (int m = 0; m < Mc; m++)
      #pragma unroll
      for (int off = 1; off < 64; off <<= 1)
        part[m] += __shfl_xor(part[m], off);
    float mx = fmaxf(fmaxf(part[0],part[1]), fmaxf(part[2],part[3])) * invs;
    float w0 = expf(part[0]*invs - mx), w1 = expf(part[1]*invs - mx);
    float w2 = expf(part[2]*invs - mx), w3 = expf(part[3]*invs - mx);
    float isum = 1.0f/(w0+w1+w2+w3);
    w0 *= isum; w1 *= isum; w2 *= isum; w3 *= isum;
    const unsigned short* mW  = (side ? mWt16  : mWh16) + (size_t)(b*Ec+e)*Mc*Dc;
    const unsigned short* rsW = (side ? rsWt16 : rsWh16) + (size_t)r*Dc;
    const float* bias = side ? tailb : headb;
    unsigned short* o = (side ? ts16 : hs16) + (size_t)r*Dc;
    #pragma unroll
    for (int u = 0; u < 12; u++){
      int d = lane + u*64;
      float v = h2f(rsW[d]) + bias[d]
              + w0*h2f(mW[d]) + w1*h2f(mW[Dc+d]) + w2*h2f(mW[2*Dc+d]) + w3*h2f(mW[3*Dc+d]);
      o[d] = f2h(tanhf(v));
    }
  }
}

// ---------------- K8: MFMA bilinear fp16, 4 m-frags/wave, KSPL=48, fp16 partial ----------------
__global__ __launch_bounds__(256) void k_bilinear_mfma(
    const unsigned short* __restrict__ hs16, const unsigned short* __restrict__ ts16,
    const unsigned short* __restrict__ Wbf,
    unsigned short* __restrict__ partial)
{
  int mb = blockIdx.x / KSPL;
  int kb = blockIdx.x % KSPL;
  int k  = kb >> 2;             // EMB block 0..11
  int i0 = (kb & 3) * 16;       // i sub-range (16 wide)

  int tid  = threadIdx.x;
  int lane = tid & 63;
  int wid  = tid >> 6;
  int row16 = lane & 15;
  int oct   = lane >> 4;

  int rbase = mb*256 + wid*64;

  __shared__ __align__(16) unsigned short Wlds[2][8960];

  f16x8 tsh[4][2];  // [m][jhalf]
  f16x8 hsh[4][2];  // [m][q], i = q*8 + e  (16 i-values)
  #pragma unroll
  for (int m = 0; m < 4; m++){
    int r = rbase + m*16 + row16; if (r > Rc-1) r = Rc-1;
    const unsigned short* tp = ts16 + (size_t)r*EMBc + k*64;
    tsh[m][0] = __builtin_bit_cast(f16x8, *(const short8*)(tp + oct*8));
    tsh[m][1] = __builtin_bit_cast(f16x8, *(const short8*)(tp + 32 + oct*8));
    const unsigned short* hp = hs16 + (size_t)r*EMBc + k*64 + i0;
    hsh[m][0] = __builtin_bit_cast(f16x8, *(const short8*)(hp));
    hsh[m][1] = __builtin_bit_cast(f16x8, *(const short8*)(hp + 8));
  }

  const char* wsrc = (const char*)(Wbf + ((size_t)(k*128 + i0*2))*4480);

  #pragma unroll
  for (int rr = 0; rr < 5; rr++){
    int u = tid + rr*256;
    if (u < 1120)
      __builtin_amdgcn_global_load_lds(
        (const __attribute__((address_space(1))) unsigned int*)(wsrc + (size_t)u*16),
        (__attribute__((address_space(3))) unsigned int*)((char*)&Wlds[0][0] + u*16),
        16, 0, 0);
  }

  f32x4 acc[4][7];
  #pragma unroll
  for (int m = 0; m < 4; m++)
    #pragma unroll
    for (int n = 0; n < 7; n++) acc[m][n] = (f32x4){0.f,0.f,0.f,0.f};

  __syncthreads();   // pair 0 staged

  #pragma unroll
  for (int cp = 0; cp < 16; cp++){    // pair cp = chunks (i=cp, jh=0/1)
    int cur = cp & 1;
    if (cp < 15){
      const char* nsrc = wsrc + (size_t)(cp+1)*17920;
      #pragma unroll
      for (int rr = 0; rr < 5; rr++){
        int u = tid + rr*256;
        if (u < 1120)
          __builtin_amdgcn_global_load_lds(
            (const __attribute__((address_space(1))) unsigned int*)(nsrc + (size_t)u*16),
            (__attribute__((address_space(3))) unsigned int*)((char*)&Wlds[cur^1][0] + u*16),
            16, 0, 0);
      }
    }
    #pragma unroll
    for (int half = 0; half < 2; half++){
      f16x8 af[4];
      #pragma unroll
      for (int m = 0; m < 4; m++){
        _Float16 hv = hsh[m][cp>>3][cp&7];       // static after full unroll
        f16x8 hvb = {hv,hv,hv,hv,hv,hv,hv,hv};
        af[m] = tsh[m][half] * hvb;              // 4x v_pk_mul_f16
      }
      #pragma unroll
      for (int n = 0; n < 7; n++){
        f16x8 bfr = __builtin_bit_cast(f16x8,
            *(const short8*)&Wlds[cur][half*4480 + (n*16 + row16)*40 + oct*8]);
        #pragma unroll
        for (int m = 0; m < 4; m++)
          acc[m][n] = __builtin_amdgcn_mfma_f32_16x16x32_f16(af[m], bfr, acc[m][n], 0, 0, 0);
      }
    }
    __syncthreads();
  }

  unsigned short* pk = partial + (size_t)kb*Rc*NLc;
  #pragma unroll
  for (int m = 0; m < 4; m++){
    #pragma unroll
    for (int n = 0; n < 7; n++){
      #pragma unroll
      for (int j = 0; j < 4; j++){
        int r = rbase + m*16 + oct*4 + j;
        int col = n*16 + row16;
        if (r < Rc && col < NLc)
          pk[(size_t)r*NLc + col] = f2h(acc[m][n][j]);
      }
    }
  }
}

// ---------------- K9: sum fp16 partials + bias ----------------
__global__ __launch_bounds__(256) void k_reduce(const unsigned short* __restrict__ partial,
                                                const float* __restrict__ bilb,
                                                float* __restrict__ out){
  int idx = blockIdx.x*256 + threadIdx.x;
  if (idx >= Rc*NLc) return;
  int n = idx % NLc;
  float s = bilb[n];
  #pragma unroll
  for (int ks = 0; ks < KSPL; ks++) s += h2f(partial[(size_t)ks*Rc*NLc + idx]);
  out[idx] = s;
}

extern "C" void kernel_launch(void* const* d_in, const int* in_sizes, int n_in,
                              void* d_out, int out_size, void* d_ws, size_t ws_size,
                              hipStream_t stream){
  const float* seq   = (const float*)d_in[0];
  const float* att   = (const float*)d_in[1];
  const float* W_q   = (const float*)d_in[2];
  const float* W_k   = (const float*)d_in[3];
  const float* headW = (const float*)d_in[4];
  const float* headb = (const float*)d_in[5];
  const float* tailW = (const float*)d_in[6];
  const float* tailb = (const float*)d_in[7];
  const float* bilW  = (const float*)d_in[8];
  const float* bilb  = (const float*)d_in[9];
  const int*   mpos  = (const int*)d_in[10];
  const int*   hts   = (const int*)d_in[11];
  float* out = (float*)d_out;

  float* ws = (float*)d_ws;
  float* ent_att = ws;                                      // 1,179,648 f (= 2,359,296 sh)
  unsigned short* base = (unsigned short*)(ws + 1179648);
  unsigned short* q16     = base;                           // 1,695,744 sh
  unsigned short* km16    = q16 + 1695744;                  //   294,912 sh
  unsigned short* seqf    = km16 + 294912;                  // 3,145,728 sh
  unsigned short* htbf    = seqf + 3145728;                 // 2,293,760 sh (4*HT_ABS)
  unsigned short* rs_bf   = htbf + 4*HT_ABS;                // 1,695,744 sh
  unsigned short* ment_bf = rs_bf + 1695744;                //   294,912 sh
  unsigned short* Wq_f    = ment_bf + 294912;               //   589,824 sh
  unsigned short* Wk_f    = Wq_f + 589824;                  //   589,824 sh
  unsigned short* headW_f = Wk_f + 589824;                  // 1,179,648 sh
  unsigned short* tailW_f = headW_f + 1179648;              // 1,179,648 sh
  unsigned short* hs16    = tailW_f + 1179648;              // 1,695,744 sh (offset 15.3M sh)
  unsigned short* ts16    = hs16 + 1695744;
  unsigned short* Wbf     = ts16 + 1695744;                 // 6,881,280 sh
  unsigned short* rsWh16  = Wbf + 6881280;                  // 1,695,744 sh
  unsigned short* rsWt16  = rsWh16 + 1695744;               // 1,695,744 sh
  unsigned short* mWh16   = rsWt16 + 1695744;               //   294,912 sh
  unsigned short* mWt16   = mWh16 + 294912;                 //   294,912 sh
  unsigned short* partial = (unsigned short*)ws;
  // fp16 partial: 48*2208*97 = 10,280,448 sh = 20.6 MB; region [ws .. hs16) spans
  // 30.6 MB and is all dead before the bilinear: safe.

  k_prep   <<<4320, 256, 0, stream>>>(bilW, Wbf, seq, seqf, W_q, Wq_f, W_k, Wk_f,
                                      headW, headW_f, tailW, tailW_f,
                                      att, mpos, ent_att, ment_bf);
  k_ht_att <<<4*560, 256, 0, stream>>>(ent_att, hts, htbf);
  {
    FJob jrs = { htbf, seqf, nullptr, rs_bf, Pc, 35, 32, Pc,
                 (size_t)HT_ABS, (size_t)(48*32*512) };
    k_fgemmN<32,2,2,32><<<dim3(5,24,4), 256, 0, stream>>>(jrs);
  }
  {
    F3 jA = { rs_bf,   Wq_f, headW_f + 24*512, tailW_f + 24*512,
              q16,  rsWh16, rsWt16, Rc,  138, 24, 48, 48 };
    F3 jB = { ment_bf, Wk_f, headW_f,          tailW_f,
              km16, mWh16,  mWt16,  384, 24,  24, 48, 48 };
    k_fgemm3<24,2,12><<<dim3(21,24), 256, 0, stream>>>(jA, jB, 18);
  }
  k_pool   <<<Rc/4, 256, 0, stream>>>(km16, q16, rsWh16, rsWt16, mWh16, mWt16,
                                      headb, tailb, hts, hs16, ts16);
  k_bilinear_mfma<<<9*KSPL, 256, 0, stream>>>(hs16, ts16, Wbf, partial);
  k_reduce <<<(Rc*NLc+255)/256, 256, 0, stream>>>(partial, bilb, out);
}